// Round 1
// baseline (3507.552 us; speedup 1.0000x reference)
//
#include <hip/hip_runtime.h>

#define N_NODES 100000
#define N_EDGES 1600000
#define N_GRAPHS 64
#define IN_CH 15
#define HID 128
#define NCLS 11

// ---------------- init: deg=1 (self-loop), pooled=0, cnt=0 ----------------
__global__ __launch_bounds__(256) void k_init(int* __restrict__ deg,
                                              float* __restrict__ pooled,
                                              int* __restrict__ cnt) {
    int i = blockIdx.x * 256 + threadIdx.x;
    if (i < N_NODES) deg[i] = 1;
    if (i < N_GRAPHS * HID) pooled[i] = 0.f;
    if (i < N_GRAPHS) cnt[i] = 0;
}

// ---------------- degree count over dst ----------------
__global__ __launch_bounds__(256) void k_deg(const int* __restrict__ dst,
                                             int* __restrict__ deg) {
    int e = blockIdx.x * 256 + threadIdx.x;
    if (e < N_EDGES) atomicAdd(&deg[dst[e]], 1);
}

__global__ __launch_bounds__(256) void k_dinv(const int* __restrict__ deg,
                                              float* __restrict__ dinv) {
    int i = blockIdx.x * 256 + threadIdx.x;
    if (i < N_NODES) dinv[i] = rsqrtf((float)deg[i]);
}

// ---------------- layer-1 transform: m' = (x @ W1) * dinv; agg init = m' ----------------
__global__ __launch_bounds__(256) void k_xform1(const float* __restrict__ x,
                                                const float* __restrict__ W1,
                                                const float* __restrict__ dinv,
                                                float* __restrict__ m,
                                                float* __restrict__ agg) {
    __shared__ float w[IN_CH * HID];  // 7.5 KB
    int t = threadIdx.x;
    for (int i = t; i < IN_CH * HID; i += 256) w[i] = W1[i];
    __syncthreads();
    int node = blockIdx.x * 2 + (t >> 7);
    if (node >= N_NODES) return;
    int h = t & 127;
    const float* xr = x + node * IN_CH;
    float acc = 0.f;
#pragma unroll
    for (int c = 0; c < IN_CH; ++c) acc += xr[c] * w[c * HID + h];
    acc *= dinv[node];
    m[(size_t)node * HID + h] = acc;
    agg[(size_t)node * HID + h] = acc;
}

// ---------------- edge scatter: agg[dst] += m[src], float2 per thread ----------------
// one wave (64 lanes x float2 = 128 ch) == one edge; src/dst load is wave-uniform
__global__ __launch_bounds__(256) void k_scatter(const int* __restrict__ src,
                                                 const int* __restrict__ dst,
                                                 const float* __restrict__ m,
                                                 float* __restrict__ agg) {
    unsigned i = blockIdx.x * 256u + threadIdx.x;
    unsigned e = i >> 6;
    unsigned c = (i & 63u) * 2u;
    if (e < N_EDGES) {
        int s = src[e], d = dst[e];
        const float2 v = *(const float2*)&m[(size_t)s * HID + c];
        float* a = &agg[(size_t)d * HID + c];
        atomicAdd(a, v.x);
        atomicAdd(a + 1, v.y);
    }
}

// ---------------- h = relu(dinv * agg + b), in place, float4 ----------------
__global__ __launch_bounds__(256) void k_bias_relu(float* __restrict__ hbuf,
                                                   const float* __restrict__ bias,
                                                   const float* __restrict__ dinv) {
    unsigned i = blockIdx.x * 256u + threadIdx.x;  // over N*HID/4
    if (i < (unsigned)(N_NODES * HID / 4)) {
        int node = i >> 5;         // 32 float4 per node row
        int c4 = i & 31;
        float4 v = ((float4*)hbuf)[i];
        float dv = dinv[node];
        float4 b = ((const float4*)bias)[c4];
        v.x = fmaxf(dv * v.x + b.x, 0.f);
        v.y = fmaxf(dv * v.y + b.y, 0.f);
        v.z = fmaxf(dv * v.z + b.z, 0.f);
        v.w = fmaxf(dv * v.w + b.w, 0.f);
        ((float4*)hbuf)[i] = v;
    }
}

// ---------------- layer-2 transform: m' = (H @ W2) * dinv; agg init = m' ----------------
// 32 nodes x 128 cols per block; thread computes 4x4; W2 (64KB) + padded H tile in LDS.
// agg may alias H: each block only overwrites rows it staged into LDS.
#define NT2 32
__global__ __launch_bounds__(256) void k_xform2(const float* __restrict__ H,
                                                const float* __restrict__ W2,
                                                const float* __restrict__ dinv,
                                                float* __restrict__ m,
                                                float* __restrict__ agg) {
    __shared__ float ws[HID * HID];       // [k][col], 64 KB
    __shared__ float hs[NT2][HID + 1];    // padded, 16.5 KB
    int t = threadIdx.x;
    for (int i = t; i < HID * HID / 4; i += 256)
        ((float4*)ws)[i] = ((const float4*)W2)[i];
    int n0 = blockIdx.x * NT2;
    for (int i = t; i < NT2 * HID / 4; i += 256) {
        int r = i >> 5;
        int c = (i & 31) * 4;
        float4 v = *(const float4*)&H[(size_t)(n0 + r) * HID + c];
        hs[r][c] = v.x; hs[r][c + 1] = v.y; hs[r][c + 2] = v.z; hs[r][c + 3] = v.w;
    }
    __syncthreads();
    int c0 = (t & 31) * 4;
    int r0 = (t >> 5) * 4;
    float acc[4][4];
#pragma unroll
    for (int j = 0; j < 4; ++j)
#pragma unroll
        for (int q = 0; q < 4; ++q) acc[j][q] = 0.f;
    for (int k = 0; k < HID; ++k) {
        float4 wv = *(const float4*)&ws[k * HID + c0];
        float h0 = hs[r0][k], h1 = hs[r0 + 1][k], h2 = hs[r0 + 2][k], h3 = hs[r0 + 3][k];
        acc[0][0] += h0 * wv.x; acc[0][1] += h0 * wv.y; acc[0][2] += h0 * wv.z; acc[0][3] += h0 * wv.w;
        acc[1][0] += h1 * wv.x; acc[1][1] += h1 * wv.y; acc[1][2] += h1 * wv.z; acc[1][3] += h1 * wv.w;
        acc[2][0] += h2 * wv.x; acc[2][1] += h2 * wv.y; acc[2][2] += h2 * wv.z; acc[2][3] += h2 * wv.w;
        acc[3][0] += h3 * wv.x; acc[3][1] += h3 * wv.y; acc[3][2] += h3 * wv.z; acc[3][3] += h3 * wv.w;
    }
#pragma unroll
    for (int j = 0; j < 4; ++j) {
        int nn = n0 + r0 + j;
        float dv = dinv[nn];
        float4 v = make_float4(acc[j][0] * dv, acc[j][1] * dv, acc[j][2] * dv, acc[j][3] * dv);
        *(float4*)&m[(size_t)nn * HID + c0] = v;
        *(float4*)&agg[(size_t)nn * HID + c0] = v;
    }
}

// ---------------- node count per graph ----------------
__global__ __launch_bounds__(256) void k_cnt(const int* __restrict__ batch,
                                             int* __restrict__ cnt) {
    int n = blockIdx.x * 256 + threadIdx.x;
    if (n < N_NODES) atomicAdd(&cnt[batch[n]], 1);
}

// ---------------- pooled sums: run-length accumulate (batch sorted) ----------------
#define POOL_CHUNK 512
__global__ __launch_bounds__(256) void k_pool(const float* __restrict__ h,
                                              const int* __restrict__ batch,
                                              float* __restrict__ pooled) {
    int t = threadIdx.x;
    int c = t & 127, half = t >> 7;
    int start = blockIdx.x * POOL_CHUNK;
    int end = min(start + POOL_CHUNK, N_NODES);
    float acc = 0.f;
    int cur = -1;
    for (int n = start + half; n < end; n += 2) {
        int g = batch[n];
        if (g != cur) {
            if (cur >= 0) atomicAdd(&pooled[cur * HID + c], acc);
            acc = 0.f;
            cur = g;
        }
        acc += h[(size_t)n * HID + c];
    }
    if (cur >= 0) atomicAdd(&pooled[cur * HID + c], acc);
}

// ---------------- final: out = (pooled/cnt) @ Wf + bf ----------------
__global__ __launch_bounds__(128) void k_final(const float* __restrict__ pooled,
                                               const int* __restrict__ cnt,
                                               const float* __restrict__ Wf,
                                               const float* __restrict__ bf,
                                               float* __restrict__ out) {
    __shared__ float p[HID];
    int g = blockIdx.x, t = threadIdx.x;
    float inv = 1.f / fmaxf((float)cnt[g], 1.f);
    p[t] = pooled[g * HID + t] * inv;
    __syncthreads();
    if (t < NCLS) {
        float acc = bf[t];
        for (int k = 0; k < HID; ++k) acc += p[k] * Wf[k * NCLS + t];
        out[g * NCLS + t] = acc;
    }
}

extern "C" void kernel_launch(void* const* d_in, const int* in_sizes, int n_in,
                              void* d_out, int out_size, void* d_ws, size_t ws_size,
                              hipStream_t stream) {
    const float* x   = (const float*)d_in[0];
    const int*   ei  = (const int*)d_in[1];   // [2][E] flat
    const int*   src = ei;
    const int*   dst = ei + N_EDGES;
    const int*   batch = (const int*)d_in[2];
    const float* W1 = (const float*)d_in[3];
    const float* b1 = (const float*)d_in[4];
    const float* W2 = (const float*)d_in[5];
    const float* b2 = (const float*)d_in[6];
    const float* Wf = (const float*)d_in[7];
    const float* bf = (const float*)d_in[8];
    float* out = (float*)d_out;

    char* ws = (char*)d_ws;
    size_t off = 0;
    int* deg = (int*)(ws + off);      off += (size_t)N_NODES * 4;       // 400000
    float* dinv = (float*)(ws + off); off += (size_t)N_NODES * 4;       // 400000
    float* bufA = (float*)(ws + off); off += (size_t)N_NODES * HID * 4; // 51.2 MB
    float* bufB = (float*)(ws + off); off += (size_t)N_NODES * HID * 4; // 51.2 MB
    float* pooled = (float*)(ws + off); off += (size_t)N_GRAPHS * HID * 4;
    int* cnt = (int*)(ws + off);      off += (size_t)N_GRAPHS * 4;

    // init deg=1, pooled=0, cnt=0
    k_init<<<(N_NODES + 255) / 256, 256, 0, stream>>>(deg, pooled, cnt);
    // degree + dinv
    k_deg<<<(N_EDGES + 255) / 256, 256, 0, stream>>>(dst, deg);
    k_dinv<<<(N_NODES + 255) / 256, 256, 0, stream>>>(deg, dinv);

    // layer 1
    k_xform1<<<N_NODES / 2, 256, 0, stream>>>(x, W1, dinv, bufA, bufB);
    k_scatter<<<N_EDGES * 64 / 256, 256, 0, stream>>>(src, dst, bufA, bufB);
    k_bias_relu<<<N_NODES * HID / 4 / 256, 256, 0, stream>>>(bufB, b1, dinv);

    // layer 2
    k_xform2<<<N_NODES / NT2, 256, 0, stream>>>(bufB, W2, dinv, bufA, bufB);
    k_scatter<<<N_EDGES * 64 / 256, 256, 0, stream>>>(src, dst, bufA, bufB);
    k_bias_relu<<<N_NODES * HID / 4 / 256, 256, 0, stream>>>(bufB, b2, dinv);

    // pooling + classifier
    k_cnt<<<(N_NODES + 255) / 256, 256, 0, stream>>>(batch, cnt);
    k_pool<<<(N_NODES + POOL_CHUNK - 1) / POOL_CHUNK, 256, 0, stream>>>(bufB, batch, pooled);
    k_final<<<N_GRAPHS, 128, 0, stream>>>(pooled, cnt, Wf, bf, out);
}

// Round 2
// 1463.865 us; speedup vs baseline: 2.3961x; 2.3961x over previous
//
#include <hip/hip_runtime.h>

#define N_NODES 100000
#define N_EDGES 1600000
#define N_GRAPHS 64
#define IN_CH 15
#define HID 128
#define NCLS 11

// ---------------- init: deg=0, pooled=0, cnt=0 ----------------
__global__ __launch_bounds__(256) void k_init(int* __restrict__ deg,
                                              float* __restrict__ pooled,
                                              int* __restrict__ cnt) {
    int i = blockIdx.x * 256 + threadIdx.x;
    if (i < N_NODES) deg[i] = 0;
    if (i < N_GRAPHS * HID) pooled[i] = 0.f;
    if (i < N_GRAPHS) cnt[i] = 0;
}

// ---------------- in-degree count over dst (int atomics, cheap) ----------------
__global__ __launch_bounds__(256) void k_deg(const int* __restrict__ dst,
                                             int* __restrict__ deg) {
    int e = blockIdx.x * 256 + threadIdx.x;
    if (e < N_EDGES) atomicAdd(&deg[dst[e]], 1);
}

__global__ __launch_bounds__(256) void k_dinv(const int* __restrict__ deg,
                                              float* __restrict__ dinv) {
    int i = blockIdx.x * 256 + threadIdx.x;
    if (i < N_NODES) dinv[i] = rsqrtf((float)(deg[i] + 1));  // +1 self-loop
}

// ---------------- exclusive scan of deg -> rowptr, cursor (1 block) ----------------
#define SCAN_T 1024
#define SCAN_C 98  // ceil(100000/1024)
__global__ __launch_bounds__(SCAN_T) void k_scan(const int* __restrict__ deg,
                                                 int* __restrict__ rowptr,
                                                 int* __restrict__ cursor) {
    __shared__ int partial[SCAN_T];
    int t = threadIdx.x;
    int start = t * SCAN_C;
    int s = 0;
    for (int i = 0; i < SCAN_C; ++i) {
        int idx = start + i;
        if (idx < N_NODES) s += deg[idx];
    }
    partial[t] = s;
    __syncthreads();
    // Hillis-Steele inclusive scan
    for (int off = 1; off < SCAN_T; off <<= 1) {
        int v = (t >= off) ? partial[t - off] : 0;
        __syncthreads();
        partial[t] += v;
        __syncthreads();
    }
    int run = (t == 0) ? 0 : partial[t - 1];
    for (int i = 0; i < SCAN_C; ++i) {
        int idx = start + i;
        if (idx < N_NODES) {
            int d = deg[idx];
            rowptr[idx] = run;
            cursor[idx] = run;
            run += d;
        }
    }
    if (t == SCAN_T - 1) rowptr[N_NODES] = run;
}

// ---------------- fill CSR: csr_src grouped by dst ----------------
__global__ __launch_bounds__(256) void k_fill(const int* __restrict__ src,
                                              const int* __restrict__ dst,
                                              int* __restrict__ cursor,
                                              int* __restrict__ csr_src) {
    int e = blockIdx.x * 256 + threadIdx.x;
    if (e < N_EDGES) {
        int pos = atomicAdd(&cursor[dst[e]], 1);
        csr_src[pos] = src[e];
    }
}

// ---------------- layer-1 transform: m = (x @ W1) * dinv ----------------
__global__ __launch_bounds__(256) void k_xform1(const float* __restrict__ x,
                                                const float* __restrict__ W1,
                                                const float* __restrict__ dinv,
                                                float* __restrict__ m) {
    __shared__ float w[IN_CH * HID];  // 7.5 KB
    int t = threadIdx.x;
    for (int i = t; i < IN_CH * HID; i += 256) w[i] = W1[i];
    __syncthreads();
    int node = blockIdx.x * 2 + (t >> 7);
    if (node >= N_NODES) return;
    int h = t & 127;
    const float* xr = x + node * IN_CH;
    float acc = 0.f;
#pragma unroll
    for (int c = 0; c < IN_CH; ++c) acc += xr[c] * w[c * HID + h];
    m[(size_t)node * HID + h] = acc * dinv[node];
}

// ---------------- gather: h' = relu(dinv * (m[n] + sum m[src]) + b) ----------------
// one wave per node, lane holds float2 (128 ch); edge index load is wave-uniform
__global__ __launch_bounds__(256) void k_gather(const int* __restrict__ rowptr,
                                                const int* __restrict__ csr_src,
                                                const float* __restrict__ m,
                                                const float* __restrict__ bias,
                                                const float* __restrict__ dinv,
                                                float* __restrict__ outh) {
    int wave = (blockIdx.x * 256 + threadIdx.x) >> 6;
    if (wave >= N_NODES) return;
    int n = wave;
    int c = (threadIdx.x & 63) * 2;
    int beg = rowptr[n], end = rowptr[n + 1];
    float2 acc = *(const float2*)&m[(size_t)n * HID + c];  // self-loop term
    int e = beg;
    for (; e + 4 <= end; e += 4) {
        int s0 = csr_src[e], s1 = csr_src[e + 1], s2 = csr_src[e + 2], s3 = csr_src[e + 3];
        float2 v0 = *(const float2*)&m[(size_t)s0 * HID + c];
        float2 v1 = *(const float2*)&m[(size_t)s1 * HID + c];
        float2 v2 = *(const float2*)&m[(size_t)s2 * HID + c];
        float2 v3 = *(const float2*)&m[(size_t)s3 * HID + c];
        acc.x += v0.x; acc.y += v0.y;
        acc.x += v1.x; acc.y += v1.y;
        acc.x += v2.x; acc.y += v2.y;
        acc.x += v3.x; acc.y += v3.y;
    }
    for (; e < end; ++e) {
        int s = csr_src[e];
        float2 v = *(const float2*)&m[(size_t)s * HID + c];
        acc.x += v.x; acc.y += v.y;
    }
    float dv = dinv[n];
    float2 b = *(const float2*)&bias[c];
    float2 r;
    r.x = fmaxf(acc.x * dv + b.x, 0.f);
    r.y = fmaxf(acc.y * dv + b.y, 0.f);
    *(float2*)&outh[(size_t)n * HID + c] = r;
}

// ---------------- layer-2 transform: m = (H @ W2) * dinv ----------------
#define NT2 32
__global__ __launch_bounds__(256) void k_xform2(const float* __restrict__ H,
                                                const float* __restrict__ W2,
                                                const float* __restrict__ dinv,
                                                float* __restrict__ m) {
    __shared__ float ws[HID * HID];       // [k][col], 64 KB
    __shared__ float hs[NT2][HID + 1];    // padded, 16.5 KB
    int t = threadIdx.x;
    for (int i = t; i < HID * HID / 4; i += 256)
        ((float4*)ws)[i] = ((const float4*)W2)[i];
    int n0 = blockIdx.x * NT2;
    for (int i = t; i < NT2 * HID / 4; i += 256) {
        int r = i >> 5;
        int c = (i & 31) * 4;
        float4 v = *(const float4*)&H[(size_t)(n0 + r) * HID + c];
        hs[r][c] = v.x; hs[r][c + 1] = v.y; hs[r][c + 2] = v.z; hs[r][c + 3] = v.w;
    }
    __syncthreads();
    int c0 = (t & 31) * 4;
    int r0 = (t >> 5) * 4;
    float acc[4][4];
#pragma unroll
    for (int j = 0; j < 4; ++j)
#pragma unroll
        for (int q = 0; q < 4; ++q) acc[j][q] = 0.f;
    for (int k = 0; k < HID; ++k) {
        float4 wv = *(const float4*)&ws[k * HID + c0];
        float h0 = hs[r0][k], h1 = hs[r0 + 1][k], h2 = hs[r0 + 2][k], h3 = hs[r0 + 3][k];
        acc[0][0] += h0 * wv.x; acc[0][1] += h0 * wv.y; acc[0][2] += h0 * wv.z; acc[0][3] += h0 * wv.w;
        acc[1][0] += h1 * wv.x; acc[1][1] += h1 * wv.y; acc[1][2] += h1 * wv.z; acc[1][3] += h1 * wv.w;
        acc[2][0] += h2 * wv.x; acc[2][1] += h2 * wv.y; acc[2][2] += h2 * wv.z; acc[2][3] += h2 * wv.w;
        acc[3][0] += h3 * wv.x; acc[3][1] += h3 * wv.y; acc[3][2] += h3 * wv.z; acc[3][3] += h3 * wv.w;
    }
#pragma unroll
    for (int j = 0; j < 4; ++j) {
        int nn = n0 + r0 + j;
        float dv = dinv[nn];
        float4 v = make_float4(acc[j][0] * dv, acc[j][1] * dv, acc[j][2] * dv, acc[j][3] * dv);
        *(float4*)&m[(size_t)nn * HID + c0] = v;
    }
}

// ---------------- node count per graph ----------------
__global__ __launch_bounds__(256) void k_cnt(const int* __restrict__ batch,
                                             int* __restrict__ cnt) {
    int n = blockIdx.x * 256 + threadIdx.x;
    if (n < N_NODES) atomicAdd(&cnt[batch[n]], 1);
}

// ---------------- pooled sums: run-length accumulate (batch sorted) ----------------
#define POOL_CHUNK 512
__global__ __launch_bounds__(256) void k_pool(const float* __restrict__ h,
                                              const int* __restrict__ batch,
                                              float* __restrict__ pooled) {
    int t = threadIdx.x;
    int c = t & 127, half = t >> 7;
    int start = blockIdx.x * POOL_CHUNK;
    int end = min(start + POOL_CHUNK, N_NODES);
    float acc = 0.f;
    int cur = -1;
    for (int n = start + half; n < end; n += 2) {
        int g = batch[n];
        if (g != cur) {
            if (cur >= 0) atomicAdd(&pooled[cur * HID + c], acc);
            acc = 0.f;
            cur = g;
        }
        acc += h[(size_t)n * HID + c];
    }
    if (cur >= 0) atomicAdd(&pooled[cur * HID + c], acc);
}

// ---------------- final: out = (pooled/cnt) @ Wf + bf ----------------
__global__ __launch_bounds__(128) void k_final(const float* __restrict__ pooled,
                                               const int* __restrict__ cnt,
                                               const float* __restrict__ Wf,
                                               const float* __restrict__ bf,
                                               float* __restrict__ out) {
    __shared__ float p[HID];
    int g = blockIdx.x, t = threadIdx.x;
    float inv = 1.f / fmaxf((float)cnt[g], 1.f);
    p[t] = pooled[g * HID + t] * inv;
    __syncthreads();
    if (t < NCLS) {
        float acc = bf[t];
        for (int k = 0; k < HID; ++k) acc += p[k] * Wf[k * NCLS + t];
        out[g * NCLS + t] = acc;
    }
}

extern "C" void kernel_launch(void* const* d_in, const int* in_sizes, int n_in,
                              void* d_out, int out_size, void* d_ws, size_t ws_size,
                              hipStream_t stream) {
    const float* x   = (const float*)d_in[0];
    const int*   ei  = (const int*)d_in[1];   // [2][E] flat
    const int*   src = ei;
    const int*   dst = ei + N_EDGES;
    const int*   batch = (const int*)d_in[2];
    const float* W1 = (const float*)d_in[3];
    const float* b1 = (const float*)d_in[4];
    const float* W2 = (const float*)d_in[5];
    const float* b2 = (const float*)d_in[6];
    const float* Wf = (const float*)d_in[7];
    const float* bf = (const float*)d_in[8];
    float* out = (float*)d_out;

    char* ws = (char*)d_ws;
    size_t off = 0;
    float* bufA = (float*)(ws + off);   off += (size_t)N_NODES * HID * 4;   // 51.2 MB
    float* bufB = (float*)(ws + off);   off += (size_t)N_NODES * HID * 4;   // 51.2 MB
    int* csr_src = (int*)(ws + off);    off += (size_t)N_EDGES * 4;         // 6.4 MB
    int* deg = (int*)(ws + off);        off += (size_t)N_NODES * 4;
    float* dinv = (float*)(ws + off);   off += (size_t)N_NODES * 4;
    int* rowptr = (int*)(ws + off);     off += (size_t)(N_NODES + 1) * 4;
    int* cursor = (int*)(ws + off);     off += (size_t)N_NODES * 4;
    float* pooled = (float*)(ws + off); off += (size_t)N_GRAPHS * HID * 4;
    int* cnt = (int*)(ws + off);        off += (size_t)N_GRAPHS * 4;

    // graph preprocessing: degree, dinv, CSR by dst
    k_init<<<(N_NODES + 255) / 256, 256, 0, stream>>>(deg, pooled, cnt);
    k_deg<<<(N_EDGES + 255) / 256, 256, 0, stream>>>(dst, deg);
    k_dinv<<<(N_NODES + 255) / 256, 256, 0, stream>>>(deg, dinv);
    k_scan<<<1, SCAN_T, 0, stream>>>(deg, rowptr, cursor);
    k_fill<<<(N_EDGES + 255) / 256, 256, 0, stream>>>(src, dst, cursor, csr_src);

    // layer 1
    k_xform1<<<N_NODES / 2, 256, 0, stream>>>(x, W1, dinv, bufA);
    k_gather<<<(N_NODES + 3) / 4, 256, 0, stream>>>(rowptr, csr_src, bufA, b1, dinv, bufB);

    // layer 2
    k_xform2<<<N_NODES / NT2, 256, 0, stream>>>(bufB, W2, dinv, bufA);
    k_gather<<<(N_NODES + 3) / 4, 256, 0, stream>>>(rowptr, csr_src, bufA, b2, dinv, bufB);

    // pooling + classifier
    k_cnt<<<(N_NODES + 255) / 256, 256, 0, stream>>>(batch, cnt);
    k_pool<<<(N_NODES + POOL_CHUNK - 1) / POOL_CHUNK, 256, 0, stream>>>(bufB, batch, pooled);
    k_final<<<N_GRAPHS, 128, 0, stream>>>(pooled, cnt, Wf, bf, out);
}

// Round 3
// 958.784 us; speedup vs baseline: 3.6583x; 1.5268x over previous
//
#include <hip/hip_runtime.h>

#define N_NODES 100000
#define N_EDGES 1600000
#define N_GRAPHS 64
#define IN_CH 15
#define HID 128
#define NCLS 11

// ---------------- init: deg=0, pooled=0 ----------------
__global__ __launch_bounds__(256) void k_init(int* __restrict__ deg,
                                              float* __restrict__ pooled) {
    int i = blockIdx.x * 256 + threadIdx.x;
    if (i < N_NODES) deg[i] = 0;
    if (i < N_GRAPHS * HID) pooled[i] = 0.f;
}

// ---------------- in-degree count over dst (int atomics, scattered -> cheap) ----------------
__global__ __launch_bounds__(256) void k_deg(const int* __restrict__ dst,
                                             int* __restrict__ deg) {
    int e = blockIdx.x * 256 + threadIdx.x;
    if (e < N_EDGES) atomicAdd(&deg[dst[e]], 1);
}

__global__ __launch_bounds__(256) void k_dinv(const int* __restrict__ deg,
                                              float* __restrict__ dinv) {
    int i = blockIdx.x * 256 + threadIdx.x;
    if (i < N_NODES) dinv[i] = rsqrtf((float)(deg[i] + 1));  // +1 self-loop
}

// ---------------- exclusive scan of deg -> rowptr, cursor (1 block) ----------------
#define SCAN_T 1024
#define SCAN_C 98  // ceil(100000/1024)
__global__ __launch_bounds__(SCAN_T) void k_scan(const int* __restrict__ deg,
                                                 int* __restrict__ rowptr,
                                                 int* __restrict__ cursor) {
    __shared__ int partial[SCAN_T];
    int t = threadIdx.x;
    int start = t * SCAN_C;
    int s = 0;
    for (int i = 0; i < SCAN_C; ++i) {
        int idx = start + i;
        if (idx < N_NODES) s += deg[idx];
    }
    partial[t] = s;
    __syncthreads();
    // Hillis-Steele inclusive scan
    for (int off = 1; off < SCAN_T; off <<= 1) {
        int v = (t >= off) ? partial[t - off] : 0;
        __syncthreads();
        partial[t] += v;
        __syncthreads();
    }
    int run = (t == 0) ? 0 : partial[t - 1];
    for (int i = 0; i < SCAN_C; ++i) {
        int idx = start + i;
        if (idx < N_NODES) {
            int d = deg[idx];
            rowptr[idx] = run;
            cursor[idx] = run;
            run += d;
        }
    }
    if (t == SCAN_T - 1) rowptr[N_NODES] = run;
}

// ---------------- fill CSR: csr_src grouped by dst ----------------
__global__ __launch_bounds__(256) void k_fill(const int* __restrict__ src,
                                              const int* __restrict__ dst,
                                              int* __restrict__ cursor,
                                              int* __restrict__ csr_src) {
    int e = blockIdx.x * 256 + threadIdx.x;
    if (e < N_EDGES) {
        int pos = atomicAdd(&cursor[dst[e]], 1);
        csr_src[pos] = src[e];
    }
}

// ---------------- layer-1 transform: m = (x @ W1) * dinv ----------------
__global__ __launch_bounds__(256) void k_xform1(const float* __restrict__ x,
                                                const float* __restrict__ W1,
                                                const float* __restrict__ dinv,
                                                float* __restrict__ m) {
    __shared__ float w[IN_CH * HID];  // 7.5 KB
    int t = threadIdx.x;
    for (int i = t; i < IN_CH * HID; i += 256) w[i] = W1[i];
    __syncthreads();
    int node = blockIdx.x * 2 + (t >> 7);
    if (node >= N_NODES) return;
    int h = t & 127;
    const float* xr = x + node * IN_CH;
    float acc = 0.f;
#pragma unroll
    for (int c = 0; c < IN_CH; ++c) acc += xr[c] * w[c * HID + h];
    m[(size_t)node * HID + h] = acc * dinv[node];
}

// ---------------- gather: h' = relu(dinv * (m[n] + sum m[src]) + b) ----------------
// one wave per node, lane holds float2 (128 ch); edge index load is wave-uniform
__global__ __launch_bounds__(256) void k_gather(const int* __restrict__ rowptr,
                                                const int* __restrict__ csr_src,
                                                const float* __restrict__ m,
                                                const float* __restrict__ bias,
                                                const float* __restrict__ dinv,
                                                float* __restrict__ outh) {
    int wave = (blockIdx.x * 256 + threadIdx.x) >> 6;
    if (wave >= N_NODES) return;
    int n = wave;
    int c = (threadIdx.x & 63) * 2;
    int beg = rowptr[n], end = rowptr[n + 1];
    float2 acc = *(const float2*)&m[(size_t)n * HID + c];  // self-loop term
    int e = beg;
    for (; e + 4 <= end; e += 4) {
        int s0 = csr_src[e], s1 = csr_src[e + 1], s2 = csr_src[e + 2], s3 = csr_src[e + 3];
        float2 v0 = *(const float2*)&m[(size_t)s0 * HID + c];
        float2 v1 = *(const float2*)&m[(size_t)s1 * HID + c];
        float2 v2 = *(const float2*)&m[(size_t)s2 * HID + c];
        float2 v3 = *(const float2*)&m[(size_t)s3 * HID + c];
        acc.x += v0.x; acc.y += v0.y;
        acc.x += v1.x; acc.y += v1.y;
        acc.x += v2.x; acc.y += v2.y;
        acc.x += v3.x; acc.y += v3.y;
    }
    for (; e < end; ++e) {
        int s = csr_src[e];
        float2 v = *(const float2*)&m[(size_t)s * HID + c];
        acc.x += v.x; acc.y += v.y;
    }
    float dv = dinv[n];
    float2 b = *(const float2*)&bias[c];
    float2 r;
    r.x = fmaxf(acc.x * dv + b.x, 0.f);
    r.y = fmaxf(acc.y * dv + b.y, 0.f);
    *(float2*)&outh[(size_t)n * HID + c] = r;
}

// ---------------- layer-2 transform: m = (H @ W2) * dinv ----------------
#define NT2 32
__global__ __launch_bounds__(256) void k_xform2(const float* __restrict__ H,
                                                const float* __restrict__ W2,
                                                const float* __restrict__ dinv,
                                                float* __restrict__ m) {
    __shared__ float ws[HID * HID];       // [k][col], 64 KB
    __shared__ float hs[NT2][HID + 1];    // padded, 16.5 KB
    int t = threadIdx.x;
    for (int i = t; i < HID * HID / 4; i += 256)
        ((float4*)ws)[i] = ((const float4*)W2)[i];
    int n0 = blockIdx.x * NT2;
    for (int i = t; i < NT2 * HID / 4; i += 256) {
        int r = i >> 5;
        int c = (i & 31) * 4;
        float4 v = *(const float4*)&H[(size_t)(n0 + r) * HID + c];
        hs[r][c] = v.x; hs[r][c + 1] = v.y; hs[r][c + 2] = v.z; hs[r][c + 3] = v.w;
    }
    __syncthreads();
    int c0 = (t & 31) * 4;
    int r0 = (t >> 5) * 4;
    float acc[4][4];
#pragma unroll
    for (int j = 0; j < 4; ++j)
#pragma unroll
        for (int q = 0; q < 4; ++q) acc[j][q] = 0.f;
    for (int k = 0; k < HID; ++k) {
        float4 wv = *(const float4*)&ws[k * HID + c0];
        float h0 = hs[r0][k], h1 = hs[r0 + 1][k], h2 = hs[r0 + 2][k], h3 = hs[r0 + 3][k];
        acc[0][0] += h0 * wv.x; acc[0][1] += h0 * wv.y; acc[0][2] += h0 * wv.z; acc[0][3] += h0 * wv.w;
        acc[1][0] += h1 * wv.x; acc[1][1] += h1 * wv.y; acc[1][2] += h1 * wv.z; acc[1][3] += h1 * wv.w;
        acc[2][0] += h2 * wv.x; acc[2][1] += h2 * wv.y; acc[2][2] += h2 * wv.z; acc[2][3] += h2 * wv.w;
        acc[3][0] += h3 * wv.x; acc[3][1] += h3 * wv.y; acc[3][2] += h3 * wv.z; acc[3][3] += h3 * wv.w;
    }
#pragma unroll
    for (int j = 0; j < 4; ++j) {
        int nn = n0 + r0 + j;
        float dv = dinv[nn];
        float4 v = make_float4(acc[j][0] * dv, acc[j][1] * dv, acc[j][2] * dv, acc[j][3] * dv);
        *(float4*)&m[(size_t)nn * HID + c0] = v;
    }
}

// ---------------- node count per graph: binary search on sorted batch ----------------
// replaces 100k same-address atomics (was 497 us of pure contention) with
// 64 threads x 2 binary searches over the sorted batch array.
__global__ __launch_bounds__(64) void k_cnt(const int* __restrict__ batch,
                                            int* __restrict__ cnt) {
    int g = threadIdx.x;
    if (g >= N_GRAPHS) return;
    // lower_bound(batch, g) and lower_bound(batch, g+1)
    int lo0 = 0, hi0 = N_NODES;
    while (lo0 < hi0) { int mid = (lo0 + hi0) >> 1; if (batch[mid] < g) lo0 = mid + 1; else hi0 = mid; }
    int lo1 = lo0, hi1 = N_NODES;
    while (lo1 < hi1) { int mid = (lo1 + hi1) >> 1; if (batch[mid] < g + 1) lo1 = mid + 1; else hi1 = mid; }
    cnt[g] = lo1 - lo0;
}

// ---------------- pooled sums: run-length accumulate (batch sorted) ----------------
#define POOL_CHUNK 512
__global__ __launch_bounds__(256) void k_pool(const float* __restrict__ h,
                                              const int* __restrict__ batch,
                                              float* __restrict__ pooled) {
    int t = threadIdx.x;
    int c = t & 127, half = t >> 7;
    int start = blockIdx.x * POOL_CHUNK;
    int end = min(start + POOL_CHUNK, N_NODES);
    float acc = 0.f;
    int cur = -1;
    for (int n = start + half; n < end; n += 2) {
        int g = batch[n];
        if (g != cur) {
            if (cur >= 0) atomicAdd(&pooled[cur * HID + c], acc);
            acc = 0.f;
            cur = g;
        }
        acc += h[(size_t)n * HID + c];
    }
    if (cur >= 0) atomicAdd(&pooled[cur * HID + c], acc);
}

// ---------------- final: out = (pooled/cnt) @ Wf + bf ----------------
__global__ __launch_bounds__(128) void k_final(const float* __restrict__ pooled,
                                               const int* __restrict__ cnt,
                                               const float* __restrict__ Wf,
                                               const float* __restrict__ bf,
                                               float* __restrict__ out) {
    __shared__ float p[HID];
    int g = blockIdx.x, t = threadIdx.x;
    float inv = 1.f / fmaxf((float)cnt[g], 1.f);
    p[t] = pooled[g * HID + t] * inv;
    __syncthreads();
    if (t < NCLS) {
        float acc = bf[t];
        for (int k = 0; k < HID; ++k) acc += p[k] * Wf[k * NCLS + t];
        out[g * NCLS + t] = acc;
    }
}

extern "C" void kernel_launch(void* const* d_in, const int* in_sizes, int n_in,
                              void* d_out, int out_size, void* d_ws, size_t ws_size,
                              hipStream_t stream) {
    const float* x   = (const float*)d_in[0];
    const int*   ei  = (const int*)d_in[1];   // [2][E] flat
    const int*   src = ei;
    const int*   dst = ei + N_EDGES;
    const int*   batch = (const int*)d_in[2];
    const float* W1 = (const float*)d_in[3];
    const float* b1 = (const float*)d_in[4];
    const float* W2 = (const float*)d_in[5];
    const float* b2 = (const float*)d_in[6];
    const float* Wf = (const float*)d_in[7];
    const float* bf = (const float*)d_in[8];
    float* out = (float*)d_out;

    char* ws = (char*)d_ws;
    size_t off = 0;
    float* bufA = (float*)(ws + off);   off += (size_t)N_NODES * HID * 4;   // 51.2 MB
    float* bufB = (float*)(ws + off);   off += (size_t)N_NODES * HID * 4;   // 51.2 MB
    int* csr_src = (int*)(ws + off);    off += (size_t)N_EDGES * 4;         // 6.4 MB
    int* deg = (int*)(ws + off);        off += (size_t)N_NODES * 4;
    float* dinv = (float*)(ws + off);   off += (size_t)N_NODES * 4;
    int* rowptr = (int*)(ws + off);     off += (size_t)(N_NODES + 1) * 4;
    int* cursor = (int*)(ws + off);     off += (size_t)N_NODES * 4;
    float* pooled = (float*)(ws + off); off += (size_t)N_GRAPHS * HID * 4;
    int* cnt = (int*)(ws + off);        off += (size_t)N_GRAPHS * 4;

    // graph preprocessing: degree, dinv, CSR by dst
    k_init<<<(N_NODES + 255) / 256, 256, 0, stream>>>(deg, pooled);
    k_deg<<<(N_EDGES + 255) / 256, 256, 0, stream>>>(dst, deg);
    k_dinv<<<(N_NODES + 255) / 256, 256, 0, stream>>>(deg, dinv);
    k_scan<<<1, SCAN_T, 0, stream>>>(deg, rowptr, cursor);
    k_fill<<<(N_EDGES + 255) / 256, 256, 0, stream>>>(src, dst, cursor, csr_src);

    // layer 1
    k_xform1<<<N_NODES / 2, 256, 0, stream>>>(x, W1, dinv, bufA);
    k_gather<<<(N_NODES + 3) / 4, 256, 0, stream>>>(rowptr, csr_src, bufA, b1, dinv, bufB);

    // layer 2
    k_xform2<<<N_NODES / NT2, 256, 0, stream>>>(bufB, W2, dinv, bufA);
    k_gather<<<(N_NODES + 3) / 4, 256, 0, stream>>>(rowptr, csr_src, bufA, b2, dinv, bufB);

    // pooling + classifier
    k_cnt<<<1, 64, 0, stream>>>(batch, cnt);
    k_pool<<<(N_NODES + POOL_CHUNK - 1) / POOL_CHUNK, 256, 0, stream>>>(bufB, batch, pooled);
    k_final<<<N_GRAPHS, 128, 0, stream>>>(pooled, cnt, Wf, bf, out);
}

// Round 4
// 713.570 us; speedup vs baseline: 4.9155x; 1.3436x over previous
//
#include <hip/hip_runtime.h>

#define N_NODES 100000
#define N_EDGES 1600000
#define N_GRAPHS 64
#define IN_CH 15
#define HID 128
#define NCLS 11

// ---------------- init: deg=0, pooled=0 ----------------
__global__ __launch_bounds__(256) void k_init(int* __restrict__ deg,
                                              float* __restrict__ pooled) {
    int i = blockIdx.x * 256 + threadIdx.x;
    if (i < N_NODES) deg[i] = 0;
    if (i < N_GRAPHS * HID) pooled[i] = 0.f;
}

// ---------------- in-degree count over dst (int atomics, scattered -> cheap) ----------------
__global__ __launch_bounds__(256) void k_deg(const int* __restrict__ dst,
                                             int* __restrict__ deg) {
    int e = blockIdx.x * 256 + threadIdx.x;
    if (e < N_EDGES) atomicAdd(&deg[dst[e]], 1);
}

__global__ __launch_bounds__(256) void k_dinv(const int* __restrict__ deg,
                                              float* __restrict__ dinv) {
    int i = blockIdx.x * 256 + threadIdx.x;
    if (i < N_NODES) dinv[i] = rsqrtf((float)(deg[i] + 1));  // +1 self-loop
}

// ---------------- multi-block exclusive scan of deg -> rowptr, cursor ----------------
// pass 1: per-block (1024 elems) reduce
#define SCAN_BLK 1024
#define SCAN_NB ((N_NODES + SCAN_BLK - 1) / SCAN_BLK)  // 98
__global__ __launch_bounds__(256) void k_part(const int* __restrict__ deg,
                                              int* __restrict__ partials) {
    __shared__ int red[256];
    int t = threadIdx.x;
    int base = blockIdx.x * SCAN_BLK + t * 4;
    int s = 0;
#pragma unroll
    for (int i = 0; i < 4; ++i) {
        int idx = base + i;
        if (idx < N_NODES) s += deg[idx];
    }
    red[t] = s;
    __syncthreads();
    for (int off = 128; off > 0; off >>= 1) {
        if (t < off) red[t] += red[t + off];
        __syncthreads();
    }
    if (t == 0) partials[blockIdx.x] = red[0];
}

// pass 2: scan the 98 partials (1 tiny block); also rowptr[N] = E (all dst in range)
__global__ __launch_bounds__(128) void k_scanblk(const int* __restrict__ partials,
                                                 int* __restrict__ blockoff,
                                                 int* __restrict__ rowptr) {
    __shared__ int arr[128];
    int t = threadIdx.x;
    arr[t] = (t < SCAN_NB) ? partials[t] : 0;
    __syncthreads();
    for (int off = 1; off < 128; off <<= 1) {
        int v = (t >= off) ? arr[t - off] : 0;
        __syncthreads();
        arr[t] += v;
        __syncthreads();
    }
    if (t < SCAN_NB) blockoff[t] = (t == 0) ? 0 : arr[t - 1];
    if (t == 0) rowptr[N_NODES] = N_EDGES;
}

// pass 3: in-block exclusive scan + global offset -> rowptr, cursor
__global__ __launch_bounds__(256) void k_apply(const int* __restrict__ deg,
                                               const int* __restrict__ blockoff,
                                               int* __restrict__ rowptr,
                                               int* __restrict__ cursor) {
    __shared__ int arr[256];
    int t = threadIdx.x;
    int base = blockIdx.x * SCAN_BLK + t * 4;
    int d[4];
    int s = 0;
#pragma unroll
    for (int i = 0; i < 4; ++i) {
        int idx = base + i;
        d[i] = (idx < N_NODES) ? deg[idx] : 0;
        s += d[i];
    }
    arr[t] = s;
    __syncthreads();
    for (int off = 1; off < 256; off <<= 1) {
        int v = (t >= off) ? arr[t - off] : 0;
        __syncthreads();
        arr[t] += v;
        __syncthreads();
    }
    int run = blockoff[blockIdx.x] + ((t == 0) ? 0 : arr[t - 1]);
#pragma unroll
    for (int i = 0; i < 4; ++i) {
        int idx = base + i;
        if (idx < N_NODES) {
            rowptr[idx] = run;
            cursor[idx] = run;
            run += d[i];
        }
    }
}

// ---------------- fill CSR: csr_src grouped by dst ----------------
__global__ __launch_bounds__(256) void k_fill(const int* __restrict__ src,
                                              const int* __restrict__ dst,
                                              int* __restrict__ cursor,
                                              int* __restrict__ csr_src) {
    int e = blockIdx.x * 256 + threadIdx.x;
    if (e < N_EDGES) {
        int pos = atomicAdd(&cursor[dst[e]], 1);
        csr_src[pos] = src[e];
    }
}

// ---------------- layer-1 transform: m = (x @ W1) * dinv ----------------
__global__ __launch_bounds__(256) void k_xform1(const float* __restrict__ x,
                                                const float* __restrict__ W1,
                                                const float* __restrict__ dinv,
                                                float* __restrict__ m) {
    __shared__ float w[IN_CH * HID];  // 7.5 KB
    int t = threadIdx.x;
    for (int i = t; i < IN_CH * HID; i += 256) w[i] = W1[i];
    __syncthreads();
    int node = blockIdx.x * 2 + (t >> 7);
    if (node >= N_NODES) return;
    int h = t & 127;
    const float* xr = x + node * IN_CH;
    float acc = 0.f;
#pragma unroll
    for (int c = 0; c < IN_CH; ++c) acc += xr[c] * w[c * HID + h];
    m[(size_t)node * HID + h] = acc * dinv[node];
}

// ---------------- gather: h' = relu(dinv * (m[n] + sum m[src]) + b) ----------------
// one wave per node, lane holds float2 (128 ch); edge index load is wave-uniform
__global__ __launch_bounds__(256) void k_gather(const int* __restrict__ rowptr,
                                                const int* __restrict__ csr_src,
                                                const float* __restrict__ m,
                                                const float* __restrict__ bias,
                                                const float* __restrict__ dinv,
                                                float* __restrict__ outh) {
    int wave = (blockIdx.x * 256 + threadIdx.x) >> 6;
    if (wave >= N_NODES) return;
    int n = wave;
    int c = (threadIdx.x & 63) * 2;
    int beg = rowptr[n], end = rowptr[n + 1];
    float2 acc = *(const float2*)&m[(size_t)n * HID + c];  // self-loop term
    int e = beg;
    for (; e + 4 <= end; e += 4) {
        int s0 = csr_src[e], s1 = csr_src[e + 1], s2 = csr_src[e + 2], s3 = csr_src[e + 3];
        float2 v0 = *(const float2*)&m[(size_t)s0 * HID + c];
        float2 v1 = *(const float2*)&m[(size_t)s1 * HID + c];
        float2 v2 = *(const float2*)&m[(size_t)s2 * HID + c];
        float2 v3 = *(const float2*)&m[(size_t)s3 * HID + c];
        acc.x += v0.x; acc.y += v0.y;
        acc.x += v1.x; acc.y += v1.y;
        acc.x += v2.x; acc.y += v2.y;
        acc.x += v3.x; acc.y += v3.y;
    }
    for (; e < end; ++e) {
        int s = csr_src[e];
        float2 v = *(const float2*)&m[(size_t)s * HID + c];
        acc.x += v.x; acc.y += v.y;
    }
    float dv = dinv[n];
    float2 b = *(const float2*)&bias[c];
    float2 r;
    r.x = fmaxf(acc.x * dv + b.x, 0.f);
    r.y = fmaxf(acc.y * dv + b.y, 0.f);
    *(float2*)&outh[(size_t)n * HID + c] = r;
}

// ---------------- layer-2 transform: m = (H @ W2) * dinv ----------------
#define NT2 32
__global__ __launch_bounds__(256) void k_xform2(const float* __restrict__ H,
                                                const float* __restrict__ W2,
                                                const float* __restrict__ dinv,
                                                float* __restrict__ m) {
    __shared__ float ws[HID * HID];       // [k][col], 64 KB
    __shared__ float hs[NT2][HID + 1];    // padded, 16.5 KB
    int t = threadIdx.x;
    for (int i = t; i < HID * HID / 4; i += 256)
        ((float4*)ws)[i] = ((const float4*)W2)[i];
    int n0 = blockIdx.x * NT2;
    for (int i = t; i < NT2 * HID / 4; i += 256) {
        int r = i >> 5;
        int c = (i & 31) * 4;
        float4 v = *(const float4*)&H[(size_t)(n0 + r) * HID + c];
        hs[r][c] = v.x; hs[r][c + 1] = v.y; hs[r][c + 2] = v.z; hs[r][c + 3] = v.w;
    }
    __syncthreads();
    int c0 = (t & 31) * 4;
    int r0 = (t >> 5) * 4;
    float acc[4][4];
#pragma unroll
    for (int j = 0; j < 4; ++j)
#pragma unroll
        for (int q = 0; q < 4; ++q) acc[j][q] = 0.f;
    for (int k = 0; k < HID; ++k) {
        float4 wv = *(const float4*)&ws[k * HID + c0];
        float h0 = hs[r0][k], h1 = hs[r0 + 1][k], h2 = hs[r0 + 2][k], h3 = hs[r0 + 3][k];
        acc[0][0] += h0 * wv.x; acc[0][1] += h0 * wv.y; acc[0][2] += h0 * wv.z; acc[0][3] += h0 * wv.w;
        acc[1][0] += h1 * wv.x; acc[1][1] += h1 * wv.y; acc[1][2] += h1 * wv.z; acc[1][3] += h1 * wv.w;
        acc[2][0] += h2 * wv.x; acc[2][1] += h2 * wv.y; acc[2][2] += h2 * wv.z; acc[2][3] += h2 * wv.w;
        acc[3][0] += h3 * wv.x; acc[3][1] += h3 * wv.y; acc[3][2] += h3 * wv.z; acc[3][3] += h3 * wv.w;
    }
#pragma unroll
    for (int j = 0; j < 4; ++j) {
        int nn = n0 + r0 + j;
        float dv = dinv[nn];
        float4 v = make_float4(acc[j][0] * dv, acc[j][1] * dv, acc[j][2] * dv, acc[j][3] * dv);
        *(float4*)&m[(size_t)nn * HID + c0] = v;
    }
}

// ---------------- node count per graph: binary search on sorted batch ----------------
__global__ __launch_bounds__(64) void k_cnt(const int* __restrict__ batch,
                                            int* __restrict__ cnt) {
    int g = threadIdx.x;
    if (g >= N_GRAPHS) return;
    int lo0 = 0, hi0 = N_NODES;
    while (lo0 < hi0) { int mid = (lo0 + hi0) >> 1; if (batch[mid] < g) lo0 = mid + 1; else hi0 = mid; }
    int lo1 = lo0, hi1 = N_NODES;
    while (lo1 < hi1) { int mid = (lo1 + hi1) >> 1; if (batch[mid] < g + 1) lo1 = mid + 1; else hi1 = mid; }
    cnt[g] = lo1 - lo0;
}

// ---------------- pooled sums: run-length accumulate (batch sorted) ----------------
#define POOL_CHUNK 512
__global__ __launch_bounds__(256) void k_pool(const float* __restrict__ h,
                                              const int* __restrict__ batch,
                                              float* __restrict__ pooled) {
    int t = threadIdx.x;
    int c = t & 127, half = t >> 7;
    int start = blockIdx.x * POOL_CHUNK;
    int end = min(start + POOL_CHUNK, N_NODES);
    float acc = 0.f;
    int cur = -1;
    for (int n = start + half; n < end; n += 2) {
        int g = batch[n];
        if (g != cur) {
            if (cur >= 0) atomicAdd(&pooled[cur * HID + c], acc);
            acc = 0.f;
            cur = g;
        }
        acc += h[(size_t)n * HID + c];
    }
    if (cur >= 0) atomicAdd(&pooled[cur * HID + c], acc);
}

// ---------------- final: out = (pooled/cnt) @ Wf + bf ----------------
__global__ __launch_bounds__(128) void k_final(const float* __restrict__ pooled,
                                               const int* __restrict__ cnt,
                                               const float* __restrict__ Wf,
                                               const float* __restrict__ bf,
                                               float* __restrict__ out) {
    __shared__ float p[HID];
    int g = blockIdx.x, t = threadIdx.x;
    float inv = 1.f / fmaxf((float)cnt[g], 1.f);
    p[t] = pooled[g * HID + t] * inv;
    __syncthreads();
    if (t < NCLS) {
        float acc = bf[t];
        for (int k = 0; k < HID; ++k) acc += p[k] * Wf[k * NCLS + t];
        out[g * NCLS + t] = acc;
    }
}

extern "C" void kernel_launch(void* const* d_in, const int* in_sizes, int n_in,
                              void* d_out, int out_size, void* d_ws, size_t ws_size,
                              hipStream_t stream) {
    const float* x   = (const float*)d_in[0];
    const int*   ei  = (const int*)d_in[1];   // [2][E] flat
    const int*   src = ei;
    const int*   dst = ei + N_EDGES;
    const int*   batch = (const int*)d_in[2];
    const float* W1 = (const float*)d_in[3];
    const float* b1 = (const float*)d_in[4];
    const float* W2 = (const float*)d_in[5];
    const float* b2 = (const float*)d_in[6];
    const float* Wf = (const float*)d_in[7];
    const float* bf = (const float*)d_in[8];
    float* out = (float*)d_out;

    char* ws = (char*)d_ws;
    size_t off = 0;
    float* bufA = (float*)(ws + off);   off += (size_t)N_NODES * HID * 4;   // 51.2 MB
    float* bufB = (float*)(ws + off);   off += (size_t)N_NODES * HID * 4;   // 51.2 MB
    int* csr_src = (int*)(ws + off);    off += (size_t)N_EDGES * 4;         // 6.4 MB
    int* deg = (int*)(ws + off);        off += (size_t)N_NODES * 4;
    float* dinv = (float*)(ws + off);   off += (size_t)N_NODES * 4;
    int* rowptr = (int*)(ws + off);     off += (size_t)(N_NODES + 1) * 4;
    int* cursor = (int*)(ws + off);     off += (size_t)N_NODES * 4;
    int* partials = (int*)(ws + off);   off += (size_t)SCAN_NB * 4;
    int* blockoff = (int*)(ws + off);   off += (size_t)SCAN_NB * 4;
    float* pooled = (float*)(ws + off); off += (size_t)N_GRAPHS * HID * 4;
    int* cnt = (int*)(ws + off);        off += (size_t)N_GRAPHS * 4;

    // graph preprocessing: degree, dinv, CSR by dst
    k_init<<<(N_NODES + 255) / 256, 256, 0, stream>>>(deg, pooled);
    k_deg<<<(N_EDGES + 255) / 256, 256, 0, stream>>>(dst, deg);
    k_dinv<<<(N_NODES + 255) / 256, 256, 0, stream>>>(deg, dinv);
    k_part<<<SCAN_NB, 256, 0, stream>>>(deg, partials);
    k_scanblk<<<1, 128, 0, stream>>>(partials, blockoff, rowptr);
    k_apply<<<SCAN_NB, 256, 0, stream>>>(deg, blockoff, rowptr, cursor);
    k_fill<<<(N_EDGES + 255) / 256, 256, 0, stream>>>(src, dst, cursor, csr_src);

    // layer 1
    k_xform1<<<N_NODES / 2, 256, 0, stream>>>(x, W1, dinv, bufA);
    k_gather<<<(N_NODES + 3) / 4, 256, 0, stream>>>(rowptr, csr_src, bufA, b1, dinv, bufB);

    // layer 2
    k_xform2<<<N_NODES / NT2, 256, 0, stream>>>(bufB, W2, dinv, bufA);
    k_gather<<<(N_NODES + 3) / 4, 256, 0, stream>>>(rowptr, csr_src, bufA, b2, dinv, bufB);

    // pooling + classifier
    k_cnt<<<1, 64, 0, stream>>>(batch, cnt);
    k_pool<<<(N_NODES + POOL_CHUNK - 1) / POOL_CHUNK, 256, 0, stream>>>(bufB, batch, pooled);
    k_final<<<N_GRAPHS, 128, 0, stream>>>(pooled, cnt, Wf, bf, out);
}

// Round 5
// 601.765 us; speedup vs baseline: 5.8288x; 1.1858x over previous
//
#include <hip/hip_runtime.h>

#define N_NODES 100000
#define N_EDGES 1600000
#define N_GRAPHS 64
#define IN_CH 15
#define HID 128
#define NCLS 11

// ---- bf16 pack/unpack (RNE) ----
__device__ __forceinline__ unsigned short f2bf(float f) {
    unsigned u = __builtin_bit_cast(unsigned, f);
    u += 0x7FFF + ((u >> 16) & 1);
    return (unsigned short)(u >> 16);
}
__device__ __forceinline__ unsigned packbf(float a, float b) {
    return (unsigned)f2bf(a) | ((unsigned)f2bf(b) << 16);
}
__device__ __forceinline__ float2 unpackbf(unsigned v) {
    float2 r;
    unsigned lo = v << 16;
    unsigned hi = v & 0xFFFF0000u;
    r.x = __builtin_bit_cast(float, lo);
    r.y = __builtin_bit_cast(float, hi);
    return r;
}

// ---------------- init: deg=0, pooled=0 ----------------
__global__ __launch_bounds__(256) void k_init(int* __restrict__ deg,
                                              float* __restrict__ pooled) {
    int i = blockIdx.x * 256 + threadIdx.x;
    if (i < N_NODES) deg[i] = 0;
    if (i < N_GRAPHS * HID) pooled[i] = 0.f;
}

// ---------------- in-degree count over dst ----------------
__global__ __launch_bounds__(256) void k_deg(const int* __restrict__ dst,
                                             int* __restrict__ deg) {
    int e = blockIdx.x * 256 + threadIdx.x;
    if (e < N_EDGES) atomicAdd(&deg[dst[e]], 1);
}

__global__ __launch_bounds__(256) void k_dinv(const int* __restrict__ deg,
                                              float* __restrict__ dinv) {
    int i = blockIdx.x * 256 + threadIdx.x;
    if (i < N_NODES) dinv[i] = rsqrtf((float)(deg[i] + 1));  // +1 self-loop
}

// ---------------- multi-block exclusive scan of deg -> rowptr, cursor ----------------
#define SCAN_BLK 1024
#define SCAN_NB ((N_NODES + SCAN_BLK - 1) / SCAN_BLK)  // 98
__global__ __launch_bounds__(256) void k_part(const int* __restrict__ deg,
                                              int* __restrict__ partials) {
    __shared__ int red[256];
    int t = threadIdx.x;
    int base = blockIdx.x * SCAN_BLK + t * 4;
    int s = 0;
#pragma unroll
    for (int i = 0; i < 4; ++i) {
        int idx = base + i;
        if (idx < N_NODES) s += deg[idx];
    }
    red[t] = s;
    __syncthreads();
    for (int off = 128; off > 0; off >>= 1) {
        if (t < off) red[t] += red[t + off];
        __syncthreads();
    }
    if (t == 0) partials[blockIdx.x] = red[0];
}

__global__ __launch_bounds__(128) void k_scanblk(const int* __restrict__ partials,
                                                 int* __restrict__ blockoff,
                                                 int* __restrict__ rowptr) {
    __shared__ int arr[128];
    int t = threadIdx.x;
    arr[t] = (t < SCAN_NB) ? partials[t] : 0;
    __syncthreads();
    for (int off = 1; off < 128; off <<= 1) {
        int v = (t >= off) ? arr[t - off] : 0;
        __syncthreads();
        arr[t] += v;
        __syncthreads();
    }
    if (t < SCAN_NB) blockoff[t] = (t == 0) ? 0 : arr[t - 1];
    if (t == 0) rowptr[N_NODES] = N_EDGES;
}

__global__ __launch_bounds__(256) void k_apply(const int* __restrict__ deg,
                                               const int* __restrict__ blockoff,
                                               int* __restrict__ rowptr,
                                               int* __restrict__ cursor) {
    __shared__ int arr[256];
    int t = threadIdx.x;
    int base = blockIdx.x * SCAN_BLK + t * 4;
    int d[4];
    int s = 0;
#pragma unroll
    for (int i = 0; i < 4; ++i) {
        int idx = base + i;
        d[i] = (idx < N_NODES) ? deg[idx] : 0;
        s += d[i];
    }
    arr[t] = s;
    __syncthreads();
    for (int off = 1; off < 256; off <<= 1) {
        int v = (t >= off) ? arr[t - off] : 0;
        __syncthreads();
        arr[t] += v;
        __syncthreads();
    }
    int run = blockoff[blockIdx.x] + ((t == 0) ? 0 : arr[t - 1]);
#pragma unroll
    for (int i = 0; i < 4; ++i) {
        int idx = base + i;
        if (idx < N_NODES) {
            rowptr[idx] = run;
            cursor[idx] = run;
            run += d[i];
        }
    }
}

// ---------------- fill CSR: csr_src grouped by dst ----------------
__global__ __launch_bounds__(256) void k_fill(const int* __restrict__ src,
                                              const int* __restrict__ dst,
                                              int* __restrict__ cursor,
                                              int* __restrict__ csr_src) {
    int e = blockIdx.x * 256 + threadIdx.x;
    if (e < N_EDGES) {
        int pos = atomicAdd(&cursor[dst[e]], 1);
        csr_src[pos] = src[e];
    }
}

// ---------------- layer-1 transform: m = bf16((x @ W1) * dinv) ----------------
// 64 threads per node (2 channels each), 4 nodes per block
__global__ __launch_bounds__(256) void k_xform1(const float* __restrict__ x,
                                                const float* __restrict__ W1,
                                                const float* __restrict__ dinv,
                                                unsigned* __restrict__ m) {
    __shared__ float w[IN_CH * HID];  // 7.5 KB
    int t = threadIdx.x;
    for (int i = t; i < IN_CH * HID; i += 256) w[i] = W1[i];
    __syncthreads();
    int node = blockIdx.x * 4 + (t >> 6);
    int lane = t & 63;
    int c = lane * 2;
    const float* xr = x + node * IN_CH;
    float a0 = 0.f, a1 = 0.f;
#pragma unroll
    for (int k = 0; k < IN_CH; ++k) {
        float xv = xr[k];
        a0 += xv * w[k * HID + c];
        a1 += xv * w[k * HID + c + 1];
    }
    float dv = dinv[node];
    m[(size_t)node * 64 + lane] = packbf(a0 * dv, a1 * dv);
}

// ---------------- gather: h' = relu(dinv * (m[n] + sum m[src]) + b) ----------------
// one wave per node; lane holds one packed uint (2 bf16 ch); f32 accumulate
__global__ __launch_bounds__(256) void k_gather(const int* __restrict__ rowptr,
                                                const int* __restrict__ csr_src,
                                                const unsigned* __restrict__ m,
                                                const float* __restrict__ bias,
                                                const float* __restrict__ dinv,
                                                float* __restrict__ outh) {
    int wave = (blockIdx.x * 256 + threadIdx.x) >> 6;
    if (wave >= N_NODES) return;
    int n = wave;
    int lane = threadIdx.x & 63;
    int c = lane * 2;
    int beg = rowptr[n], end = rowptr[n + 1];
    float2 acc = unpackbf(m[(size_t)n * 64 + lane]);  // self-loop term
    int e = beg;
    for (; e + 4 <= end; e += 4) {
        int s0 = csr_src[e], s1 = csr_src[e + 1], s2 = csr_src[e + 2], s3 = csr_src[e + 3];
        float2 v0 = unpackbf(m[(size_t)s0 * 64 + lane]);
        float2 v1 = unpackbf(m[(size_t)s1 * 64 + lane]);
        float2 v2 = unpackbf(m[(size_t)s2 * 64 + lane]);
        float2 v3 = unpackbf(m[(size_t)s3 * 64 + lane]);
        acc.x += v0.x; acc.y += v0.y;
        acc.x += v1.x; acc.y += v1.y;
        acc.x += v2.x; acc.y += v2.y;
        acc.x += v3.x; acc.y += v3.y;
    }
    for (; e < end; ++e) {
        int s = csr_src[e];
        float2 v = unpackbf(m[(size_t)s * 64 + lane]);
        acc.x += v.x; acc.y += v.y;
    }
    float dv = dinv[n];
    float2 b = *(const float2*)&bias[c];
    float2 r;
    r.x = fmaxf(acc.x * dv + b.x, 0.f);
    r.y = fmaxf(acc.y * dv + b.y, 0.f);
    *(float2*)&outh[(size_t)n * HID + c] = r;
}

// ---------------- layer-2 transform: m = bf16((H @ W2) * dinv) ----------------
#define NT2 32
__global__ __launch_bounds__(256) void k_xform2(const float* __restrict__ H,
                                                const float* __restrict__ W2,
                                                const float* __restrict__ dinv,
                                                unsigned* __restrict__ m) {
    __shared__ float ws[HID * HID];       // [k][col], 64 KB
    __shared__ float hs[NT2][HID + 1];    // padded, 16.5 KB
    int t = threadIdx.x;
    for (int i = t; i < HID * HID / 4; i += 256)
        ((float4*)ws)[i] = ((const float4*)W2)[i];
    int n0 = blockIdx.x * NT2;
    for (int i = t; i < NT2 * HID / 4; i += 256) {
        int r = i >> 5;
        int c = (i & 31) * 4;
        float4 v = *(const float4*)&H[(size_t)(n0 + r) * HID + c];
        hs[r][c] = v.x; hs[r][c + 1] = v.y; hs[r][c + 2] = v.z; hs[r][c + 3] = v.w;
    }
    __syncthreads();
    int c0 = (t & 31) * 4;
    int r0 = (t >> 5) * 4;
    float acc[4][4];
#pragma unroll
    for (int j = 0; j < 4; ++j)
#pragma unroll
        for (int q = 0; q < 4; ++q) acc[j][q] = 0.f;
    for (int k = 0; k < HID; ++k) {
        float4 wv = *(const float4*)&ws[k * HID + c0];
        float h0 = hs[r0][k], h1 = hs[r0 + 1][k], h2 = hs[r0 + 2][k], h3 = hs[r0 + 3][k];
        acc[0][0] += h0 * wv.x; acc[0][1] += h0 * wv.y; acc[0][2] += h0 * wv.z; acc[0][3] += h0 * wv.w;
        acc[1][0] += h1 * wv.x; acc[1][1] += h1 * wv.y; acc[1][2] += h1 * wv.z; acc[1][3] += h1 * wv.w;
        acc[2][0] += h2 * wv.x; acc[2][1] += h2 * wv.y; acc[2][2] += h2 * wv.z; acc[2][3] += h2 * wv.w;
        acc[3][0] += h3 * wv.x; acc[3][1] += h3 * wv.y; acc[3][2] += h3 * wv.z; acc[3][3] += h3 * wv.w;
    }
#pragma unroll
    for (int j = 0; j < 4; ++j) {
        int nn = n0 + r0 + j;
        float dv = dinv[nn];
        uint2 pv;
        pv.x = packbf(acc[j][0] * dv, acc[j][1] * dv);
        pv.y = packbf(acc[j][2] * dv, acc[j][3] * dv);
        *(uint2*)&m[(size_t)nn * 64 + (size_t)(c0 >> 1)] = pv;
    }
}

// ---------------- node count per graph: binary search on sorted batch ----------------
__global__ __launch_bounds__(64) void k_cnt(const int* __restrict__ batch,
                                            int* __restrict__ cnt) {
    int g = threadIdx.x;
    if (g >= N_GRAPHS) return;
    int lo0 = 0, hi0 = N_NODES;
    while (lo0 < hi0) { int mid = (lo0 + hi0) >> 1; if (batch[mid] < g) lo0 = mid + 1; else hi0 = mid; }
    int lo1 = lo0, hi1 = N_NODES;
    while (lo1 < hi1) { int mid = (lo1 + hi1) >> 1; if (batch[mid] < g + 1) lo1 = mid + 1; else hi1 = mid; }
    cnt[g] = lo1 - lo0;
}

// ---------------- pooled sums: run-length accumulate (batch sorted) ----------------
#define POOL_CHUNK 512
__global__ __launch_bounds__(256) void k_pool(const float* __restrict__ h,
                                              const int* __restrict__ batch,
                                              float* __restrict__ pooled) {
    int t = threadIdx.x;
    int c = t & 127, half = t >> 7;
    int start = blockIdx.x * POOL_CHUNK;
    int end = min(start + POOL_CHUNK, N_NODES);
    float acc = 0.f;
    int cur = -1;
    for (int n = start + half; n < end; n += 2) {
        int g = batch[n];
        if (g != cur) {
            if (cur >= 0) atomicAdd(&pooled[cur * HID + c], acc);
            acc = 0.f;
            cur = g;
        }
        acc += h[(size_t)n * HID + c];
    }
    if (cur >= 0) atomicAdd(&pooled[cur * HID + c], acc);
}

// ---------------- final: out = (pooled/cnt) @ Wf + bf ----------------
__global__ __launch_bounds__(128) void k_final(const float* __restrict__ pooled,
                                               const int* __restrict__ cnt,
                                               const float* __restrict__ Wf,
                                               const float* __restrict__ bf,
                                               float* __restrict__ out) {
    __shared__ float p[HID];
    int g = blockIdx.x, t = threadIdx.x;
    float inv = 1.f / fmaxf((float)cnt[g], 1.f);
    p[t] = pooled[g * HID + t] * inv;
    __syncthreads();
    if (t < NCLS) {
        float acc = bf[t];
        for (int k = 0; k < HID; ++k) acc += p[k] * Wf[k * NCLS + t];
        out[g * NCLS + t] = acc;
    }
}

extern "C" void kernel_launch(void* const* d_in, const int* in_sizes, int n_in,
                              void* d_out, int out_size, void* d_ws, size_t ws_size,
                              hipStream_t stream) {
    const float* x   = (const float*)d_in[0];
    const int*   ei  = (const int*)d_in[1];   // [2][E] flat
    const int*   src = ei;
    const int*   dst = ei + N_EDGES;
    const int*   batch = (const int*)d_in[2];
    const float* W1 = (const float*)d_in[3];
    const float* b1 = (const float*)d_in[4];
    const float* W2 = (const float*)d_in[5];
    const float* b2 = (const float*)d_in[6];
    const float* Wf = (const float*)d_in[7];
    const float* bf = (const float*)d_in[8];
    float* out = (float*)d_out;

    char* ws = (char*)d_ws;
    size_t off = 0;
    unsigned* mbuf = (unsigned*)(ws + off); off += (size_t)N_NODES * 64 * 4;   // 25.6 MB bf16-packed
    float* hbuf = (float*)(ws + off);       off += (size_t)N_NODES * HID * 4;  // 51.2 MB
    int* csr_src = (int*)(ws + off);        off += (size_t)N_EDGES * 4;        // 6.4 MB
    int* deg = (int*)(ws + off);            off += (size_t)N_NODES * 4;
    float* dinv = (float*)(ws + off);       off += (size_t)N_NODES * 4;
    int* rowptr = (int*)(ws + off);         off += (size_t)(N_NODES + 1) * 4;
    int* cursor = (int*)(ws + off);         off += (size_t)N_NODES * 4;
    int* partials = (int*)(ws + off);       off += (size_t)SCAN_NB * 4;
    int* blockoff = (int*)(ws + off);       off += (size_t)SCAN_NB * 4;
    float* pooled = (float*)(ws + off);     off += (size_t)N_GRAPHS * HID * 4;
    int* cnt = (int*)(ws + off);            off += (size_t)N_GRAPHS * 4;

    // graph preprocessing: degree, dinv, CSR by dst
    k_init<<<(N_NODES + 255) / 256, 256, 0, stream>>>(deg, pooled);
    k_deg<<<(N_EDGES + 255) / 256, 256, 0, stream>>>(dst, deg);
    k_dinv<<<(N_NODES + 255) / 256, 256, 0, stream>>>(deg, dinv);
    k_part<<<SCAN_NB, 256, 0, stream>>>(deg, partials);
    k_scanblk<<<1, 128, 0, stream>>>(partials, blockoff, rowptr);
    k_apply<<<SCAN_NB, 256, 0, stream>>>(deg, blockoff, rowptr, cursor);
    k_fill<<<(N_EDGES + 255) / 256, 256, 0, stream>>>(src, dst, cursor, csr_src);

    // layer 1
    k_xform1<<<N_NODES / 4, 256, 0, stream>>>(x, W1, dinv, mbuf);
    k_gather<<<(N_NODES + 3) / 4, 256, 0, stream>>>(rowptr, csr_src, mbuf, b1, dinv, hbuf);

    // layer 2
    k_xform2<<<N_NODES / NT2, 256, 0, stream>>>(hbuf, W2, dinv, mbuf);
    k_gather<<<(N_NODES + 3) / 4, 256, 0, stream>>>(rowptr, csr_src, mbuf, b2, dinv, hbuf);

    // pooling + classifier
    k_cnt<<<1, 64, 0, stream>>>(batch, cnt);
    k_pool<<<(N_NODES + POOL_CHUNK - 1) / POOL_CHUNK, 256, 0, stream>>>(hbuf, batch, pooled);
    k_final<<<N_GRAPHS, 128, 0, stream>>>(pooled, cnt, Wf, bf, out);
}

// Round 6
// 505.523 us; speedup vs baseline: 6.9385x; 1.1904x over previous
//
#include <hip/hip_runtime.h>

#define N_NODES 100000
#define N_EDGES 1600000
#define N_GRAPHS 64
#define IN_CH 15
#define HID 128
#define NCLS 11

using short8 = __attribute__((ext_vector_type(8))) short;
using f32x4 = __attribute__((ext_vector_type(4))) float;

// ---- bf16 pack/unpack (RNE) ----
__device__ __forceinline__ unsigned short f2bf(float f) {
    unsigned u = __builtin_bit_cast(unsigned, f);
    u += 0x7FFF + ((u >> 16) & 1);
    return (unsigned short)(u >> 16);
}
__device__ __forceinline__ unsigned packbf(float a, float b) {
    return (unsigned)f2bf(a) | ((unsigned)f2bf(b) << 16);
}
__device__ __forceinline__ float2 unpackbf(unsigned v) {
    float2 r;
    unsigned lo = v << 16;
    unsigned hi = v & 0xFFFF0000u;
    r.x = __builtin_bit_cast(float, lo);
    r.y = __builtin_bit_cast(float, hi);
    return r;
}

// ---------------- init: deg=0, pooled=0 ----------------
__global__ __launch_bounds__(256) void k_init(int* __restrict__ deg,
                                              float* __restrict__ pooled) {
    int i = blockIdx.x * 256 + threadIdx.x;
    if (i < N_NODES) deg[i] = 0;
    if (i < N_GRAPHS * HID) pooled[i] = 0.f;
}

// ---------------- in-degree count over dst ----------------
__global__ __launch_bounds__(256) void k_deg(const int* __restrict__ dst,
                                             int* __restrict__ deg) {
    int e = blockIdx.x * 256 + threadIdx.x;
    if (e < N_EDGES) atomicAdd(&deg[dst[e]], 1);
}

__global__ __launch_bounds__(256) void k_dinv(const int* __restrict__ deg,
                                              float* __restrict__ dinv) {
    int i = blockIdx.x * 256 + threadIdx.x;
    if (i < N_NODES) dinv[i] = rsqrtf((float)(deg[i] + 1));  // +1 self-loop
}

// ---------------- multi-block exclusive scan of deg -> rowptr, cursor ----------------
#define SCAN_BLK 1024
#define SCAN_NB ((N_NODES + SCAN_BLK - 1) / SCAN_BLK)  // 98
__global__ __launch_bounds__(256) void k_part(const int* __restrict__ deg,
                                              int* __restrict__ partials) {
    __shared__ int red[256];
    int t = threadIdx.x;
    int base = blockIdx.x * SCAN_BLK + t * 4;
    int s = 0;
#pragma unroll
    for (int i = 0; i < 4; ++i) {
        int idx = base + i;
        if (idx < N_NODES) s += deg[idx];
    }
    red[t] = s;
    __syncthreads();
    for (int off = 128; off > 0; off >>= 1) {
        if (t < off) red[t] += red[t + off];
        __syncthreads();
    }
    if (t == 0) partials[blockIdx.x] = red[0];
}

__global__ __launch_bounds__(128) void k_scanblk(const int* __restrict__ partials,
                                                 int* __restrict__ blockoff,
                                                 int* __restrict__ rowptr) {
    __shared__ int arr[128];
    int t = threadIdx.x;
    arr[t] = (t < SCAN_NB) ? partials[t] : 0;
    __syncthreads();
    for (int off = 1; off < 128; off <<= 1) {
        int v = (t >= off) ? arr[t - off] : 0;
        __syncthreads();
        arr[t] += v;
        __syncthreads();
    }
    if (t < SCAN_NB) blockoff[t] = (t == 0) ? 0 : arr[t - 1];
    if (t == 0) rowptr[N_NODES] = N_EDGES;
}

__global__ __launch_bounds__(256) void k_apply(const int* __restrict__ deg,
                                               const int* __restrict__ blockoff,
                                               int* __restrict__ rowptr,
                                               int* __restrict__ cursor) {
    __shared__ int arr[256];
    int t = threadIdx.x;
    int base = blockIdx.x * SCAN_BLK + t * 4;
    int d[4];
    int s = 0;
#pragma unroll
    for (int i = 0; i < 4; ++i) {
        int idx = base + i;
        d[i] = (idx < N_NODES) ? deg[idx] : 0;
        s += d[i];
    }
    arr[t] = s;
    __syncthreads();
    for (int off = 1; off < 256; off <<= 1) {
        int v = (t >= off) ? arr[t - off] : 0;
        __syncthreads();
        arr[t] += v;
        __syncthreads();
    }
    int run = blockoff[blockIdx.x] + ((t == 0) ? 0 : arr[t - 1]);
#pragma unroll
    for (int i = 0; i < 4; ++i) {
        int idx = base + i;
        if (idx < N_NODES) {
            rowptr[idx] = run;
            cursor[idx] = run;
            run += d[i];
        }
    }
}

// ---------------- fill CSR: csr_src grouped by dst ----------------
__global__ __launch_bounds__(256) void k_fill(const int* __restrict__ src,
                                              const int* __restrict__ dst,
                                              int* __restrict__ cursor,
                                              int* __restrict__ csr_src) {
    int e = blockIdx.x * 256 + threadIdx.x;
    if (e < N_EDGES) {
        int pos = atomicAdd(&cursor[dst[e]], 1);
        csr_src[pos] = src[e];
    }
}

// ---------------- W2 -> MFMA B-fragment layout, bf16 ----------------
// slot s = (ct*4 + kb)*64 + lane; element j (0..7): B[k = kb*32 + (lane>>4)*8 + j][col = ct*16 + (lane&15)]
__global__ __launch_bounds__(256) void k_w2pack(const float* __restrict__ W2,
                                                uint4* __restrict__ Bp) {
    int i = blockIdx.x * 256 + threadIdx.x;  // 2048 slots
    if (i >= 2048) return;
    int lane = i & 63;
    int kb = (i >> 6) & 3;
    int ct = i >> 8;
    int col = ct * 16 + (lane & 15);
    int k0 = kb * 32 + ((lane >> 4) & 3) * 8;
    unsigned w[4];
#pragma unroll
    for (int p = 0; p < 4; ++p) {
        int k = k0 + 2 * p;
        w[p] = packbf(W2[k * HID + col], W2[(k + 1) * HID + col]);
    }
    Bp[i] = make_uint4(w[0], w[1], w[2], w[3]);
}

// ---------------- layer-1 transform: m = bf16((x @ W1) * dinv) ----------------
__global__ __launch_bounds__(256) void k_xform1(const float* __restrict__ x,
                                                const float* __restrict__ W1,
                                                const float* __restrict__ dinv,
                                                unsigned* __restrict__ m) {
    __shared__ float w[IN_CH * HID];  // 7.5 KB
    int t = threadIdx.x;
    for (int i = t; i < IN_CH * HID; i += 256) w[i] = W1[i];
    __syncthreads();
    int node = blockIdx.x * 4 + (t >> 6);
    int lane = t & 63;
    int c = lane * 2;
    const float* xr = x + node * IN_CH;
    float a0 = 0.f, a1 = 0.f;
#pragma unroll
    for (int k = 0; k < IN_CH; ++k) {
        float xv = xr[k];
        a0 += xv * w[k * HID + c];
        a1 += xv * w[k * HID + c + 1];
    }
    float dv = dinv[node];
    m[(size_t)node * 64 + lane] = packbf(a0 * dv, a1 * dv);
}

// ---------------- gather (bf16 out): h1 = relu(dinv*(m[n]+sum m[src])+b), packed bf16 ----------------
__global__ __launch_bounds__(256) void k_gather_bf(const int* __restrict__ rowptr,
                                                   const int* __restrict__ csr_src,
                                                   const unsigned* __restrict__ m,
                                                   const float* __restrict__ bias,
                                                   const float* __restrict__ dinv,
                                                   unsigned* __restrict__ outh) {
    int wave = (blockIdx.x * 256 + threadIdx.x) >> 6;
    if (wave >= N_NODES) return;
    int n = wave;
    int lane = threadIdx.x & 63;
    int c = lane * 2;
    int beg = rowptr[n], end = rowptr[n + 1];
    float2 acc = unpackbf(m[(size_t)n * 64 + lane]);  // self-loop term
    int e = beg;
    for (; e + 4 <= end; e += 4) {
        int s0 = csr_src[e], s1 = csr_src[e + 1], s2 = csr_src[e + 2], s3 = csr_src[e + 3];
        float2 v0 = unpackbf(m[(size_t)s0 * 64 + lane]);
        float2 v1 = unpackbf(m[(size_t)s1 * 64 + lane]);
        float2 v2 = unpackbf(m[(size_t)s2 * 64 + lane]);
        float2 v3 = unpackbf(m[(size_t)s3 * 64 + lane]);
        acc.x += v0.x; acc.y += v0.y;
        acc.x += v1.x; acc.y += v1.y;
        acc.x += v2.x; acc.y += v2.y;
        acc.x += v3.x; acc.y += v3.y;
    }
    for (; e < end; ++e) {
        int s = csr_src[e];
        float2 v = unpackbf(m[(size_t)s * 64 + lane]);
        acc.x += v.x; acc.y += v.y;
    }
    float dv = dinv[n];
    float2 b = *(const float2*)&bias[c];
    float rx = fmaxf(acc.x * dv + b.x, 0.f);
    float ry = fmaxf(acc.y * dv + b.y, 0.f);
    outh[(size_t)n * 64 + lane] = packbf(rx, ry);
}

// ---------------- gather (f32 out): h2 for pooling ----------------
__global__ __launch_bounds__(256) void k_gather_f32(const int* __restrict__ rowptr,
                                                    const int* __restrict__ csr_src,
                                                    const unsigned* __restrict__ m,
                                                    const float* __restrict__ bias,
                                                    const float* __restrict__ dinv,
                                                    float* __restrict__ outh) {
    int wave = (blockIdx.x * 256 + threadIdx.x) >> 6;
    if (wave >= N_NODES) return;
    int n = wave;
    int lane = threadIdx.x & 63;
    int c = lane * 2;
    int beg = rowptr[n], end = rowptr[n + 1];
    float2 acc = unpackbf(m[(size_t)n * 64 + lane]);
    int e = beg;
    for (; e + 4 <= end; e += 4) {
        int s0 = csr_src[e], s1 = csr_src[e + 1], s2 = csr_src[e + 2], s3 = csr_src[e + 3];
        float2 v0 = unpackbf(m[(size_t)s0 * 64 + lane]);
        float2 v1 = unpackbf(m[(size_t)s1 * 64 + lane]);
        float2 v2 = unpackbf(m[(size_t)s2 * 64 + lane]);
        float2 v3 = unpackbf(m[(size_t)s3 * 64 + lane]);
        acc.x += v0.x; acc.y += v0.y;
        acc.x += v1.x; acc.y += v1.y;
        acc.x += v2.x; acc.y += v2.y;
        acc.x += v3.x; acc.y += v3.y;
    }
    for (; e < end; ++e) {
        int s = csr_src[e];
        float2 v = unpackbf(m[(size_t)s * 64 + lane]);
        acc.x += v.x; acc.y += v.y;
    }
    float dv = dinv[n];
    float2 b = *(const float2*)&bias[c];
    float2 r;
    r.x = fmaxf(acc.x * dv + b.x, 0.f);
    r.y = fmaxf(acc.y * dv + b.y, 0.f);
    *(float2*)&outh[(size_t)n * HID + c] = r;
}

// ---------------- layer-2 transform via MFMA: m = bf16((h1 @ W2) * dinv) ----------------
// wave = 16 rows x 128 cols; block = 4 waves = 64 rows. No LDS.
// A-frag: lane reads h1[row=row0+(lane&15)][k=(lane>>4)*8 ...] per 32-k block.
// C/D: col = lane&15 (+16*ct), row = row0 + (lane>>4)*4 + reg   [m89-verified]
__global__ __launch_bounds__(256) void k_xform2(const unsigned* __restrict__ h1b,
                                                const uint4* __restrict__ Bp,
                                                const float* __restrict__ dinv,
                                                unsigned short* __restrict__ mout) {
    int lane = threadIdx.x & 63;
    int wid = threadIdx.x >> 6;
    int row0 = blockIdx.x * 64 + wid * 16;
    int arow = row0 + (lane & 15);
    const uint4* hbase = (const uint4*)h1b;
    uint4 a_u[4];
#pragma unroll
    for (int kb = 0; kb < 4; ++kb)
        a_u[kb] = hbase[(size_t)arow * 16 + kb * 4 + (lane >> 4)];  // 16B: rows OOB read into next ws buffer (mapped), stores guarded
    int rbase = row0 + (lane >> 4) * 4;
    float dv[4];
#pragma unroll
    for (int j = 0; j < 4; ++j) dv[j] = dinv[min(rbase + j, N_NODES - 1)];
#pragma unroll
    for (int ct = 0; ct < 8; ++ct) {
        f32x4 acc = {0.f, 0.f, 0.f, 0.f};
#pragma unroll
        for (int kb = 0; kb < 4; ++kb) {
            uint4 b_u = Bp[(ct * 4 + kb) * 64 + lane];
            acc = __builtin_amdgcn_mfma_f32_16x16x32_bf16(
                __builtin_bit_cast(short8, a_u[kb]),
                __builtin_bit_cast(short8, b_u), acc, 0, 0, 0);
        }
        int col = ct * 16 + (lane & 15);
#pragma unroll
        for (int j = 0; j < 4; ++j) {
            int r = rbase + j;
            if (r < N_NODES) mout[(size_t)r * HID + col] = f2bf(acc[j] * dv[j]);
        }
    }
}

// ---------------- node count per graph: binary search on sorted batch ----------------
__global__ __launch_bounds__(64) void k_cnt(const int* __restrict__ batch,
                                            int* __restrict__ cnt) {
    int g = threadIdx.x;
    if (g >= N_GRAPHS) return;
    int lo0 = 0, hi0 = N_NODES;
    while (lo0 < hi0) { int mid = (lo0 + hi0) >> 1; if (batch[mid] < g) lo0 = mid + 1; else hi0 = mid; }
    int lo1 = lo0, hi1 = N_NODES;
    while (lo1 < hi1) { int mid = (lo1 + hi1) >> 1; if (batch[mid] < g + 1) lo1 = mid + 1; else hi1 = mid; }
    cnt[g] = lo1 - lo0;
}

// ---------------- pooled sums: run-length accumulate (batch sorted) ----------------
#define POOL_CHUNK 512
__global__ __launch_bounds__(256) void k_pool(const float* __restrict__ h,
                                              const int* __restrict__ batch,
                                              float* __restrict__ pooled) {
    int t = threadIdx.x;
    int c = t & 127, half = t >> 7;
    int start = blockIdx.x * POOL_CHUNK;
    int end = min(start + POOL_CHUNK, N_NODES);
    float acc = 0.f;
    int cur = -1;
    for (int n = start + half; n < end; n += 2) {
        int g = batch[n];
        if (g != cur) {
            if (cur >= 0) atomicAdd(&pooled[cur * HID + c], acc);
            acc = 0.f;
            cur = g;
        }
        acc += h[(size_t)n * HID + c];
    }
    if (cur >= 0) atomicAdd(&pooled[cur * HID + c], acc);
}

// ---------------- final: out = (pooled/cnt) @ Wf + bf ----------------
__global__ __launch_bounds__(128) void k_final(const float* __restrict__ pooled,
                                               const int* __restrict__ cnt,
                                               const float* __restrict__ Wf,
                                               const float* __restrict__ bf,
                                               float* __restrict__ out) {
    __shared__ float p[HID];
    int g = blockIdx.x, t = threadIdx.x;
    float inv = 1.f / fmaxf((float)cnt[g], 1.f);
    p[t] = pooled[g * HID + t] * inv;
    __syncthreads();
    if (t < NCLS) {
        float acc = bf[t];
        for (int k = 0; k < HID; ++k) acc += p[k] * Wf[k * NCLS + t];
        out[g * NCLS + t] = acc;
    }
}

extern "C" void kernel_launch(void* const* d_in, const int* in_sizes, int n_in,
                              void* d_out, int out_size, void* d_ws, size_t ws_size,
                              hipStream_t stream) {
    const float* x   = (const float*)d_in[0];
    const int*   ei  = (const int*)d_in[1];   // [2][E] flat
    const int*   src = ei;
    const int*   dst = ei + N_EDGES;
    const int*   batch = (const int*)d_in[2];
    const float* W1 = (const float*)d_in[3];
    const float* b1 = (const float*)d_in[4];
    const float* W2 = (const float*)d_in[5];
    const float* b2 = (const float*)d_in[6];
    const float* Wf = (const float*)d_in[7];
    const float* bf = (const float*)d_in[8];
    float* out = (float*)d_out;

    char* ws = (char*)d_ws;
    size_t off = 0;
    unsigned* mbuf = (unsigned*)(ws + off);  off += (size_t)N_NODES * 64 * 4;   // 25.6 MB bf16 messages
    unsigned* h1b = (unsigned*)(ws + off);   off += (size_t)N_NODES * 64 * 4;   // 25.6 MB bf16 h1
    float* hbuf = (float*)(ws + off);        off += (size_t)N_NODES * HID * 4;  // 51.2 MB f32 h2
    int* csr_src = (int*)(ws + off);         off += (size_t)N_EDGES * 4;        // 6.4 MB
    uint4* Bp = (uint4*)(ws + off);          off += (size_t)2048 * 16;          // 32 KB
    int* deg = (int*)(ws + off);             off += (size_t)N_NODES * 4;
    float* dinv = (float*)(ws + off);        off += (size_t)N_NODES * 4;
    int* rowptr = (int*)(ws + off);          off += (size_t)(N_NODES + 1) * 4;
    int* cursor = (int*)(ws + off);          off += (size_t)N_NODES * 4;
    int* partials = (int*)(ws + off);        off += (size_t)SCAN_NB * 4;
    int* blockoff = (int*)(ws + off);        off += (size_t)SCAN_NB * 4;
    float* pooled = (float*)(ws + off);      off += (size_t)N_GRAPHS * HID * 4;
    int* cnt = (int*)(ws + off);             off += (size_t)N_GRAPHS * 4;

    // graph preprocessing: degree, dinv, CSR by dst, W2 fragment pack
    k_init<<<(N_NODES + 255) / 256, 256, 0, stream>>>(deg, pooled);
    k_deg<<<(N_EDGES + 255) / 256, 256, 0, stream>>>(dst, deg);
    k_dinv<<<(N_NODES + 255) / 256, 256, 0, stream>>>(deg, dinv);
    k_part<<<SCAN_NB, 256, 0, stream>>>(deg, partials);
    k_scanblk<<<1, 128, 0, stream>>>(partials, blockoff, rowptr);
    k_apply<<<SCAN_NB, 256, 0, stream>>>(deg, blockoff, rowptr, cursor);
    k_fill<<<(N_EDGES + 255) / 256, 256, 0, stream>>>(src, dst, cursor, csr_src);
    k_w2pack<<<8, 256, 0, stream>>>(W2, Bp);

    // layer 1
    k_xform1<<<N_NODES / 4, 256, 0, stream>>>(x, W1, dinv, mbuf);
    k_gather_bf<<<(N_NODES + 3) / 4, 256, 0, stream>>>(rowptr, csr_src, mbuf, b1, dinv, h1b);

    // layer 2 (MFMA transform; overwrites mbuf — dead after gather1)
    k_xform2<<<(N_NODES + 63) / 64, 256, 0, stream>>>(h1b, Bp, dinv, (unsigned short*)mbuf);
    k_gather_f32<<<(N_NODES + 3) / 4, 256, 0, stream>>>(rowptr, csr_src, mbuf, b2, dinv, hbuf);

    // pooling + classifier
    k_cnt<<<1, 64, 0, stream>>>(batch, cnt);
    k_pool<<<(N_NODES + POOL_CHUNK - 1) / POOL_CHUNK, 256, 0, stream>>>(hbuf, batch, pooled);
    k_final<<<N_GRAPHS, 128, 0, stream>>>(pooled, cnt, Wf, bf, out);
}

// Round 7
// 412.240 us; speedup vs baseline: 8.5085x; 1.2263x over previous
//
#include <hip/hip_runtime.h>

#define N_NODES 100000
#define N_EDGES 1600000
#define N_GRAPHS 64
#define IN_CH 15
#define HID 128
#define NCLS 11

// bucketed CSR-fill geometry
#define NBUCK 196            // ceil(100000 / 512), bucket = dst >> 9
#define NBF 512              // partition blocks
#define EPB (N_EDGES / NBF)  // 3125 edges per block

using short8 = __attribute__((ext_vector_type(8))) short;
using f32x4 = __attribute__((ext_vector_type(4))) float;

// ---- bf16 pack/unpack (RNE) ----
__device__ __forceinline__ unsigned short f2bf(float f) {
    unsigned u = __builtin_bit_cast(unsigned, f);
    u += 0x7FFF + ((u >> 16) & 1);
    return (unsigned short)(u >> 16);
}
__device__ __forceinline__ unsigned packbf(float a, float b) {
    return (unsigned)f2bf(a) | ((unsigned)f2bf(b) << 16);
}
__device__ __forceinline__ float2 unpackbf(unsigned v) {
    float2 r;
    unsigned lo = v << 16;
    unsigned hi = v & 0xFFFF0000u;
    r.x = __builtin_bit_cast(float, lo);
    r.y = __builtin_bit_cast(float, hi);
    return r;
}

// ---------------- init: deg=0, pooled=0 ----------------
__global__ __launch_bounds__(256) void k_init(int* __restrict__ deg,
                                              float* __restrict__ pooled) {
    int i = blockIdx.x * 256 + threadIdx.x;
    if (i < N_NODES) deg[i] = 0;
    if (i < N_GRAPHS * HID) pooled[i] = 0.f;
}

// ---------------- deg atomics + per-block bucket histogram ----------------
__global__ __launch_bounds__(256) void k_deg_hist(const int* __restrict__ dst,
                                                  int* __restrict__ deg,
                                                  int* __restrict__ cntm) {
    __shared__ int hist[NBUCK];
    int t = threadIdx.x;
    for (int i = t; i < NBUCK; i += 256) hist[i] = 0;
    __syncthreads();
    int base = blockIdx.x * EPB;
#pragma unroll
    for (int i = 0; i < (EPB + 255) / 256; ++i) {
        int e = i * 256 + t;
        if (e < EPB) {
            int d = dst[base + e];
            atomicAdd(&deg[d], 1);
            atomicAdd(&hist[d >> 9], 1);
        }
    }
    __syncthreads();
    for (int b = t; b < NBUCK; b += 256)
        cntm[b * NBF + blockIdx.x] = hist[b];
}

__global__ __launch_bounds__(256) void k_dinv(const int* __restrict__ deg,
                                              float* __restrict__ dinv) {
    int i = blockIdx.x * 256 + threadIdx.x;
    if (i < N_NODES) dinv[i] = rsqrtf((float)(deg[i] + 1));  // +1 self-loop
}

// ---------------- multi-block exclusive scan of deg -> rowptr ----------------
#define SCAN_BLK 1024
#define SCAN_NB ((N_NODES + SCAN_BLK - 1) / SCAN_BLK)  // 98
__global__ __launch_bounds__(256) void k_part(const int* __restrict__ deg,
                                              int* __restrict__ partials) {
    __shared__ int red[256];
    int t = threadIdx.x;
    int base = blockIdx.x * SCAN_BLK + t * 4;
    int s = 0;
#pragma unroll
    for (int i = 0; i < 4; ++i) {
        int idx = base + i;
        if (idx < N_NODES) s += deg[idx];
    }
    red[t] = s;
    __syncthreads();
    for (int off = 128; off > 0; off >>= 1) {
        if (t < off) red[t] += red[t + off];
        __syncthreads();
    }
    if (t == 0) partials[blockIdx.x] = red[0];
}

__global__ __launch_bounds__(128) void k_scanblk(const int* __restrict__ partials,
                                                 int* __restrict__ blockoff,
                                                 int* __restrict__ rowptr) {
    __shared__ int arr[128];
    int t = threadIdx.x;
    arr[t] = (t < SCAN_NB) ? partials[t] : 0;
    __syncthreads();
    for (int off = 1; off < 128; off <<= 1) {
        int v = (t >= off) ? arr[t - off] : 0;
        __syncthreads();
        arr[t] += v;
        __syncthreads();
    }
    if (t < SCAN_NB) blockoff[t] = (t == 0) ? 0 : arr[t - 1];
    if (t == 0) rowptr[N_NODES] = N_EDGES;
}

__global__ __launch_bounds__(256) void k_apply(const int* __restrict__ deg,
                                               const int* __restrict__ blockoff,
                                               int* __restrict__ rowptr) {
    __shared__ int arr[256];
    int t = threadIdx.x;
    int base = blockIdx.x * SCAN_BLK + t * 4;
    int d[4];
    int s = 0;
#pragma unroll
    for (int i = 0; i < 4; ++i) {
        int idx = base + i;
        d[i] = (idx < N_NODES) ? deg[idx] : 0;
        s += d[i];
    }
    arr[t] = s;
    __syncthreads();
    for (int off = 1; off < 256; off <<= 1) {
        int v = (t >= off) ? arr[t - off] : 0;
        __syncthreads();
        arr[t] += v;
        __syncthreads();
    }
    int run = blockoff[blockIdx.x] + ((t == 0) ? 0 : arr[t - 1]);
#pragma unroll
    for (int i = 0; i < 4; ++i) {
        int idx = base + i;
        if (idx < N_NODES) {
            rowptr[idx] = run;
            run += d[i];
        }
    }
}

// ---------------- per-(bucket,block) partition offsets ----------------
// offs[b][blk] = rowptr[512b] + excl_sum_{blk'<blk} cntm[b][blk']
__global__ __launch_bounds__(NBF) void k_offs(const int* __restrict__ cntm,
                                              const int* __restrict__ rowptr,
                                              int* __restrict__ offs) {
    __shared__ int arr[NBF];
    int b = blockIdx.x, t = threadIdx.x;
    arr[t] = cntm[b * NBF + t];
    __syncthreads();
    for (int off = 1; off < NBF; off <<= 1) {
        int v = (t >= off) ? arr[t - off] : 0;
        __syncthreads();
        arr[t] += v;
        __syncthreads();
    }
    int base = rowptr[b << 9];
    offs[b * NBF + t] = base + ((t == 0) ? 0 : arr[t - 1]);
}

// ---------------- partition: edges -> staging, grouped by 512-node bucket ----------------
// packed: (dst & 511) << 17 | src   (src < 2^17)
__global__ __launch_bounds__(256) void k_partition(const int* __restrict__ src,
                                                   const int* __restrict__ dst,
                                                   const int* __restrict__ offs,
                                                   unsigned* __restrict__ staging) {
    __shared__ int cur[NBUCK];
    int t = threadIdx.x;
    for (int b = t; b < NBUCK; b += 256) cur[b] = offs[b * NBF + blockIdx.x];
    __syncthreads();
    int base = blockIdx.x * EPB;
#pragma unroll
    for (int i = 0; i < (EPB + 255) / 256; ++i) {
        int e = i * 256 + t;
        if (e < EPB) {
            int d = dst[base + e];
            int s = src[base + e];
            int slot = atomicAdd(&cur[d >> 9], 1);
            staging[slot] = ((unsigned)(d & 511) << 17) | (unsigned)s;
        }
    }
}

// ---------------- csr fill: one block per bucket, LDS node cursors ----------------
__global__ __launch_bounds__(256) void k_csrfill(const unsigned* __restrict__ staging,
                                                 const int* __restrict__ rowptr,
                                                 int* __restrict__ csr_src) {
    __shared__ int cur[512];
    int b = blockIdx.x, t = threadIdx.x;
    int n0 = b << 9;
#pragma unroll
    for (int i = 0; i < 2; ++i) {
        int n = n0 + t + i * 256;
        cur[t + i * 256] = (n < N_NODES) ? rowptr[n] : 0;
    }
    __syncthreads();
    int beg = rowptr[n0];
    int end = rowptr[min(n0 + 512, N_NODES)];
    for (int e = beg + t; e < end; e += 256) {
        unsigned v = staging[e];
        int nloc = v >> 17;
        int pos = atomicAdd(&cur[nloc], 1);
        csr_src[pos] = (int)(v & 0x1FFFFu);
    }
}

// ---------------- W2 -> MFMA B-fragment layout, bf16 ----------------
__global__ __launch_bounds__(256) void k_w2pack(const float* __restrict__ W2,
                                                uint4* __restrict__ Bp) {
    int i = blockIdx.x * 256 + threadIdx.x;  // 2048 slots
    if (i >= 2048) return;
    int lane = i & 63;
    int kb = (i >> 6) & 3;
    int ct = i >> 8;
    int col = ct * 16 + (lane & 15);
    int k0 = kb * 32 + ((lane >> 4) & 3) * 8;
    unsigned w[4];
#pragma unroll
    for (int p = 0; p < 4; ++p) {
        int k = k0 + 2 * p;
        w[p] = packbf(W2[k * HID + col], W2[(k + 1) * HID + col]);
    }
    Bp[i] = make_uint4(w[0], w[1], w[2], w[3]);
}

// ---------------- layer-1 transform: m = bf16((x @ W1) * dinv) ----------------
__global__ __launch_bounds__(256) void k_xform1(const float* __restrict__ x,
                                                const float* __restrict__ W1,
                                                const float* __restrict__ dinv,
                                                unsigned* __restrict__ m) {
    __shared__ float w[IN_CH * HID];  // 7.5 KB
    int t = threadIdx.x;
    for (int i = t; i < IN_CH * HID; i += 256) w[i] = W1[i];
    __syncthreads();
    int node = blockIdx.x * 4 + (t >> 6);
    int lane = t & 63;
    int c = lane * 2;
    const float* xr = x + node * IN_CH;
    float a0 = 0.f, a1 = 0.f;
#pragma unroll
    for (int k = 0; k < IN_CH; ++k) {
        float xv = xr[k];
        a0 += xv * w[k * HID + c];
        a1 += xv * w[k * HID + c + 1];
    }
    float dv = dinv[node];
    m[(size_t)node * 64 + lane] = packbf(a0 * dv, a1 * dv);
}

// ---------------- gather (bf16 out): h1 = relu(dinv*(m[n]+sum m[src])+b) ----------------
__global__ __launch_bounds__(256) void k_gather_bf(const int* __restrict__ rowptr,
                                                   const int* __restrict__ csr_src,
                                                   const unsigned* __restrict__ m,
                                                   const float* __restrict__ bias,
                                                   const float* __restrict__ dinv,
                                                   unsigned* __restrict__ outh) {
    int wave = (blockIdx.x * 256 + threadIdx.x) >> 6;
    if (wave >= N_NODES) return;
    int n = wave;
    int lane = threadIdx.x & 63;
    int c = lane * 2;
    int beg = rowptr[n], end = rowptr[n + 1];
    float2 acc = unpackbf(m[(size_t)n * 64 + lane]);  // self-loop term
    int e = beg;
    for (; e + 4 <= end; e += 4) {
        int s0 = csr_src[e], s1 = csr_src[e + 1], s2 = csr_src[e + 2], s3 = csr_src[e + 3];
        float2 v0 = unpackbf(m[(size_t)s0 * 64 + lane]);
        float2 v1 = unpackbf(m[(size_t)s1 * 64 + lane]);
        float2 v2 = unpackbf(m[(size_t)s2 * 64 + lane]);
        float2 v3 = unpackbf(m[(size_t)s3 * 64 + lane]);
        acc.x += v0.x; acc.y += v0.y;
        acc.x += v1.x; acc.y += v1.y;
        acc.x += v2.x; acc.y += v2.y;
        acc.x += v3.x; acc.y += v3.y;
    }
    for (; e < end; ++e) {
        int s = csr_src[e];
        float2 v = unpackbf(m[(size_t)s * 64 + lane]);
        acc.x += v.x; acc.y += v.y;
    }
    float dv = dinv[n];
    float2 b = *(const float2*)&bias[c];
    float rx = fmaxf(acc.x * dv + b.x, 0.f);
    float ry = fmaxf(acc.y * dv + b.y, 0.f);
    outh[(size_t)n * 64 + lane] = packbf(rx, ry);
}

// ---------------- gather (f32 out): h2 for pooling ----------------
__global__ __launch_bounds__(256) void k_gather_f32(const int* __restrict__ rowptr,
                                                    const int* __restrict__ csr_src,
                                                    const unsigned* __restrict__ m,
                                                    const float* __restrict__ bias,
                                                    const float* __restrict__ dinv,
                                                    float* __restrict__ outh) {
    int wave = (blockIdx.x * 256 + threadIdx.x) >> 6;
    if (wave >= N_NODES) return;
    int n = wave;
    int lane = threadIdx.x & 63;
    int c = lane * 2;
    int beg = rowptr[n], end = rowptr[n + 1];
    float2 acc = unpackbf(m[(size_t)n * 64 + lane]);
    int e = beg;
    for (; e + 4 <= end; e += 4) {
        int s0 = csr_src[e], s1 = csr_src[e + 1], s2 = csr_src[e + 2], s3 = csr_src[e + 3];
        float2 v0 = unpackbf(m[(size_t)s0 * 64 + lane]);
        float2 v1 = unpackbf(m[(size_t)s1 * 64 + lane]);
        float2 v2 = unpackbf(m[(size_t)s2 * 64 + lane]);
        float2 v3 = unpackbf(m[(size_t)s3 * 64 + lane]);
        acc.x += v0.x; acc.y += v0.y;
        acc.x += v1.x; acc.y += v1.y;
        acc.x += v2.x; acc.y += v2.y;
        acc.x += v3.x; acc.y += v3.y;
    }
    for (; e < end; ++e) {
        int s = csr_src[e];
        float2 v = unpackbf(m[(size_t)s * 64 + lane]);
        acc.x += v.x; acc.y += v.y;
    }
    float dv = dinv[n];
    float2 b = *(const float2*)&bias[c];
    float2 r;
    r.x = fmaxf(acc.x * dv + b.x, 0.f);
    r.y = fmaxf(acc.y * dv + b.y, 0.f);
    *(float2*)&outh[(size_t)n * HID + c] = r;
}

// ---------------- layer-2 transform via MFMA: m = bf16((h1 @ W2) * dinv) ----------------
__global__ __launch_bounds__(256) void k_xform2(const unsigned* __restrict__ h1b,
                                                const uint4* __restrict__ Bp,
                                                const float* __restrict__ dinv,
                                                unsigned short* __restrict__ mout) {
    int lane = threadIdx.x & 63;
    int wid = threadIdx.x >> 6;
    int row0 = blockIdx.x * 64 + wid * 16;
    int arow = row0 + (lane & 15);
    const uint4* hbase = (const uint4*)h1b;
    uint4 a_u[4];
#pragma unroll
    for (int kb = 0; kb < 4; ++kb)
        a_u[kb] = hbase[(size_t)arow * 16 + kb * 4 + (lane >> 4)];
    int rbase = row0 + (lane >> 4) * 4;
    float dv[4];
#pragma unroll
    for (int j = 0; j < 4; ++j) dv[j] = dinv[min(rbase + j, N_NODES - 1)];
#pragma unroll
    for (int ct = 0; ct < 8; ++ct) {
        f32x4 acc = {0.f, 0.f, 0.f, 0.f};
#pragma unroll
        for (int kb = 0; kb < 4; ++kb) {
            uint4 b_u = Bp[(ct * 4 + kb) * 64 + lane];
            acc = __builtin_amdgcn_mfma_f32_16x16x32_bf16(
                __builtin_bit_cast(short8, a_u[kb]),
                __builtin_bit_cast(short8, b_u), acc, 0, 0, 0);
        }
        int col = ct * 16 + (lane & 15);
#pragma unroll
        for (int j = 0; j < 4; ++j) {
            int r = rbase + j;
            if (r < N_NODES) mout[(size_t)r * HID + col] = f2bf(acc[j] * dv[j]);
        }
    }
}

// ---------------- node count per graph: binary search on sorted batch ----------------
__global__ __launch_bounds__(64) void k_cnt(const int* __restrict__ batch,
                                            int* __restrict__ cnt) {
    int g = threadIdx.x;
    if (g >= N_GRAPHS) return;
    int lo0 = 0, hi0 = N_NODES;
    while (lo0 < hi0) { int mid = (lo0 + hi0) >> 1; if (batch[mid] < g) lo0 = mid + 1; else hi0 = mid; }
    int lo1 = lo0, hi1 = N_NODES;
    while (lo1 < hi1) { int mid = (lo1 + hi1) >> 1; if (batch[mid] < g + 1) lo1 = mid + 1; else hi1 = mid; }
    cnt[g] = lo1 - lo0;
}

// ---------------- pooled sums: run-length accumulate (batch sorted) ----------------
#define POOL_CHUNK 512
__global__ __launch_bounds__(256) void k_pool(const float* __restrict__ h,
                                              const int* __restrict__ batch,
                                              float* __restrict__ pooled) {
    int t = threadIdx.x;
    int c = t & 127, half = t >> 7;
    int start = blockIdx.x * POOL_CHUNK;
    int end = min(start + POOL_CHUNK, N_NODES);
    float acc = 0.f;
    int cur = -1;
    for (int n = start + half; n < end; n += 2) {
        int g = batch[n];
        if (g != cur) {
            if (cur >= 0) atomicAdd(&pooled[cur * HID + c], acc);
            acc = 0.f;
            cur = g;
        }
        acc += h[(size_t)n * HID + c];
    }
    if (cur >= 0) atomicAdd(&pooled[cur * HID + c], acc);
}

// ---------------- final: out = (pooled/cnt) @ Wf + bf ----------------
__global__ __launch_bounds__(128) void k_final(const float* __restrict__ pooled,
                                               const int* __restrict__ cnt,
                                               const float* __restrict__ Wf,
                                               const float* __restrict__ bf,
                                               float* __restrict__ out) {
    __shared__ float p[HID];
    int g = blockIdx.x, t = threadIdx.x;
    float inv = 1.f / fmaxf((float)cnt[g], 1.f);
    p[t] = pooled[g * HID + t] * inv;
    __syncthreads();
    if (t < NCLS) {
        float acc = bf[t];
        for (int k = 0; k < HID; ++k) acc += p[k] * Wf[k * NCLS + t];
        out[g * NCLS + t] = acc;
    }
}

extern "C" void kernel_launch(void* const* d_in, const int* in_sizes, int n_in,
                              void* d_out, int out_size, void* d_ws, size_t ws_size,
                              hipStream_t stream) {
    const float* x   = (const float*)d_in[0];
    const int*   ei  = (const int*)d_in[1];   // [2][E] flat
    const int*   src = ei;
    const int*   dst = ei + N_EDGES;
    const int*   batch = (const int*)d_in[2];
    const float* W1 = (const float*)d_in[3];
    const float* b1 = (const float*)d_in[4];
    const float* W2 = (const float*)d_in[5];
    const float* b2 = (const float*)d_in[6];
    const float* Wf = (const float*)d_in[7];
    const float* bf = (const float*)d_in[8];
    float* out = (float*)d_out;

    char* ws = (char*)d_ws;
    size_t off = 0;
    unsigned* mbuf = (unsigned*)(ws + off);  off += (size_t)N_NODES * 64 * 4;   // 25.6 MB bf16 messages
    unsigned* h1b = (unsigned*)(ws + off);   off += (size_t)N_NODES * 64 * 4;   // 25.6 MB bf16 h1
    float* hbuf = (float*)(ws + off);        off += (size_t)N_NODES * HID * 4;  // 51.2 MB f32 h2
    int* csr_src = (int*)(ws + off);         off += (size_t)N_EDGES * 4;        // 6.4 MB
    uint4* Bp = (uint4*)(ws + off);          off += (size_t)2048 * 16;          // 32 KB
    int* deg = (int*)(ws + off);             off += (size_t)N_NODES * 4;
    float* dinv = (float*)(ws + off);        off += (size_t)N_NODES * 4;
    int* rowptr = (int*)(ws + off);          off += (size_t)(N_NODES + 1) * 4;
    int* cntm = (int*)(ws + off);            off += (size_t)NBUCK * NBF * 4;    // 400 KB
    int* offs = (int*)(ws + off);            off += (size_t)NBUCK * NBF * 4;    // 400 KB
    int* partials = (int*)(ws + off);        off += (size_t)SCAN_NB * 4;
    int* blockoff = (int*)(ws + off);        off += (size_t)SCAN_NB * 4;
    float* pooled = (float*)(ws + off);      off += (size_t)N_GRAPHS * HID * 4;
    int* cnt = (int*)(ws + off);             off += (size_t)N_GRAPHS * 4;
    // staging aliases hbuf: hbuf is only written after csr is built
    unsigned* staging = (unsigned*)hbuf;

    // graph preprocessing
    k_init<<<(N_NODES + 255) / 256, 256, 0, stream>>>(deg, pooled);
    k_deg_hist<<<NBF, 256, 0, stream>>>(dst, deg, cntm);
    k_dinv<<<(N_NODES + 255) / 256, 256, 0, stream>>>(deg, dinv);
    k_part<<<SCAN_NB, 256, 0, stream>>>(deg, partials);
    k_scanblk<<<1, 128, 0, stream>>>(partials, blockoff, rowptr);
    k_apply<<<SCAN_NB, 256, 0, stream>>>(deg, blockoff, rowptr);
    k_offs<<<NBUCK, NBF, 0, stream>>>(cntm, rowptr, offs);
    k_partition<<<NBF, 256, 0, stream>>>(src, dst, offs, staging);
    k_csrfill<<<NBUCK, 256, 0, stream>>>(staging, rowptr, csr_src);
    k_w2pack<<<8, 256, 0, stream>>>(W2, Bp);

    // layer 1
    k_xform1<<<N_NODES / 4, 256, 0, stream>>>(x, W1, dinv, mbuf);
    k_gather_bf<<<(N_NODES + 3) / 4, 256, 0, stream>>>(rowptr, csr_src, mbuf, b1, dinv, h1b);

    // layer 2 (MFMA transform; overwrites mbuf — dead after gather1)
    k_xform2<<<(N_NODES + 63) / 64, 256, 0, stream>>>(h1b, Bp, dinv, (unsigned short*)mbuf);
    k_gather_f32<<<(N_NODES + 3) / 4, 256, 0, stream>>>(rowptr, csr_src, mbuf, b2, dinv, hbuf);

    // pooling + classifier
    k_cnt<<<1, 64, 0, stream>>>(batch, cnt);
    k_pool<<<(N_NODES + POOL_CHUNK - 1) / POOL_CHUNK, 256, 0, stream>>>(hbuf, batch, pooled);
    k_final<<<N_GRAPHS, 128, 0, stream>>>(pooled, cnt, Wf, bf, out);
}

// Round 8
// 345.572 us; speedup vs baseline: 10.1500x; 1.1929x over previous
//
#include <hip/hip_runtime.h>

#define N_NODES 100000
#define N_EDGES 1600000
#define N_GRAPHS 64
#define IN_CH 15
#define HID 128
#define NCLS 11

// bucketed CSR-fill geometry
#define NBUCK 196            // ceil(100000 / 512), bucket = dst >> 9
#define NBF 512              // partition blocks
#define EPB (N_EDGES / NBF)  // 3125 edges per block

using short8 = __attribute__((ext_vector_type(8))) short;
using f32x4 = __attribute__((ext_vector_type(4))) float;

// ---- bf16 pack/unpack (RNE) ----
__device__ __forceinline__ unsigned short f2bf(float f) {
    unsigned u = __builtin_bit_cast(unsigned, f);
    u += 0x7FFF + ((u >> 16) & 1);
    return (unsigned short)(u >> 16);
}
__device__ __forceinline__ unsigned packbf(float a, float b) {
    return (unsigned)f2bf(a) | ((unsigned)f2bf(b) << 16);
}
__device__ __forceinline__ float2 unpackbf(unsigned v) {
    float2 r;
    unsigned lo = v << 16;
    unsigned hi = v & 0xFFFF0000u;
    r.x = __builtin_bit_cast(float, lo);
    r.y = __builtin_bit_cast(float, hi);
    return r;
}

// ---------------- init: deg=0, pooled=0 ----------------
__global__ __launch_bounds__(256) void k_init(int* __restrict__ deg,
                                              float* __restrict__ pooled) {
    int i = blockIdx.x * 256 + threadIdx.x;
    if (i < N_NODES) deg[i] = 0;
    if (i < N_GRAPHS * HID) pooled[i] = 0.f;
}

// ---------------- deg atomics + per-block bucket histogram ----------------
__global__ __launch_bounds__(256) void k_deg_hist(const int* __restrict__ dst,
                                                  int* __restrict__ deg,
                                                  int* __restrict__ cntm) {
    __shared__ int hist[NBUCK];
    int t = threadIdx.x;
    for (int i = t; i < NBUCK; i += 256) hist[i] = 0;
    __syncthreads();
    int base = blockIdx.x * EPB;
#pragma unroll
    for (int i = 0; i < (EPB + 255) / 256; ++i) {
        int e = i * 256 + t;
        if (e < EPB) {
            int d = dst[base + e];
            atomicAdd(&deg[d], 1);
            atomicAdd(&hist[d >> 9], 1);
        }
    }
    __syncthreads();
    for (int b = t; b < NBUCK; b += 256)
        cntm[b * NBF + blockIdx.x] = hist[b];
}

__global__ __launch_bounds__(256) void k_dinv(const int* __restrict__ deg,
                                              float* __restrict__ dinv) {
    int i = blockIdx.x * 256 + threadIdx.x;
    if (i < N_NODES) dinv[i] = rsqrtf((float)(deg[i] + 1));  // +1 self-loop
}

// ---------------- multi-block exclusive scan of deg -> rowptr ----------------
#define SCAN_BLK 1024
#define SCAN_NB ((N_NODES + SCAN_BLK - 1) / SCAN_BLK)  // 98
__global__ __launch_bounds__(256) void k_part(const int* __restrict__ deg,
                                              int* __restrict__ partials) {
    __shared__ int red[256];
    int t = threadIdx.x;
    int base = blockIdx.x * SCAN_BLK + t * 4;
    int s = 0;
#pragma unroll
    for (int i = 0; i < 4; ++i) {
        int idx = base + i;
        if (idx < N_NODES) s += deg[idx];
    }
    red[t] = s;
    __syncthreads();
    for (int off = 128; off > 0; off >>= 1) {
        if (t < off) red[t] += red[t + off];
        __syncthreads();
    }
    if (t == 0) partials[blockIdx.x] = red[0];
}

__global__ __launch_bounds__(128) void k_scanblk(const int* __restrict__ partials,
                                                 int* __restrict__ blockoff,
                                                 int* __restrict__ rowptr) {
    __shared__ int arr[128];
    int t = threadIdx.x;
    arr[t] = (t < SCAN_NB) ? partials[t] : 0;
    __syncthreads();
    for (int off = 1; off < 128; off <<= 1) {
        int v = (t >= off) ? arr[t - off] : 0;
        __syncthreads();
        arr[t] += v;
        __syncthreads();
    }
    if (t < SCAN_NB) blockoff[t] = (t == 0) ? 0 : arr[t - 1];
    if (t == 0) rowptr[N_NODES] = N_EDGES;
}

__global__ __launch_bounds__(256) void k_apply(const int* __restrict__ deg,
                                               const int* __restrict__ blockoff,
                                               int* __restrict__ rowptr) {
    __shared__ int arr[256];
    int t = threadIdx.x;
    int base = blockIdx.x * SCAN_BLK + t * 4;
    int d[4];
    int s = 0;
#pragma unroll
    for (int i = 0; i < 4; ++i) {
        int idx = base + i;
        d[i] = (idx < N_NODES) ? deg[idx] : 0;
        s += d[i];
    }
    arr[t] = s;
    __syncthreads();
    for (int off = 1; off < 256; off <<= 1) {
        int v = (t >= off) ? arr[t - off] : 0;
        __syncthreads();
        arr[t] += v;
        __syncthreads();
    }
    int run = blockoff[blockIdx.x] + ((t == 0) ? 0 : arr[t - 1]);
#pragma unroll
    for (int i = 0; i < 4; ++i) {
        int idx = base + i;
        if (idx < N_NODES) {
            rowptr[idx] = run;
            run += d[i];
        }
    }
}

// ---------------- per-(bucket,block) partition offsets ----------------
__global__ __launch_bounds__(NBF) void k_offs(const int* __restrict__ cntm,
                                              const int* __restrict__ rowptr,
                                              int* __restrict__ offs) {
    __shared__ int arr[NBF];
    int b = blockIdx.x, t = threadIdx.x;
    arr[t] = cntm[b * NBF + t];
    __syncthreads();
    for (int off = 1; off < NBF; off <<= 1) {
        int v = (t >= off) ? arr[t - off] : 0;
        __syncthreads();
        arr[t] += v;
        __syncthreads();
    }
    int base = rowptr[b << 9];
    offs[b * NBF + t] = base + ((t == 0) ? 0 : arr[t - 1]);
}

// ---------------- partition: edges -> staging, grouped by 512-node bucket ----------------
// packed: (dst & 511) << 17 | src   (src < 2^17)
__global__ __launch_bounds__(256) void k_partition(const int* __restrict__ src,
                                                   const int* __restrict__ dst,
                                                   const int* __restrict__ offs,
                                                   unsigned* __restrict__ staging) {
    __shared__ int cur[NBUCK];
    int t = threadIdx.x;
    for (int b = t; b < NBUCK; b += 256) cur[b] = offs[b * NBF + blockIdx.x];
    __syncthreads();
    int base = blockIdx.x * EPB;
#pragma unroll
    for (int i = 0; i < (EPB + 255) / 256; ++i) {
        int e = i * 256 + t;
        if (e < EPB) {
            int d = dst[base + e];
            int s = src[base + e];
            int slot = atomicAdd(&cur[d >> 9], 1);
            staging[slot] = ((unsigned)(d & 511) << 17) | (unsigned)s;
        }
    }
}

// ---------------- csr fill: one block per bucket, LDS node cursors ----------------
__global__ __launch_bounds__(256) void k_csrfill(const unsigned* __restrict__ staging,
                                                 const int* __restrict__ rowptr,
                                                 int* __restrict__ csr_src) {
    __shared__ int cur[512];
    int b = blockIdx.x, t = threadIdx.x;
    int n0 = b << 9;
#pragma unroll
    for (int i = 0; i < 2; ++i) {
        int n = n0 + t + i * 256;
        cur[t + i * 256] = (n < N_NODES) ? rowptr[n] : 0;
    }
    __syncthreads();
    int beg = rowptr[n0];
    int end = rowptr[min(n0 + 512, N_NODES)];
    for (int e = beg + t; e < end; e += 256) {
        unsigned v = staging[e];
        int nloc = v >> 17;
        int pos = atomicAdd(&cur[nloc], 1);
        csr_src[pos] = (int)(v & 0x1FFFFu);
    }
}

// ---------------- W2 -> MFMA B-fragment layout, bf16 ----------------
__global__ __launch_bounds__(256) void k_w2pack(const float* __restrict__ W2,
                                                uint4* __restrict__ Bp) {
    int i = blockIdx.x * 256 + threadIdx.x;  // 2048 slots
    if (i >= 2048) return;
    int lane = i & 63;
    int kb = (i >> 6) & 3;
    int ct = i >> 8;
    int col = ct * 16 + (lane & 15);
    int k0 = kb * 32 + ((lane >> 4) & 3) * 8;
    unsigned w[4];
#pragma unroll
    for (int p = 0; p < 4; ++p) {
        int k = k0 + 2 * p;
        w[p] = packbf(W2[k * HID + col], W2[(k + 1) * HID + col]);
    }
    Bp[i] = make_uint4(w[0], w[1], w[2], w[3]);
}

// ---------------- layer-1 transform: m = bf16((x @ W1) * dinv) ----------------
__global__ __launch_bounds__(256) void k_xform1(const float* __restrict__ x,
                                                const float* __restrict__ W1,
                                                const float* __restrict__ dinv,
                                                unsigned* __restrict__ m) {
    __shared__ float w[IN_CH * HID];  // 7.5 KB
    int t = threadIdx.x;
    for (int i = t; i < IN_CH * HID; i += 256) w[i] = W1[i];
    __syncthreads();
    int node = blockIdx.x * 4 + (t >> 6);
    int lane = t & 63;
    int c = lane * 2;
    const float* xr = x + node * IN_CH;
    float a0 = 0.f, a1 = 0.f;
#pragma unroll
    for (int k = 0; k < IN_CH; ++k) {
        float xv = xr[k];
        a0 += xv * w[k * HID + c];
        a1 += xv * w[k * HID + c + 1];
    }
    float dv = dinv[node];
    m[(size_t)node * 64 + lane] = packbf(a0 * dv, a1 * dv);
}

// ---------------- gather (bf16 out): h1 = relu(dinv*(m[n]+sum m[src])+b) ----------------
__global__ __launch_bounds__(256) void k_gather_bf(const int* __restrict__ rowptr,
                                                   const int* __restrict__ csr_src,
                                                   const unsigned* __restrict__ m,
                                                   const float* __restrict__ bias,
                                                   const float* __restrict__ dinv,
                                                   unsigned* __restrict__ outh) {
    int wave = (blockIdx.x * 256 + threadIdx.x) >> 6;
    if (wave >= N_NODES) return;
    int n = wave;
    int lane = threadIdx.x & 63;
    int c = lane * 2;
    int beg = rowptr[n], end = rowptr[n + 1];
    float2 acc = unpackbf(m[(size_t)n * 64 + lane]);  // self-loop term
    int e = beg;
    for (; e + 4 <= end; e += 4) {
        int s0 = csr_src[e], s1 = csr_src[e + 1], s2 = csr_src[e + 2], s3 = csr_src[e + 3];
        float2 v0 = unpackbf(m[(size_t)s0 * 64 + lane]);
        float2 v1 = unpackbf(m[(size_t)s1 * 64 + lane]);
        float2 v2 = unpackbf(m[(size_t)s2 * 64 + lane]);
        float2 v3 = unpackbf(m[(size_t)s3 * 64 + lane]);
        acc.x += v0.x; acc.y += v0.y;
        acc.x += v1.x; acc.y += v1.y;
        acc.x += v2.x; acc.y += v2.y;
        acc.x += v3.x; acc.y += v3.y;
    }
    for (; e < end; ++e) {
        int s = csr_src[e];
        float2 v = unpackbf(m[(size_t)s * 64 + lane]);
        acc.x += v.x; acc.y += v.y;
    }
    float dv = dinv[n];
    float2 b = *(const float2*)&bias[c];
    float rx = fmaxf(acc.x * dv + b.x, 0.f);
    float ry = fmaxf(acc.y * dv + b.y, 0.f);
    outh[(size_t)n * 64 + lane] = packbf(rx, ry);
}

// ---------------- gather (f32 out): h2 for pooling ----------------
__global__ __launch_bounds__(256) void k_gather_f32(const int* __restrict__ rowptr,
                                                    const int* __restrict__ csr_src,
                                                    const unsigned* __restrict__ m,
                                                    const float* __restrict__ bias,
                                                    const float* __restrict__ dinv,
                                                    float* __restrict__ outh) {
    int wave = (blockIdx.x * 256 + threadIdx.x) >> 6;
    if (wave >= N_NODES) return;
    int n = wave;
    int lane = threadIdx.x & 63;
    int c = lane * 2;
    int beg = rowptr[n], end = rowptr[n + 1];
    float2 acc = unpackbf(m[(size_t)n * 64 + lane]);
    int e = beg;
    for (; e + 4 <= end; e += 4) {
        int s0 = csr_src[e], s1 = csr_src[e + 1], s2 = csr_src[e + 2], s3 = csr_src[e + 3];
        float2 v0 = unpackbf(m[(size_t)s0 * 64 + lane]);
        float2 v1 = unpackbf(m[(size_t)s1 * 64 + lane]);
        float2 v2 = unpackbf(m[(size_t)s2 * 64 + lane]);
        float2 v3 = unpackbf(m[(size_t)s3 * 64 + lane]);
        acc.x += v0.x; acc.y += v0.y;
        acc.x += v1.x; acc.y += v1.y;
        acc.x += v2.x; acc.y += v2.y;
        acc.x += v3.x; acc.y += v3.y;
    }
    for (; e < end; ++e) {
        int s = csr_src[e];
        float2 v = unpackbf(m[(size_t)s * 64 + lane]);
        acc.x += v.x; acc.y += v.y;
    }
    float dv = dinv[n];
    float2 b = *(const float2*)&bias[c];
    float2 r;
    r.x = fmaxf(acc.x * dv + b.x, 0.f);
    r.y = fmaxf(acc.y * dv + b.y, 0.f);
    *(float2*)&outh[(size_t)n * HID + c] = r;
}

// ---------------- layer-2 transform via MFMA: m = bf16((h1 @ W2) * dinv) ----------------
__global__ __launch_bounds__(256) void k_xform2(const unsigned* __restrict__ h1b,
                                                const uint4* __restrict__ Bp,
                                                const float* __restrict__ dinv,
                                                unsigned short* __restrict__ mout) {
    int lane = threadIdx.x & 63;
    int wid = threadIdx.x >> 6;
    int row0 = blockIdx.x * 64 + wid * 16;
    int arow = row0 + (lane & 15);
    const uint4* hbase = (const uint4*)h1b;
    uint4 a_u[4];
#pragma unroll
    for (int kb = 0; kb < 4; ++kb)
        a_u[kb] = hbase[(size_t)arow * 16 + kb * 4 + (lane >> 4)];
    int rbase = row0 + (lane >> 4) * 4;
    float dv[4];
#pragma unroll
    for (int j = 0; j < 4; ++j) dv[j] = dinv[min(rbase + j, N_NODES - 1)];
#pragma unroll
    for (int ct = 0; ct < 8; ++ct) {
        f32x4 acc = {0.f, 0.f, 0.f, 0.f};
#pragma unroll
        for (int kb = 0; kb < 4; ++kb) {
            uint4 b_u = Bp[(ct * 4 + kb) * 64 + lane];
            acc = __builtin_amdgcn_mfma_f32_16x16x32_bf16(
                __builtin_bit_cast(short8, a_u[kb]),
                __builtin_bit_cast(short8, b_u), acc, 0, 0, 0);
        }
        int col = ct * 16 + (lane & 15);
#pragma unroll
        for (int j = 0; j < 4; ++j) {
            int r = rbase + j;
            if (r < N_NODES) mout[(size_t)r * HID + col] = f2bf(acc[j] * dv[j]);
        }
    }
}

// ---------------- node count per graph: binary search on sorted batch ----------------
__global__ __launch_bounds__(64) void k_cnt(const int* __restrict__ batch,
                                            int* __restrict__ cnt) {
    int g = threadIdx.x;
    if (g >= N_GRAPHS) return;
    int lo0 = 0, hi0 = N_NODES;
    while (lo0 < hi0) { int mid = (lo0 + hi0) >> 1; if (batch[mid] < g) lo0 = mid + 1; else hi0 = mid; }
    int lo1 = lo0, hi1 = N_NODES;
    while (lo1 < hi1) { int mid = (lo1 + hi1) >> 1; if (batch[mid] < g + 1) lo1 = mid + 1; else hi1 = mid; }
    cnt[g] = lo1 - lo0;
}

// ---------------- pooled sums: run-length accumulate (batch sorted) ----------------
// POOL_CHUNK=64: 1563 blocks (~6/CU) — was 512 -> 196 blocks, 8% occupancy,
// latency-bound at 85us. Atomic flushes ~416k over 8192 addrs, no intra-wave
// same-address collisions (lanes own distinct channels).
#define POOL_CHUNK 64
__global__ __launch_bounds__(256) void k_pool(const float* __restrict__ h,
                                              const int* __restrict__ batch,
                                              float* __restrict__ pooled) {
    int t = threadIdx.x;
    int c = t & 127, half = t >> 7;
    int start = blockIdx.x * POOL_CHUNK;
    int end = min(start + POOL_CHUNK, N_NODES);
    float acc = 0.f;
    int cur = -1;
    for (int n = start + half; n < end; n += 2) {
        int g = batch[n];
        if (g != cur) {
            if (cur >= 0) atomicAdd(&pooled[cur * HID + c], acc);
            acc = 0.f;
            cur = g;
        }
        acc += h[(size_t)n * HID + c];
    }
    if (cur >= 0) atomicAdd(&pooled[cur * HID + c], acc);
}

// ---------------- final: out = (pooled/cnt) @ Wf + bf ----------------
__global__ __launch_bounds__(128) void k_final(const float* __restrict__ pooled,
                                               const int* __restrict__ cnt,
                                               const float* __restrict__ Wf,
                                               const float* __restrict__ bf,
                                               float* __restrict__ out) {
    __shared__ float p[HID];
    int g = blockIdx.x, t = threadIdx.x;
    float inv = 1.f / fmaxf((float)cnt[g], 1.f);
    p[t] = pooled[g * HID + t] * inv;
    __syncthreads();
    if (t < NCLS) {
        float acc = bf[t];
        for (int k = 0; k < HID; ++k) acc += p[k] * Wf[k * NCLS + t];
        out[g * NCLS + t] = acc;
    }
}

extern "C" void kernel_launch(void* const* d_in, const int* in_sizes, int n_in,
                              void* d_out, int out_size, void* d_ws, size_t ws_size,
                              hipStream_t stream) {
    const float* x   = (const float*)d_in[0];
    const int*   ei  = (const int*)d_in[1];   // [2][E] flat
    const int*   src = ei;
    const int*   dst = ei + N_EDGES;
    const int*   batch = (const int*)d_in[2];
    const float* W1 = (const float*)d_in[3];
    const float* b1 = (const float*)d_in[4];
    const float* W2 = (const float*)d_in[5];
    const float* b2 = (const float*)d_in[6];
    const float* Wf = (const float*)d_in[7];
    const float* bf = (const float*)d_in[8];
    float* out = (float*)d_out;

    char* ws = (char*)d_ws;
    size_t off = 0;
    unsigned* mbuf = (unsigned*)(ws + off);  off += (size_t)N_NODES * 64 * 4;   // 25.6 MB bf16 messages
    unsigned* h1b = (unsigned*)(ws + off);   off += (size_t)N_NODES * 64 * 4;   // 25.6 MB bf16 h1
    float* hbuf = (float*)(ws + off);        off += (size_t)N_NODES * HID * 4;  // 51.2 MB f32 h2
    int* csr_src = (int*)(ws + off);         off += (size_t)N_EDGES * 4;        // 6.4 MB
    uint4* Bp = (uint4*)(ws + off);          off += (size_t)2048 * 16;          // 32 KB
    int* deg = (int*)(ws + off);             off += (size_t)N_NODES * 4;
    float* dinv = (float*)(ws + off);        off += (size_t)N_NODES * 4;
    int* rowptr = (int*)(ws + off);          off += (size_t)(N_NODES + 1) * 4;
    int* cntm = (int*)(ws + off);            off += (size_t)NBUCK * NBF * 4;    // 400 KB
    int* offs = (int*)(ws + off);            off += (size_t)NBUCK * NBF * 4;    // 400 KB
    int* partials = (int*)(ws + off);        off += (size_t)SCAN_NB * 4;
    int* blockoff = (int*)(ws + off);        off += (size_t)SCAN_NB * 4;
    float* pooled = (float*)(ws + off);      off += (size_t)N_GRAPHS * HID * 4;
    int* cnt = (int*)(ws + off);             off += (size_t)N_GRAPHS * 4;
    // staging aliases hbuf: hbuf is only written after csr is built
    unsigned* staging = (unsigned*)hbuf;

    // graph preprocessing
    k_init<<<(N_NODES + 255) / 256, 256, 0, stream>>>(deg, pooled);
    k_deg_hist<<<NBF, 256, 0, stream>>>(dst, deg, cntm);
    k_dinv<<<(N_NODES + 255) / 256, 256, 0, stream>>>(deg, dinv);
    k_part<<<SCAN_NB, 256, 0, stream>>>(deg, partials);
    k_scanblk<<<1, 128, 0, stream>>>(partials, blockoff, rowptr);
    k_apply<<<SCAN_NB, 256, 0, stream>>>(deg, blockoff, rowptr);
    k_offs<<<NBUCK, NBF, 0, stream>>>(cntm, rowptr, offs);
    k_partition<<<NBF, 256, 0, stream>>>(src, dst, offs, staging);
    k_csrfill<<<NBUCK, 256, 0, stream>>>(staging, rowptr, csr_src);
    k_w2pack<<<8, 256, 0, stream>>>(W2, Bp);

    // layer 1
    k_xform1<<<N_NODES / 4, 256, 0, stream>>>(x, W1, dinv, mbuf);
    k_gather_bf<<<(N_NODES + 3) / 4, 256, 0, stream>>>(rowptr, csr_src, mbuf, b1, dinv, h1b);

    // layer 2 (MFMA transform; overwrites mbuf — dead after gather1)
    k_xform2<<<(N_NODES + 63) / 64, 256, 0, stream>>>(h1b, Bp, dinv, (unsigned short*)mbuf);
    k_gather_f32<<<(N_NODES + 3) / 4, 256, 0, stream>>>(rowptr, csr_src, mbuf, b2, dinv, hbuf);

    // pooling + classifier
    k_cnt<<<1, 64, 0, stream>>>(batch, cnt);
    k_pool<<<(N_NODES + POOL_CHUNK - 1) / POOL_CHUNK, 256, 0, stream>>>(hbuf, batch, pooled);
    k_final<<<N_GRAPHS, 128, 0, stream>>>(pooled, cnt, Wf, bf, out);
}

// Round 9
// 331.999 us; speedup vs baseline: 10.5649x; 1.0409x over previous
//
#include <hip/hip_runtime.h>

#define N_NODES 100000
#define N_EDGES 1600000
#define N_GRAPHS 64
#define IN_CH 15
#define HID 128
#define NCLS 11

// bucketed CSR-fill geometry
#define NBUCK 196            // ceil(100000 / 512), bucket = dst >> 9
#define NBF 512              // partition blocks
#define EPB (N_EDGES / NBF)  // 3125 edges per block

using short8 = __attribute__((ext_vector_type(8))) short;
using f32x4 = __attribute__((ext_vector_type(4))) float;

// ---- bf16 pack/unpack (RNE) ----
__device__ __forceinline__ unsigned short f2bf(float f) {
    unsigned u = __builtin_bit_cast(unsigned, f);
    u += 0x7FFF + ((u >> 16) & 1);
    return (unsigned short)(u >> 16);
}
__device__ __forceinline__ unsigned packbf(float a, float b) {
    return (unsigned)f2bf(a) | ((unsigned)f2bf(b) << 16);
}
__device__ __forceinline__ float2 unpackbf(unsigned v) {
    float2 r;
    unsigned lo = v << 16;
    unsigned hi = v & 0xFFFF0000u;
    r.x = __builtin_bit_cast(float, lo);
    r.y = __builtin_bit_cast(float, hi);
    return r;
}

// ---------------- init: deg=0, pooled=0 ----------------
__global__ __launch_bounds__(256) void k_init(int* __restrict__ deg,
                                              float* __restrict__ pooled) {
    int i = blockIdx.x * 256 + threadIdx.x;
    if (i < N_NODES) deg[i] = 0;
    if (i < N_GRAPHS * HID) pooled[i] = 0.f;
}

// ---------------- deg atomics + per-block bucket histogram ----------------
__global__ __launch_bounds__(256) void k_deg_hist(const int* __restrict__ dst,
                                                  int* __restrict__ deg,
                                                  int* __restrict__ cntm) {
    __shared__ int hist[NBUCK];
    int t = threadIdx.x;
    for (int i = t; i < NBUCK; i += 256) hist[i] = 0;
    __syncthreads();
    int base = blockIdx.x * EPB;
#pragma unroll
    for (int i = 0; i < (EPB + 255) / 256; ++i) {
        int e = i * 256 + t;
        if (e < EPB) {
            int d = dst[base + e];
            atomicAdd(&deg[d], 1);
            atomicAdd(&hist[d >> 9], 1);
        }
    }
    __syncthreads();
    for (int b = t; b < NBUCK; b += 256)
        cntm[b * NBF + blockIdx.x] = hist[b];
}

__global__ __launch_bounds__(256) void k_dinv(const int* __restrict__ deg,
                                              float* __restrict__ dinv) {
    int i = blockIdx.x * 256 + threadIdx.x;
    if (i < N_NODES) dinv[i] = rsqrtf((float)(deg[i] + 1));  // +1 self-loop
}

// ---------------- multi-block exclusive scan of deg -> rowptr ----------------
#define SCAN_BLK 1024
#define SCAN_NB ((N_NODES + SCAN_BLK - 1) / SCAN_BLK)  // 98
__global__ __launch_bounds__(256) void k_part(const int* __restrict__ deg,
                                              int* __restrict__ partials) {
    __shared__ int red[256];
    int t = threadIdx.x;
    int base = blockIdx.x * SCAN_BLK + t * 4;
    int s = 0;
#pragma unroll
    for (int i = 0; i < 4; ++i) {
        int idx = base + i;
        if (idx < N_NODES) s += deg[idx];
    }
    red[t] = s;
    __syncthreads();
    for (int off = 128; off > 0; off >>= 1) {
        if (t < off) red[t] += red[t + off];
        __syncthreads();
    }
    if (t == 0) partials[blockIdx.x] = red[0];
}

__global__ __launch_bounds__(128) void k_scanblk(const int* __restrict__ partials,
                                                 int* __restrict__ blockoff,
                                                 int* __restrict__ rowptr) {
    __shared__ int arr[128];
    int t = threadIdx.x;
    arr[t] = (t < SCAN_NB) ? partials[t] : 0;
    __syncthreads();
    for (int off = 1; off < 128; off <<= 1) {
        int v = (t >= off) ? arr[t - off] : 0;
        __syncthreads();
        arr[t] += v;
        __syncthreads();
    }
    if (t < SCAN_NB) blockoff[t] = (t == 0) ? 0 : arr[t - 1];
    if (t == 0) rowptr[N_NODES] = N_EDGES;
}

__global__ __launch_bounds__(256) void k_apply(const int* __restrict__ deg,
                                               const int* __restrict__ blockoff,
                                               int* __restrict__ rowptr) {
    __shared__ int arr[256];
    int t = threadIdx.x;
    int base = blockIdx.x * SCAN_BLK + t * 4;
    int d[4];
    int s = 0;
#pragma unroll
    for (int i = 0; i < 4; ++i) {
        int idx = base + i;
        d[i] = (idx < N_NODES) ? deg[idx] : 0;
        s += d[i];
    }
    arr[t] = s;
    __syncthreads();
    for (int off = 1; off < 256; off <<= 1) {
        int v = (t >= off) ? arr[t - off] : 0;
        __syncthreads();
        arr[t] += v;
        __syncthreads();
    }
    int run = blockoff[blockIdx.x] + ((t == 0) ? 0 : arr[t - 1]);
#pragma unroll
    for (int i = 0; i < 4; ++i) {
        int idx = base + i;
        if (idx < N_NODES) {
            rowptr[idx] = run;
            run += d[i];
        }
    }
}

// ---------------- per-(bucket,block) partition offsets ----------------
__global__ __launch_bounds__(NBF) void k_offs(const int* __restrict__ cntm,
                                              const int* __restrict__ rowptr,
                                              int* __restrict__ offs) {
    __shared__ int arr[NBF];
    int b = blockIdx.x, t = threadIdx.x;
    arr[t] = cntm[b * NBF + t];
    __syncthreads();
    for (int off = 1; off < NBF; off <<= 1) {
        int v = (t >= off) ? arr[t - off] : 0;
        __syncthreads();
        arr[t] += v;
        __syncthreads();
    }
    int base = rowptr[b << 9];
    offs[b * NBF + t] = base + ((t == 0) ? 0 : arr[t - 1]);
}

// ---------------- partition: edges -> staging, grouped by 512-node bucket ----------------
// packed: (dst & 511) << 17 | src   (src < 2^17)
__global__ __launch_bounds__(256) void k_partition(const int* __restrict__ src,
                                                   const int* __restrict__ dst,
                                                   const int* __restrict__ offs,
                                                   unsigned* __restrict__ staging) {
    __shared__ int cur[NBUCK];
    int t = threadIdx.x;
    for (int b = t; b < NBUCK; b += 256) cur[b] = offs[b * NBF + blockIdx.x];
    __syncthreads();
    int base = blockIdx.x * EPB;
#pragma unroll
    for (int i = 0; i < (EPB + 255) / 256; ++i) {
        int e = i * 256 + t;
        if (e < EPB) {
            int d = dst[base + e];
            int s = src[base + e];
            int slot = atomicAdd(&cur[d >> 9], 1);
            staging[slot] = ((unsigned)(d & 511) << 17) | (unsigned)s;
        }
    }
}

// ---------------- csr fill: one block per bucket, LDS node cursors ----------------
__global__ __launch_bounds__(256) void k_csrfill(const unsigned* __restrict__ staging,
                                                 const int* __restrict__ rowptr,
                                                 int* __restrict__ csr_src) {
    __shared__ int cur[512];
    int b = blockIdx.x, t = threadIdx.x;
    int n0 = b << 9;
#pragma unroll
    for (int i = 0; i < 2; ++i) {
        int n = n0 + t + i * 256;
        cur[t + i * 256] = (n < N_NODES) ? rowptr[n] : 0;
    }
    __syncthreads();
    int beg = rowptr[n0];
    int end = rowptr[min(n0 + 512, N_NODES)];
    for (int e = beg + t; e < end; e += 256) {
        unsigned v = staging[e];
        int nloc = v >> 17;
        int pos = atomicAdd(&cur[nloc], 1);
        csr_src[pos] = (int)(v & 0x1FFFFu);
    }
}

// ---------------- W2 -> MFMA B-fragment layout, bf16 ----------------
__global__ __launch_bounds__(256) void k_w2pack(const float* __restrict__ W2,
                                                uint4* __restrict__ Bp) {
    int i = blockIdx.x * 256 + threadIdx.x;  // 2048 slots
    if (i >= 2048) return;
    int lane = i & 63;
    int kb = (i >> 6) & 3;
    int ct = i >> 8;
    int col = ct * 16 + (lane & 15);
    int k0 = kb * 32 + ((lane >> 4) & 3) * 8;
    unsigned w[4];
#pragma unroll
    for (int p = 0; p < 4; ++p) {
        int k = k0 + 2 * p;
        w[p] = packbf(W2[k * HID + col], W2[(k + 1) * HID + col]);
    }
    Bp[i] = make_uint4(w[0], w[1], w[2], w[3]);
}

// ---------------- layer-1 transform: m = bf16((x @ W1) * dinv) ----------------
__global__ __launch_bounds__(256) void k_xform1(const float* __restrict__ x,
                                                const float* __restrict__ W1,
                                                const float* __restrict__ dinv,
                                                unsigned* __restrict__ m) {
    __shared__ float w[IN_CH * HID];  // 7.5 KB
    int t = threadIdx.x;
    for (int i = t; i < IN_CH * HID; i += 256) w[i] = W1[i];
    __syncthreads();
    int node = blockIdx.x * 4 + (t >> 6);
    int lane = t & 63;
    int c = lane * 2;
    const float* xr = x + node * IN_CH;
    float a0 = 0.f, a1 = 0.f;
#pragma unroll
    for (int k = 0; k < IN_CH; ++k) {
        float xv = xr[k];
        a0 += xv * w[k * HID + c];
        a1 += xv * w[k * HID + c + 1];
    }
    float dv = dinv[node];
    m[(size_t)node * 64 + lane] = packbf(a0 * dv, a1 * dv);
}

// ---------------- gather: out = bf16(relu(dinv*(m[n]+sum m[src])+b)) ----------------
// one wave per node; lane holds one packed uint (2 bf16 ch); f32 accumulate.
// unroll-8: 8 independent 256B row loads in flight per iteration (latency-bound fix)
__global__ __launch_bounds__(256) void k_gather(const int* __restrict__ rowptr,
                                                const int* __restrict__ csr_src,
                                                const unsigned* __restrict__ m,
                                                const float* __restrict__ bias,
                                                const float* __restrict__ dinv,
                                                unsigned* __restrict__ outh) {
    int wave = (blockIdx.x * 256 + threadIdx.x) >> 6;
    if (wave >= N_NODES) return;
    int n = wave;
    int lane = threadIdx.x & 63;
    int c = lane * 2;
    int beg = rowptr[n], end = rowptr[n + 1];
    float2 acc = unpackbf(m[(size_t)n * 64 + lane]);  // self-loop term
    int e = beg;
    for (; e + 8 <= end; e += 8) {
        int s0 = csr_src[e + 0], s1 = csr_src[e + 1], s2 = csr_src[e + 2], s3 = csr_src[e + 3];
        int s4 = csr_src[e + 4], s5 = csr_src[e + 5], s6 = csr_src[e + 6], s7 = csr_src[e + 7];
        unsigned v0 = m[(size_t)s0 * 64 + lane];
        unsigned v1 = m[(size_t)s1 * 64 + lane];
        unsigned v2 = m[(size_t)s2 * 64 + lane];
        unsigned v3 = m[(size_t)s3 * 64 + lane];
        unsigned v4 = m[(size_t)s4 * 64 + lane];
        unsigned v5 = m[(size_t)s5 * 64 + lane];
        unsigned v6 = m[(size_t)s6 * 64 + lane];
        unsigned v7 = m[(size_t)s7 * 64 + lane];
        float2 f0 = unpackbf(v0), f1 = unpackbf(v1), f2 = unpackbf(v2), f3 = unpackbf(v3);
        float2 f4 = unpackbf(v4), f5 = unpackbf(v5), f6 = unpackbf(v6), f7 = unpackbf(v7);
        acc.x += f0.x + f1.x + f2.x + f3.x + f4.x + f5.x + f6.x + f7.x;
        acc.y += f0.y + f1.y + f2.y + f3.y + f4.y + f5.y + f6.y + f7.y;
    }
    for (; e + 2 <= end; e += 2) {
        int s0 = csr_src[e], s1 = csr_src[e + 1];
        unsigned v0 = m[(size_t)s0 * 64 + lane];
        unsigned v1 = m[(size_t)s1 * 64 + lane];
        float2 f0 = unpackbf(v0), f1 = unpackbf(v1);
        acc.x += f0.x + f1.x;
        acc.y += f0.y + f1.y;
    }
    if (e < end) {
        float2 f = unpackbf(m[(size_t)csr_src[e] * 64 + lane]);
        acc.x += f.x; acc.y += f.y;
    }
    float dv = dinv[n];
    float2 b = *(const float2*)&bias[c];
    float rx = fmaxf(acc.x * dv + b.x, 0.f);
    float ry = fmaxf(acc.y * dv + b.y, 0.f);
    outh[(size_t)n * 64 + lane] = packbf(rx, ry);
}

// ---------------- layer-2 transform via MFMA: m = bf16((h1 @ W2) * dinv) ----------------
__global__ __launch_bounds__(256) void k_xform2(const unsigned* __restrict__ h1b,
                                                const uint4* __restrict__ Bp,
                                                const float* __restrict__ dinv,
                                                unsigned short* __restrict__ mout) {
    int lane = threadIdx.x & 63;
    int wid = threadIdx.x >> 6;
    int row0 = blockIdx.x * 64 + wid * 16;
    int arow = row0 + (lane & 15);
    const uint4* hbase = (const uint4*)h1b;
    uint4 a_u[4];
#pragma unroll
    for (int kb = 0; kb < 4; ++kb)
        a_u[kb] = hbase[(size_t)arow * 16 + kb * 4 + (lane >> 4)];
    int rbase = row0 + (lane >> 4) * 4;
    float dv[4];
#pragma unroll
    for (int j = 0; j < 4; ++j) dv[j] = dinv[min(rbase + j, N_NODES - 1)];
#pragma unroll
    for (int ct = 0; ct < 8; ++ct) {
        f32x4 acc = {0.f, 0.f, 0.f, 0.f};
#pragma unroll
        for (int kb = 0; kb < 4; ++kb) {
            uint4 b_u = Bp[(ct * 4 + kb) * 64 + lane];
            acc = __builtin_amdgcn_mfma_f32_16x16x32_bf16(
                __builtin_bit_cast(short8, a_u[kb]),
                __builtin_bit_cast(short8, b_u), acc, 0, 0, 0);
        }
        int col = ct * 16 + (lane & 15);
#pragma unroll
        for (int j = 0; j < 4; ++j) {
            int r = rbase + j;
            if (r < N_NODES) mout[(size_t)r * HID + col] = f2bf(acc[j] * dv[j]);
        }
    }
}

// ---------------- node count per graph: binary search on sorted batch ----------------
__global__ __launch_bounds__(64) void k_cnt(const int* __restrict__ batch,
                                            int* __restrict__ cnt) {
    int g = threadIdx.x;
    if (g >= N_GRAPHS) return;
    int lo0 = 0, hi0 = N_NODES;
    while (lo0 < hi0) { int mid = (lo0 + hi0) >> 1; if (batch[mid] < g) lo0 = mid + 1; else hi0 = mid; }
    int lo1 = lo0, hi1 = N_NODES;
    while (lo1 < hi1) { int mid = (lo1 + hi1) >> 1; if (batch[mid] < g + 1) lo1 = mid + 1; else hi1 = mid; }
    cnt[g] = lo1 - lo0;
}

// ---------------- pooled sums over packed bf16 h2 ----------------
// wave per node-stream: block covers POOL_CHUNK nodes with 4 waves (stride 4);
// all 64 lanes of a wave share n (uniform), lane owns channel pair.
#define POOL_CHUNK 128
__global__ __launch_bounds__(256) void k_pool(const unsigned* __restrict__ h,
                                              const int* __restrict__ batch,
                                              float* __restrict__ pooled) {
    int t = threadIdx.x;
    int lane = t & 63;
    int grp = t >> 6;  // 0..3
    int start = blockIdx.x * POOL_CHUNK;
    int end = min(start + POOL_CHUNK, N_NODES);
    float2 acc = make_float2(0.f, 0.f);
    int cur = -1;
    for (int n = start + grp; n < end; n += 4) {
        int g = batch[n];
        if (g != cur) {
            if (cur >= 0) {
                atomicAdd(&pooled[cur * HID + lane * 2], acc.x);
                atomicAdd(&pooled[cur * HID + lane * 2 + 1], acc.y);
            }
            acc = make_float2(0.f, 0.f);
            cur = g;
        }
        float2 v = unpackbf(h[(size_t)n * 64 + lane]);
        acc.x += v.x; acc.y += v.y;
    }
    if (cur >= 0) {
        atomicAdd(&pooled[cur * HID + lane * 2], acc.x);
        atomicAdd(&pooled[cur * HID + lane * 2 + 1], acc.y);
    }
}

// ---------------- final: out = (pooled/cnt) @ Wf + bf ----------------
__global__ __launch_bounds__(128) void k_final(const float* __restrict__ pooled,
                                               const int* __restrict__ cnt,
                                               const float* __restrict__ Wf,
                                               const float* __restrict__ bf,
                                               float* __restrict__ out) {
    __shared__ float p[HID];
    int g = blockIdx.x, t = threadIdx.x;
    float inv = 1.f / fmaxf((float)cnt[g], 1.f);
    p[t] = pooled[g * HID + t] * inv;
    __syncthreads();
    if (t < NCLS) {
        float acc = bf[t];
        for (int k = 0; k < HID; ++k) acc += p[k] * Wf[k * NCLS + t];
        out[g * NCLS + t] = acc;
    }
}

extern "C" void kernel_launch(void* const* d_in, const int* in_sizes, int n_in,
                              void* d_out, int out_size, void* d_ws, size_t ws_size,
                              hipStream_t stream) {
    const float* x   = (const float*)d_in[0];
    const int*   ei  = (const int*)d_in[1];   // [2][E] flat
    const int*   src = ei;
    const int*   dst = ei + N_EDGES;
    const int*   batch = (const int*)d_in[2];
    const float* W1 = (const float*)d_in[3];
    const float* b1 = (const float*)d_in[4];
    const float* W2 = (const float*)d_in[5];
    const float* b2 = (const float*)d_in[6];
    const float* Wf = (const float*)d_in[7];
    const float* bf = (const float*)d_in[8];
    float* out = (float*)d_out;

    char* ws = (char*)d_ws;
    size_t off = 0;
    unsigned* mbuf = (unsigned*)(ws + off);  off += (size_t)N_NODES * 64 * 4;   // 25.6 MB bf16 messages
    unsigned* h1b = (unsigned*)(ws + off);   off += (size_t)N_NODES * 64 * 4;   // 25.6 MB bf16 h1
    unsigned* h2b = (unsigned*)(ws + off);   off += (size_t)N_NODES * 64 * 4;   // 25.6 MB bf16 h2 (aliases old staging region)
    int* csr_src = (int*)(ws + off);         off += (size_t)N_EDGES * 4;        // 6.4 MB
    uint4* Bp = (uint4*)(ws + off);          off += (size_t)2048 * 16;          // 32 KB
    int* deg = (int*)(ws + off);             off += (size_t)N_NODES * 4;
    float* dinv = (float*)(ws + off);        off += (size_t)N_NODES * 4;
    int* rowptr = (int*)(ws + off);          off += (size_t)(N_NODES + 1) * 4;
    int* cntm = (int*)(ws + off);            off += (size_t)NBUCK * NBF * 4;    // 400 KB
    int* offs = (int*)(ws + off);            off += (size_t)NBUCK * NBF * 4;    // 400 KB
    int* partials = (int*)(ws + off);        off += (size_t)SCAN_NB * 4;
    int* blockoff = (int*)(ws + off);        off += (size_t)SCAN_NB * 4;
    float* pooled = (float*)(ws + off);      off += (size_t)N_GRAPHS * HID * 4;
    int* cnt = (int*)(ws + off);             off += (size_t)N_GRAPHS * 4;
    // staging aliases h2b: h2b only written by gather2, after csr is built
    unsigned* staging = h2b;

    // graph preprocessing
    k_init<<<(N_NODES + 255) / 256, 256, 0, stream>>>(deg, pooled);
    k_deg_hist<<<NBF, 256, 0, stream>>>(dst, deg, cntm);
    k_dinv<<<(N_NODES + 255) / 256, 256, 0, stream>>>(deg, dinv);
    k_part<<<SCAN_NB, 256, 0, stream>>>(deg, partials);
    k_scanblk<<<1, 128, 0, stream>>>(partials, blockoff, rowptr);
    k_apply<<<SCAN_NB, 256, 0, stream>>>(deg, blockoff, rowptr);
    k_offs<<<NBUCK, NBF, 0, stream>>>(cntm, rowptr, offs);
    k_partition<<<NBF, 256, 0, stream>>>(src, dst, offs, staging);
    k_csrfill<<<NBUCK, 256, 0, stream>>>(staging, rowptr, csr_src);
    k_w2pack<<<8, 256, 0, stream>>>(W2, Bp);

    // layer 1
    k_xform1<<<N_NODES / 4, 256, 0, stream>>>(x, W1, dinv, mbuf);
    k_gather<<<(N_NODES + 3) / 4, 256, 0, stream>>>(rowptr, csr_src, mbuf, b1, dinv, h1b);

    // layer 2 (MFMA transform; overwrites mbuf — dead after gather1)
    k_xform2<<<(N_NODES + 63) / 64, 256, 0, stream>>>(h1b, Bp, dinv, (unsigned short*)mbuf);
    k_gather<<<(N_NODES + 3) / 4, 256, 0, stream>>>(rowptr, csr_src, mbuf, b2, dinv, h2b);

    // pooling + classifier
    k_cnt<<<1, 64, 0, stream>>>(batch, cnt);
    k_pool<<<(N_NODES + POOL_CHUNK - 1) / POOL_CHUNK, 256, 0, stream>>>(h2b, batch, pooled);
    k_final<<<N_GRAPHS, 128, 0, stream>>>(pooled, cnt, Wf, bf, out);
}

// Round 10
// 272.318 us; speedup vs baseline: 12.8803x; 1.2192x over previous
//
#include <hip/hip_runtime.h>

#define N_NODES 100000
#define N_EDGES 1600000
#define N_GRAPHS 64
#define IN_CH 15
#define HID 128
#define NCLS 11

// bucketed CSR geometry
#define NBUCK 196            // ceil(100000 / 512), bucket = dst >> 9
#define NBF 512              // partition blocks
#define EPB (N_EDGES / NBF)  // 3125 edges per block

using short8 = __attribute__((ext_vector_type(8))) short;
using f32x4 = __attribute__((ext_vector_type(4))) float;

// ---- bf16 pack/unpack (RNE) ----
__device__ __forceinline__ unsigned short f2bf(float f) {
    unsigned u = __builtin_bit_cast(unsigned, f);
    u += 0x7FFF + ((u >> 16) & 1);
    return (unsigned short)(u >> 16);
}
__device__ __forceinline__ unsigned packbf(float a, float b) {
    return (unsigned)f2bf(a) | ((unsigned)f2bf(b) << 16);
}
__device__ __forceinline__ float2 unpackbf(unsigned v) {
    float2 r;
    unsigned lo = v << 16;
    unsigned hi = v & 0xFFFF0000u;
    r.x = __builtin_bit_cast(float, lo);
    r.y = __builtin_bit_cast(float, hi);
    return r;
}

// ---------------- init: pooled=0 ----------------
__global__ __launch_bounds__(256) void k_init(float* __restrict__ pooled) {
    int i = blockIdx.x * 256 + threadIdx.x;
    if (i < N_GRAPHS * HID) pooled[i] = 0.f;
}

// ---------------- per-block bucket histogram (LDS only, NO global atomics) ----------------
__global__ __launch_bounds__(256) void k_hist(const int* __restrict__ dst,
                                              int* __restrict__ cntm) {
    __shared__ int hist[NBUCK];
    int t = threadIdx.x;
    for (int i = t; i < NBUCK; i += 256) hist[i] = 0;
    __syncthreads();
    int base = blockIdx.x * EPB;
#pragma unroll
    for (int i = 0; i < (EPB + 255) / 256; ++i) {
        int e = i * 256 + t;
        if (e < EPB) atomicAdd(&hist[dst[base + e] >> 9], 1);
    }
    __syncthreads();
    for (int b = t; b < NBUCK; b += 256)
        cntm[b * NBF + blockIdx.x] = hist[b];
}

// ---------------- bucket totals: reduce each cntm row ----------------
__global__ __launch_bounds__(256) void k_btot(const int* __restrict__ cntm,
                                              int* __restrict__ tot) {
    __shared__ int red[256];
    int b = blockIdx.x, t = threadIdx.x;
    red[t] = cntm[b * NBF + t] + cntm[b * NBF + t + 256];
    __syncthreads();
    for (int off = 128; off > 0; off >>= 1) {
        if (t < off) red[t] += red[t + off];
        __syncthreads();
    }
    if (t == 0) tot[b] = red[0];
}

// ---------------- scan 196 bucket totals -> bbase; rowptr[N]=E ----------------
__global__ __launch_bounds__(256) void k_bscan(const int* __restrict__ tot,
                                               int* __restrict__ bbase,
                                               int* __restrict__ rowptr) {
    __shared__ int arr[256];
    int t = threadIdx.x;
    arr[t] = (t < NBUCK) ? tot[t] : 0;
    __syncthreads();
    for (int off = 1; off < 256; off <<= 1) {
        int v = (t >= off) ? arr[t - off] : 0;
        __syncthreads();
        arr[t] += v;
        __syncthreads();
    }
    if (t < NBUCK) bbase[t] = (t == 0) ? 0 : arr[t - 1];
    if (t == 0) rowptr[N_NODES] = N_EDGES;
}

// ---------------- per-(bucket,block) partition offsets ----------------
__global__ __launch_bounds__(NBF) void k_offs(const int* __restrict__ cntm,
                                              const int* __restrict__ bbase,
                                              int* __restrict__ offs) {
    __shared__ int arr[NBF];
    int b = blockIdx.x, t = threadIdx.x;
    arr[t] = cntm[b * NBF + t];
    __syncthreads();
    for (int off = 1; off < NBF; off <<= 1) {
        int v = (t >= off) ? arr[t - off] : 0;
        __syncthreads();
        arr[t] += v;
        __syncthreads();
    }
    offs[b * NBF + t] = bbase[b] + ((t == 0) ? 0 : arr[t - 1]);
}

// ---------------- partition: edges -> staging, grouped by 512-node bucket ----------------
// packed: (dst & 511) << 17 | src   (src < 2^17)
__global__ __launch_bounds__(256) void k_partition(const int* __restrict__ src,
                                                   const int* __restrict__ dst,
                                                   const int* __restrict__ offs,
                                                   unsigned* __restrict__ staging) {
    __shared__ int cur[NBUCK];
    int t = threadIdx.x;
    for (int b = t; b < NBUCK; b += 256) cur[b] = offs[b * NBF + blockIdx.x];
    __syncthreads();
    int base = blockIdx.x * EPB;
#pragma unroll
    for (int i = 0; i < (EPB + 255) / 256; ++i) {
        int e = i * 256 + t;
        if (e < EPB) {
            int d = dst[base + e];
            int s = src[base + e];
            int slot = atomicAdd(&cur[d >> 9], 1);
            staging[slot] = ((unsigned)(d & 511) << 17) | (unsigned)s;
        }
    }
}

// ---------------- fuse: per-bucket node histogram -> rowptr, dinv; then csr scatter ----------------
__global__ __launch_bounds__(256) void k_fuse(const unsigned* __restrict__ staging,
                                              const int* __restrict__ bbase,
                                              int* __restrict__ rowptr,
                                              float* __restrict__ dinv,
                                              int* __restrict__ csr_src) {
    __shared__ int cnt[512];
    __shared__ int cur[512];
    __shared__ int arr[256];
    int b = blockIdx.x, t = threadIdx.x;
    cnt[t] = 0; cnt[t + 256] = 0;
    __syncthreads();
    int beg = bbase[b];
    int end = (b == NBUCK - 1) ? N_EDGES : bbase[b + 1];
    // pass 1: node-local histogram
    for (int e = beg + t; e < end; e += 256)
        atomicAdd(&cnt[staging[e] >> 17], 1);
    __syncthreads();
    // scan 512 counters (pair per thread)
    int c0 = cnt[2 * t], c1 = cnt[2 * t + 1];
    arr[t] = c0 + c1;
    __syncthreads();
    for (int off = 1; off < 256; off <<= 1) {
        int v = (t >= off) ? arr[t - off] : 0;
        __syncthreads();
        arr[t] += v;
        __syncthreads();
    }
    int excl = (t == 0) ? 0 : arr[t - 1];
    int p0 = beg + excl;
    int p1 = p0 + c0;
    cur[2 * t] = p0;
    cur[2 * t + 1] = p1;
    int n0 = b << 9;
    int n = n0 + 2 * t;
    if (n < N_NODES) { rowptr[n] = p0; dinv[n] = rsqrtf((float)(c0 + 1)); }
    n = n0 + 2 * t + 1;
    if (n < N_NODES) { rowptr[n] = p1; dinv[n] = rsqrtf((float)(c1 + 1)); }
    __syncthreads();
    // pass 2: scatter into bucket-owned csr window
    for (int e = beg + t; e < end; e += 256) {
        unsigned v = staging[e];
        int pos = atomicAdd(&cur[v >> 17], 1);
        csr_src[pos] = (int)(v & 0x1FFFFu);
    }
}

// ---------------- W2 -> MFMA B-fragment layout, bf16 ----------------
__global__ __launch_bounds__(256) void k_w2pack(const float* __restrict__ W2,
                                                uint4* __restrict__ Bp) {
    int i = blockIdx.x * 256 + threadIdx.x;  // 2048 slots
    if (i >= 2048) return;
    int lane = i & 63;
    int kb = (i >> 6) & 3;
    int ct = i >> 8;
    int col = ct * 16 + (lane & 15);
    int k0 = kb * 32 + ((lane >> 4) & 3) * 8;
    unsigned w[4];
#pragma unroll
    for (int p = 0; p < 4; ++p) {
        int k = k0 + 2 * p;
        w[p] = packbf(W2[k * HID + col], W2[(k + 1) * HID + col]);
    }
    Bp[i] = make_uint4(w[0], w[1], w[2], w[3]);
}

// ---------------- layer-1 transform: m = bf16((x @ W1) * dinv) ----------------
__global__ __launch_bounds__(256) void k_xform1(const float* __restrict__ x,
                                                const float* __restrict__ W1,
                                                const float* __restrict__ dinv,
                                                unsigned* __restrict__ m) {
    __shared__ float w[IN_CH * HID];  // 7.5 KB
    int t = threadIdx.x;
    for (int i = t; i < IN_CH * HID; i += 256) w[i] = W1[i];
    __syncthreads();
    int node = blockIdx.x * 4 + (t >> 6);
    int lane = t & 63;
    int c = lane * 2;
    const float* xr = x + node * IN_CH;
    float a0 = 0.f, a1 = 0.f;
#pragma unroll
    for (int k = 0; k < IN_CH; ++k) {
        float xv = xr[k];
        a0 += xv * w[k * HID + c];
        a1 += xv * w[k * HID + c + 1];
    }
    float dv = dinv[node];
    m[(size_t)node * 64 + lane] = packbf(a0 * dv, a1 * dv);
}

// ---------------- gather: out = bf16(relu(dinv*(m[n]+sum m[src])+b)) ----------------
__global__ __launch_bounds__(256) void k_gather(const int* __restrict__ rowptr,
                                                const int* __restrict__ csr_src,
                                                const unsigned* __restrict__ m,
                                                const float* __restrict__ bias,
                                                const float* __restrict__ dinv,
                                                unsigned* __restrict__ outh) {
    int wave = (blockIdx.x * 256 + threadIdx.x) >> 6;
    if (wave >= N_NODES) return;
    int n = wave;
    int lane = threadIdx.x & 63;
    int c = lane * 2;
    int beg = rowptr[n], end = rowptr[n + 1];
    float2 acc = unpackbf(m[(size_t)n * 64 + lane]);  // self-loop term
    int e = beg;
    for (; e + 8 <= end; e += 8) {
        int s0 = csr_src[e + 0], s1 = csr_src[e + 1], s2 = csr_src[e + 2], s3 = csr_src[e + 3];
        int s4 = csr_src[e + 4], s5 = csr_src[e + 5], s6 = csr_src[e + 6], s7 = csr_src[e + 7];
        unsigned v0 = m[(size_t)s0 * 64 + lane];
        unsigned v1 = m[(size_t)s1 * 64 + lane];
        unsigned v2 = m[(size_t)s2 * 64 + lane];
        unsigned v3 = m[(size_t)s3 * 64 + lane];
        unsigned v4 = m[(size_t)s4 * 64 + lane];
        unsigned v5 = m[(size_t)s5 * 64 + lane];
        unsigned v6 = m[(size_t)s6 * 64 + lane];
        unsigned v7 = m[(size_t)s7 * 64 + lane];
        float2 f0 = unpackbf(v0), f1 = unpackbf(v1), f2 = unpackbf(v2), f3 = unpackbf(v3);
        float2 f4 = unpackbf(v4), f5 = unpackbf(v5), f6 = unpackbf(v6), f7 = unpackbf(v7);
        acc.x += f0.x + f1.x + f2.x + f3.x + f4.x + f5.x + f6.x + f7.x;
        acc.y += f0.y + f1.y + f2.y + f3.y + f4.y + f5.y + f6.y + f7.y;
    }
    for (; e + 2 <= end; e += 2) {
        int s0 = csr_src[e], s1 = csr_src[e + 1];
        unsigned v0 = m[(size_t)s0 * 64 + lane];
        unsigned v1 = m[(size_t)s1 * 64 + lane];
        float2 f0 = unpackbf(v0), f1 = unpackbf(v1);
        acc.x += f0.x + f1.x;
        acc.y += f0.y + f1.y;
    }
    if (e < end) {
        float2 f = unpackbf(m[(size_t)csr_src[e] * 64 + lane]);
        acc.x += f.x; acc.y += f.y;
    }
    float dv = dinv[n];
    float2 b = *(const float2*)&bias[c];
    float rx = fmaxf(acc.x * dv + b.x, 0.f);
    float ry = fmaxf(acc.y * dv + b.y, 0.f);
    outh[(size_t)n * 64 + lane] = packbf(rx, ry);
}

// ---------------- layer-2 transform via MFMA: m = bf16((h1 @ W2) * dinv) ----------------
__global__ __launch_bounds__(256) void k_xform2(const unsigned* __restrict__ h1b,
                                                const uint4* __restrict__ Bp,
                                                const float* __restrict__ dinv,
                                                unsigned short* __restrict__ mout) {
    int lane = threadIdx.x & 63;
    int wid = threadIdx.x >> 6;
    int row0 = blockIdx.x * 64 + wid * 16;
    int arow = row0 + (lane & 15);
    const uint4* hbase = (const uint4*)h1b;
    uint4 a_u[4];
#pragma unroll
    for (int kb = 0; kb < 4; ++kb)
        a_u[kb] = hbase[(size_t)arow * 16 + kb * 4 + (lane >> 4)];
    int rbase = row0 + (lane >> 4) * 4;
    float dv[4];
#pragma unroll
    for (int j = 0; j < 4; ++j) dv[j] = dinv[min(rbase + j, N_NODES - 1)];
#pragma unroll
    for (int ct = 0; ct < 8; ++ct) {
        f32x4 acc = {0.f, 0.f, 0.f, 0.f};
#pragma unroll
        for (int kb = 0; kb < 4; ++kb) {
            uint4 b_u = Bp[(ct * 4 + kb) * 64 + lane];
            acc = __builtin_amdgcn_mfma_f32_16x16x32_bf16(
                __builtin_bit_cast(short8, a_u[kb]),
                __builtin_bit_cast(short8, b_u), acc, 0, 0, 0);
        }
        int col = ct * 16 + (lane & 15);
#pragma unroll
        for (int j = 0; j < 4; ++j) {
            int r = rbase + j;
            if (r < N_NODES) mout[(size_t)r * HID + col] = f2bf(acc[j] * dv[j]);
        }
    }
}

// ---------------- node count per graph: binary search on sorted batch ----------------
__global__ __launch_bounds__(64) void k_cnt(const int* __restrict__ batch,
                                            int* __restrict__ cnt) {
    int g = threadIdx.x;
    if (g >= N_GRAPHS) return;
    int lo0 = 0, hi0 = N_NODES;
    while (lo0 < hi0) { int mid = (lo0 + hi0) >> 1; if (batch[mid] < g) lo0 = mid + 1; else hi0 = mid; }
    int lo1 = lo0, hi1 = N_NODES;
    while (lo1 < hi1) { int mid = (lo1 + hi1) >> 1; if (batch[mid] < g + 1) lo1 = mid + 1; else hi1 = mid; }
    cnt[g] = lo1 - lo0;
}

// ---------------- pooled sums over packed bf16 h2 ----------------
#define POOL_CHUNK 128
__global__ __launch_bounds__(256) void k_pool(const unsigned* __restrict__ h,
                                              const int* __restrict__ batch,
                                              float* __restrict__ pooled) {
    int t = threadIdx.x;
    int lane = t & 63;
    int grp = t >> 6;  // 0..3
    int start = blockIdx.x * POOL_CHUNK;
    int end = min(start + POOL_CHUNK, N_NODES);
    float2 acc = make_float2(0.f, 0.f);
    int cur = -1;
    for (int n = start + grp; n < end; n += 4) {
        int g = batch[n];
        if (g != cur) {
            if (cur >= 0) {
                atomicAdd(&pooled[cur * HID + lane * 2], acc.x);
                atomicAdd(&pooled[cur * HID + lane * 2 + 1], acc.y);
            }
            acc = make_float2(0.f, 0.f);
            cur = g;
        }
        float2 v = unpackbf(h[(size_t)n * 64 + lane]);
        acc.x += v.x; acc.y += v.y;
    }
    if (cur >= 0) {
        atomicAdd(&pooled[cur * HID + lane * 2], acc.x);
        atomicAdd(&pooled[cur * HID + lane * 2 + 1], acc.y);
    }
}

// ---------------- final: out = (pooled/cnt) @ Wf + bf ----------------
__global__ __launch_bounds__(128) void k_final(const float* __restrict__ pooled,
                                               const int* __restrict__ cnt,
                                               const float* __restrict__ Wf,
                                               const float* __restrict__ bf,
                                               float* __restrict__ out) {
    __shared__ float p[HID];
    int g = blockIdx.x, t = threadIdx.x;
    float inv = 1.f / fmaxf((float)cnt[g], 1.f);
    p[t] = pooled[g * HID + t] * inv;
    __syncthreads();
    if (t < NCLS) {
        float acc = bf[t];
        for (int k = 0; k < HID; ++k) acc += p[k] * Wf[k * NCLS + t];
        out[g * NCLS + t] = acc;
    }
}

extern "C" void kernel_launch(void* const* d_in, const int* in_sizes, int n_in,
                              void* d_out, int out_size, void* d_ws, size_t ws_size,
                              hipStream_t stream) {
    const float* x   = (const float*)d_in[0];
    const int*   ei  = (const int*)d_in[1];   // [2][E] flat
    const int*   src = ei;
    const int*   dst = ei + N_EDGES;
    const int*   batch = (const int*)d_in[2];
    const float* W1 = (const float*)d_in[3];
    const float* b1 = (const float*)d_in[4];
    const float* W2 = (const float*)d_in[5];
    const float* b2 = (const float*)d_in[6];
    const float* Wf = (const float*)d_in[7];
    const float* bf = (const float*)d_in[8];
    float* out = (float*)d_out;

    char* ws = (char*)d_ws;
    size_t off = 0;
    unsigned* mbuf = (unsigned*)(ws + off);  off += (size_t)N_NODES * 64 * 4;   // 25.6 MB bf16 messages
    unsigned* h1b = (unsigned*)(ws + off);   off += (size_t)N_NODES * 64 * 4;   // 25.6 MB bf16 h1
    unsigned* h2b = (unsigned*)(ws + off);   off += (size_t)N_NODES * 64 * 4;   // 25.6 MB bf16 h2 / staging
    int* csr_src = (int*)(ws + off);         off += (size_t)N_EDGES * 4;        // 6.4 MB
    uint4* Bp = (uint4*)(ws + off);          off += (size_t)2048 * 16;          // 32 KB
    float* dinv = (float*)(ws + off);        off += (size_t)N_NODES * 4;
    int* rowptr = (int*)(ws + off);          off += (size_t)(N_NODES + 1) * 4;
    int* cntm = (int*)(ws + off);            off += (size_t)NBUCK * NBF * 4;    // 400 KB
    int* offs = (int*)(ws + off);            off += (size_t)NBUCK * NBF * 4;    // 400 KB
    int* tot = (int*)(ws + off);             off += (size_t)NBUCK * 4;
    int* bbase = (int*)(ws + off);           off += (size_t)NBUCK * 4;
    float* pooled = (float*)(ws + off);      off += (size_t)N_GRAPHS * HID * 4;
    int* cnt = (int*)(ws + off);             off += (size_t)N_GRAPHS * 4;
    // staging aliases h2b: h2b only written by gather2, after csr is built
    unsigned* staging = h2b;

    // graph preprocessing (zero global atomics)
    k_init<<<(N_GRAPHS * HID + 255) / 256, 256, 0, stream>>>(pooled);
    k_hist<<<NBF, 256, 0, stream>>>(dst, cntm);
    k_btot<<<NBUCK, 256, 0, stream>>>(cntm, tot);
    k_bscan<<<1, 256, 0, stream>>>(tot, bbase, rowptr);
    k_offs<<<NBUCK, NBF, 0, stream>>>(cntm, bbase, offs);
    k_partition<<<NBF, 256, 0, stream>>>(src, dst, offs, staging);
    k_fuse<<<NBUCK, 256, 0, stream>>>(staging, bbase, rowptr, dinv, csr_src);
    k_w2pack<<<8, 256, 0, stream>>>(W2, Bp);

    // layer 1
    k_xform1<<<N_NODES / 4, 256, 0, stream>>>(x, W1, dinv, mbuf);
    k_gather<<<(N_NODES + 3) / 4, 256, 0, stream>>>(rowptr, csr_src, mbuf, b1, dinv, h1b);

    // layer 2 (MFMA transform; overwrites mbuf — dead after gather1)
    k_xform2<<<(N_NODES + 63) / 64, 256, 0, stream>>>(h1b, Bp, dinv, (unsigned short*)mbuf);
    k_gather<<<(N_NODES + 3) / 4, 256, 0, stream>>>(rowptr, csr_src, mbuf, b2, dinv, h2b);

    // pooling + classifier
    k_cnt<<<1, 64, 0, stream>>>(batch, cnt);
    k_pool<<<(N_NODES + POOL_CHUNK - 1) / POOL_CHUNK, 256, 0, stream>>>(h2b, batch, pooled);
    k_final<<<N_GRAPHS, 128, 0, stream>>>(pooled, cnt, Wf, bf, out);
}

// Round 11
// 248.047 us; speedup vs baseline: 14.1407x; 1.0978x over previous
//
#include <hip/hip_runtime.h>

#define N_NODES 100000
#define N_EDGES 1600000
#define N_GRAPHS 64
#define IN_CH 15
#define HID 128
#define NCLS 11

// bucketed CSR geometry
#define NBUCK 196            // ceil(100000 / 512), bucket = dst >> 9
#define NBF 512              // partition blocks
#define EPB (N_EDGES / NBF)  // 3125 edges per block

using short8 = __attribute__((ext_vector_type(8))) short;
using f32x4 = __attribute__((ext_vector_type(4))) float;

// ---- bf16 pack/unpack (RNE) ----
__device__ __forceinline__ unsigned short f2bf(float f) {
    unsigned u = __builtin_bit_cast(unsigned, f);
    u += 0x7FFF + ((u >> 16) & 1);
    return (unsigned short)(u >> 16);
}
__device__ __forceinline__ unsigned packbf(float a, float b) {
    return (unsigned)f2bf(a) | ((unsigned)f2bf(b) << 16);
}
__device__ __forceinline__ float2 unpackbf(unsigned v) {
    float2 r;
    unsigned lo = v << 16;
    unsigned hi = v & 0xFFFF0000u;
    r.x = __builtin_bit_cast(float, lo);
    r.y = __builtin_bit_cast(float, hi);
    return r;
}

// ---------------- init: pooled=0 ----------------
__global__ __launch_bounds__(256) void k_init(float* __restrict__ pooled) {
    int i = blockIdx.x * 256 + threadIdx.x;
    if (i < N_GRAPHS * HID) pooled[i] = 0.f;
}

// ---------------- per-block bucket histogram (LDS only, NO global atomics) ----------------
__global__ __launch_bounds__(256) void k_hist(const int* __restrict__ dst,
                                              int* __restrict__ cntm) {
    __shared__ int hist[NBUCK];
    int t = threadIdx.x;
    for (int i = t; i < NBUCK; i += 256) hist[i] = 0;
    __syncthreads();
    int base = blockIdx.x * EPB;
#pragma unroll
    for (int i = 0; i < (EPB + 255) / 256; ++i) {
        int e = i * 256 + t;
        if (e < EPB) atomicAdd(&hist[dst[base + e] >> 9], 1);
    }
    __syncthreads();
    for (int b = t; b < NBUCK; b += 256)
        cntm[b * NBF + blockIdx.x] = hist[b];
}

// ---------------- bucket totals: reduce each cntm row ----------------
__global__ __launch_bounds__(256) void k_btot(const int* __restrict__ cntm,
                                              int* __restrict__ tot) {
    __shared__ int red[256];
    int b = blockIdx.x, t = threadIdx.x;
    red[t] = cntm[b * NBF + t] + cntm[b * NBF + t + 256];
    __syncthreads();
    for (int off = 128; off > 0; off >>= 1) {
        if (t < off) red[t] += red[t + off];
        __syncthreads();
    }
    if (t == 0) tot[b] = red[0];
}

// ---------------- scan 196 bucket totals -> bbase; rowptr[N]=E ----------------
__global__ __launch_bounds__(256) void k_bscan(const int* __restrict__ tot,
                                               int* __restrict__ bbase,
                                               int* __restrict__ rowptr) {
    __shared__ int arr[256];
    int t = threadIdx.x;
    arr[t] = (t < NBUCK) ? tot[t] : 0;
    __syncthreads();
    for (int off = 1; off < 256; off <<= 1) {
        int v = (t >= off) ? arr[t - off] : 0;
        __syncthreads();
        arr[t] += v;
        __syncthreads();
    }
    if (t < NBUCK) bbase[t] = (t == 0) ? 0 : arr[t - 1];
    if (t == 0) rowptr[N_NODES] = N_EDGES;
}

// ---------------- per-(bucket,block) partition offsets ----------------
__global__ __launch_bounds__(NBF) void k_offs(const int* __restrict__ cntm,
                                              const int* __restrict__ bbase,
                                              int* __restrict__ offs) {
    __shared__ int arr[NBF];
    int b = blockIdx.x, t = threadIdx.x;
    arr[t] = cntm[b * NBF + t];
    __syncthreads();
    for (int off = 1; off < NBF; off <<= 1) {
        int v = (t >= off) ? arr[t - off] : 0;
        __syncthreads();
        arr[t] += v;
        __syncthreads();
    }
    offs[b * NBF + t] = bbase[b] + ((t == 0) ? 0 : arr[t - 1]);
}

// ---------------- partition: edges -> staging, grouped by 512-node bucket ----------------
// packed: (dst & 511) << 17 | src   (src < 2^17)
__global__ __launch_bounds__(256) void k_partition(const int* __restrict__ src,
                                                   const int* __restrict__ dst,
                                                   const int* __restrict__ offs,
                                                   unsigned* __restrict__ staging) {
    __shared__ int cur[NBUCK];
    int t = threadIdx.x;
    for (int b = t; b < NBUCK; b += 256) cur[b] = offs[b * NBF + blockIdx.x];
    __syncthreads();
    int base = blockIdx.x * EPB;
#pragma unroll
    for (int i = 0; i < (EPB + 255) / 256; ++i) {
        int e = i * 256 + t;
        if (e < EPB) {
            int d = dst[base + e];
            int s = src[base + e];
            int slot = atomicAdd(&cur[d >> 9], 1);
            staging[slot] = ((unsigned)(d & 511) << 17) | (unsigned)s;
        }
    }
}

// ---------------- fuse: per-bucket node histogram -> rowptr, dinv; then csr scatter ----------------
__global__ __launch_bounds__(256) void k_fuse(const unsigned* __restrict__ staging,
                                              const int* __restrict__ bbase,
                                              int* __restrict__ rowptr,
                                              float* __restrict__ dinv,
                                              int* __restrict__ csr_src) {
    __shared__ int cnt[512];
    __shared__ int cur[512];
    __shared__ int arr[256];
    int b = blockIdx.x, t = threadIdx.x;
    cnt[t] = 0; cnt[t + 256] = 0;
    __syncthreads();
    int beg = bbase[b];
    int end = (b == NBUCK - 1) ? N_EDGES : bbase[b + 1];
    for (int e = beg + t; e < end; e += 256)
        atomicAdd(&cnt[staging[e] >> 17], 1);
    __syncthreads();
    int c0 = cnt[2 * t], c1 = cnt[2 * t + 1];
    arr[t] = c0 + c1;
    __syncthreads();
    for (int off = 1; off < 256; off <<= 1) {
        int v = (t >= off) ? arr[t - off] : 0;
        __syncthreads();
        arr[t] += v;
        __syncthreads();
    }
    int excl = (t == 0) ? 0 : arr[t - 1];
    int p0 = beg + excl;
    int p1 = p0 + c0;
    cur[2 * t] = p0;
    cur[2 * t + 1] = p1;
    int n0 = b << 9;
    int n = n0 + 2 * t;
    if (n < N_NODES) { rowptr[n] = p0; dinv[n] = rsqrtf((float)(c0 + 1)); }
    n = n0 + 2 * t + 1;
    if (n < N_NODES) { rowptr[n] = p1; dinv[n] = rsqrtf((float)(c1 + 1)); }
    __syncthreads();
    for (int e = beg + t; e < end; e += 256) {
        unsigned v = staging[e];
        int pos = atomicAdd(&cur[v >> 17], 1);
        csr_src[pos] = (int)(v & 0x1FFFFu);
    }
}

// ---------------- W2 -> MFMA B-fragment layout, bf16 ----------------
__global__ __launch_bounds__(256) void k_w2pack(const float* __restrict__ W2,
                                                uint4* __restrict__ Bp) {
    int i = blockIdx.x * 256 + threadIdx.x;  // 2048 slots
    if (i >= 2048) return;
    int lane = i & 63;
    int kb = (i >> 6) & 3;
    int ct = i >> 8;
    int col = ct * 16 + (lane & 15);
    int k0 = kb * 32 + ((lane >> 4) & 3) * 8;
    unsigned w[4];
#pragma unroll
    for (int p = 0; p < 4; ++p) {
        int k = k0 + 2 * p;
        w[p] = packbf(W2[k * HID + col], W2[(k + 1) * HID + col]);
    }
    Bp[i] = make_uint4(w[0], w[1], w[2], w[3]);
}

// ---------------- prescale: xs[n][16] = bf16(x[n][ch] * dinv[n]), ch15 = 0 ----------------
__global__ __launch_bounds__(256) void k_prescale(const float* __restrict__ x,
                                                  const float* __restrict__ dinv,
                                                  unsigned* __restrict__ xs) {
    int i = blockIdx.x * 256 + threadIdx.x;  // one thread per (node, ch-pair)
    if (i >= N_NODES * 8) return;
    int n = i >> 3, p = i & 7;
    float dv = dinv[n];
    int c0 = 2 * p, c1 = c0 + 1;
    float a = x[(size_t)n * IN_CH + c0] * dv;                       // c0 <= 14 always
    float b = (c1 < IN_CH) ? x[(size_t)n * IN_CH + c1] * dv : 0.f;  // pad ch15
    xs[i] = packbf(a, b);
}

// ---------------- gather15: agg[n][16] = dinv[n]*(xs[n] + sum xs[src]) ----------------
// wave per dst node; 8 lanes per edge (lane owns channel pair); 8 edges in flight;
// 3-step shfl_xor reduce across edge groups. xs = 3.2 MB -> L2-resident.
__global__ __launch_bounds__(256) void k_gather15(const int* __restrict__ rowptr,
                                                  const int* __restrict__ csr_src,
                                                  const unsigned* __restrict__ xs,
                                                  const float* __restrict__ dinv,
                                                  float* __restrict__ agg) {
    int wave = (blockIdx.x * 256 + threadIdx.x) >> 6;
    if (wave >= N_NODES) return;
    int n = wave;
    int l = threadIdx.x & 63;
    int g = l >> 3, cp = l & 7;
    int beg = rowptr[n], end = rowptr[n + 1];
    float2 acc = make_float2(0.f, 0.f);
    for (int e = beg + g; e < end; e += 8) {
        int s = csr_src[e];
        float2 v = unpackbf(xs[(size_t)s * 8 + cp]);
        acc.x += v.x; acc.y += v.y;
    }
#pragma unroll
    for (int off = 8; off < 64; off <<= 1) {
        acc.x += __shfl_xor(acc.x, off, 64);
        acc.y += __shfl_xor(acc.y, off, 64);
    }
    if (l < 8) {
        float2 s = unpackbf(xs[(size_t)n * 8 + l]);  // self term
        float dv = dinv[n];
        float2 r = make_float2((acc.x + s.x) * dv, (acc.y + s.y) * dv);
        *(float2*)&agg[(size_t)n * 16 + 2 * l] = r;
    }
}

// ---------------- xform1b: h1 = bf16(relu(agg @ W1 + b1)) ----------------
__global__ __launch_bounds__(256) void k_xform1b(const float* __restrict__ agg,
                                                 const float* __restrict__ W1,
                                                 const float* __restrict__ b1,
                                                 unsigned* __restrict__ h1b) {
    __shared__ float w[IN_CH * HID];  // 7.5 KB
    int t = threadIdx.x;
    for (int i = t; i < IN_CH * HID; i += 256) w[i] = W1[i];
    __syncthreads();
    int node = blockIdx.x * 4 + (t >> 6);
    int lane = t & 63;
    int c = lane * 2;
    const float* ar = agg + (size_t)node * 16;
    float a0 = b1[c], a1 = b1[c + 1];
#pragma unroll
    for (int k = 0; k < IN_CH; ++k) {
        float av = ar[k];
        a0 += av * w[k * HID + c];
        a1 += av * w[k * HID + c + 1];
    }
    h1b[(size_t)node * 64 + lane] = packbf(fmaxf(a0, 0.f), fmaxf(a1, 0.f));
}

// ---------------- gather (layer 2): out = bf16(relu(dinv*(m[n]+sum m[src])+b)) ----------------
__global__ __launch_bounds__(256) void k_gather(const int* __restrict__ rowptr,
                                                const int* __restrict__ csr_src,
                                                const unsigned* __restrict__ m,
                                                const float* __restrict__ bias,
                                                const float* __restrict__ dinv,
                                                unsigned* __restrict__ outh) {
    int wave = (blockIdx.x * 256 + threadIdx.x) >> 6;
    if (wave >= N_NODES) return;
    int n = wave;
    int lane = threadIdx.x & 63;
    int c = lane * 2;
    int beg = rowptr[n], end = rowptr[n + 1];
    float2 acc = unpackbf(m[(size_t)n * 64 + lane]);  // self-loop term
    int e = beg;
    for (; e + 8 <= end; e += 8) {
        int s0 = csr_src[e + 0], s1 = csr_src[e + 1], s2 = csr_src[e + 2], s3 = csr_src[e + 3];
        int s4 = csr_src[e + 4], s5 = csr_src[e + 5], s6 = csr_src[e + 6], s7 = csr_src[e + 7];
        unsigned v0 = m[(size_t)s0 * 64 + lane];
        unsigned v1 = m[(size_t)s1 * 64 + lane];
        unsigned v2 = m[(size_t)s2 * 64 + lane];
        unsigned v3 = m[(size_t)s3 * 64 + lane];
        unsigned v4 = m[(size_t)s4 * 64 + lane];
        unsigned v5 = m[(size_t)s5 * 64 + lane];
        unsigned v6 = m[(size_t)s6 * 64 + lane];
        unsigned v7 = m[(size_t)s7 * 64 + lane];
        float2 f0 = unpackbf(v0), f1 = unpackbf(v1), f2 = unpackbf(v2), f3 = unpackbf(v3);
        float2 f4 = unpackbf(v4), f5 = unpackbf(v5), f6 = unpackbf(v6), f7 = unpackbf(v7);
        acc.x += f0.x + f1.x + f2.x + f3.x + f4.x + f5.x + f6.x + f7.x;
        acc.y += f0.y + f1.y + f2.y + f3.y + f4.y + f5.y + f6.y + f7.y;
    }
    for (; e + 2 <= end; e += 2) {
        int s0 = csr_src[e], s1 = csr_src[e + 1];
        unsigned v0 = m[(size_t)s0 * 64 + lane];
        unsigned v1 = m[(size_t)s1 * 64 + lane];
        float2 f0 = unpackbf(v0), f1 = unpackbf(v1);
        acc.x += f0.x + f1.x;
        acc.y += f0.y + f1.y;
    }
    if (e < end) {
        float2 f = unpackbf(m[(size_t)csr_src[e] * 64 + lane]);
        acc.x += f.x; acc.y += f.y;
    }
    float dv = dinv[n];
    float2 b = *(const float2*)&bias[c];
    float rx = fmaxf(acc.x * dv + b.x, 0.f);
    float ry = fmaxf(acc.y * dv + b.y, 0.f);
    outh[(size_t)n * 64 + lane] = packbf(rx, ry);
}

// ---------------- layer-2 transform via MFMA: m = bf16((h1 @ W2) * dinv) ----------------
__global__ __launch_bounds__(256) void k_xform2(const unsigned* __restrict__ h1b,
                                                const uint4* __restrict__ Bp,
                                                const float* __restrict__ dinv,
                                                unsigned short* __restrict__ mout) {
    int lane = threadIdx.x & 63;
    int wid = threadIdx.x >> 6;
    int row0 = blockIdx.x * 64 + wid * 16;
    int arow = row0 + (lane & 15);
    const uint4* hbase = (const uint4*)h1b;
    uint4 a_u[4];
#pragma unroll
    for (int kb = 0; kb < 4; ++kb)
        a_u[kb] = hbase[(size_t)arow * 16 + kb * 4 + (lane >> 4)];
    int rbase = row0 + (lane >> 4) * 4;
    float dv[4];
#pragma unroll
    for (int j = 0; j < 4; ++j) dv[j] = dinv[min(rbase + j, N_NODES - 1)];
#pragma unroll
    for (int ct = 0; ct < 8; ++ct) {
        f32x4 acc = {0.f, 0.f, 0.f, 0.f};
#pragma unroll
        for (int kb = 0; kb < 4; ++kb) {
            uint4 b_u = Bp[(ct * 4 + kb) * 64 + lane];
            acc = __builtin_amdgcn_mfma_f32_16x16x32_bf16(
                __builtin_bit_cast(short8, a_u[kb]),
                __builtin_bit_cast(short8, b_u), acc, 0, 0, 0);
        }
        int col = ct * 16 + (lane & 15);
#pragma unroll
        for (int j = 0; j < 4; ++j) {
            int r = rbase + j;
            if (r < N_NODES) mout[(size_t)r * HID + col] = f2bf(acc[j] * dv[j]);
        }
    }
}

// ---------------- node count per graph: binary search on sorted batch ----------------
__global__ __launch_bounds__(64) void k_cnt(const int* __restrict__ batch,
                                            int* __restrict__ cnt) {
    int g = threadIdx.x;
    if (g >= N_GRAPHS) return;
    int lo0 = 0, hi0 = N_NODES;
    while (lo0 < hi0) { int mid = (lo0 + hi0) >> 1; if (batch[mid] < g) lo0 = mid + 1; else hi0 = mid; }
    int lo1 = lo0, hi1 = N_NODES;
    while (lo1 < hi1) { int mid = (lo1 + hi1) >> 1; if (batch[mid] < g + 1) lo1 = mid + 1; else hi1 = mid; }
    cnt[g] = lo1 - lo0;
}

// ---------------- pooled sums over packed bf16 h2 ----------------
#define POOL_CHUNK 128
__global__ __launch_bounds__(256) void k_pool(const unsigned* __restrict__ h,
                                              const int* __restrict__ batch,
                                              float* __restrict__ pooled) {
    int t = threadIdx.x;
    int lane = t & 63;
    int grp = t >> 6;  // 0..3
    int start = blockIdx.x * POOL_CHUNK;
    int end = min(start + POOL_CHUNK, N_NODES);
    float2 acc = make_float2(0.f, 0.f);
    int cur = -1;
    for (int n = start + grp; n < end; n += 4) {
        int g = batch[n];
        if (g != cur) {
            if (cur >= 0) {
                atomicAdd(&pooled[cur * HID + lane * 2], acc.x);
                atomicAdd(&pooled[cur * HID + lane * 2 + 1], acc.y);
            }
            acc = make_float2(0.f, 0.f);
            cur = g;
        }
        float2 v = unpackbf(h[(size_t)n * 64 + lane]);
        acc.x += v.x; acc.y += v.y;
    }
    if (cur >= 0) {
        atomicAdd(&pooled[cur * HID + lane * 2], acc.x);
        atomicAdd(&pooled[cur * HID + lane * 2 + 1], acc.y);
    }
}

// ---------------- final: out = (pooled/cnt) @ Wf + bf ----------------
__global__ __launch_bounds__(128) void k_final(const float* __restrict__ pooled,
                                               const int* __restrict__ cnt,
                                               const float* __restrict__ Wf,
                                               const float* __restrict__ bf,
                                               float* __restrict__ out) {
    __shared__ float p[HID];
    int g = blockIdx.x, t = threadIdx.x;
    float inv = 1.f / fmaxf((float)cnt[g], 1.f);
    p[t] = pooled[g * HID + t] * inv;
    __syncthreads();
    if (t < NCLS) {
        float acc = bf[t];
        for (int k = 0; k < HID; ++k) acc += p[k] * Wf[k * NCLS + t];
        out[g * NCLS + t] = acc;
    }
}

extern "C" void kernel_launch(void* const* d_in, const int* in_sizes, int n_in,
                              void* d_out, int out_size, void* d_ws, size_t ws_size,
                              hipStream_t stream) {
    const float* x   = (const float*)d_in[0];
    const int*   ei  = (const int*)d_in[1];   // [2][E] flat
    const int*   src = ei;
    const int*   dst = ei + N_EDGES;
    const int*   batch = (const int*)d_in[2];
    const float* W1 = (const float*)d_in[3];
    const float* b1 = (const float*)d_in[4];
    const float* W2 = (const float*)d_in[5];
    const float* b2 = (const float*)d_in[6];
    const float* Wf = (const float*)d_in[7];
    const float* bf = (const float*)d_in[8];
    float* out = (float*)d_out;

    char* ws = (char*)d_ws;
    size_t off = 0;
    unsigned* mbuf = (unsigned*)(ws + off);  off += (size_t)N_NODES * 64 * 4;   // 25.6 MB: xs+agg early, l2 messages late
    unsigned* h1b = (unsigned*)(ws + off);   off += (size_t)N_NODES * 64 * 4;   // 25.6 MB bf16 h1
    unsigned* h2b = (unsigned*)(ws + off);   off += (size_t)N_NODES * 64 * 4;   // 25.6 MB bf16 h2 / staging
    int* csr_src = (int*)(ws + off);         off += (size_t)N_EDGES * 4;        // 6.4 MB
    uint4* Bp = (uint4*)(ws + off);          off += (size_t)2048 * 16;          // 32 KB
    float* dinv = (float*)(ws + off);        off += (size_t)N_NODES * 4;
    int* rowptr = (int*)(ws + off);          off += (size_t)(N_NODES + 1) * 4;
    int* cntm = (int*)(ws + off);            off += (size_t)NBUCK * NBF * 4;    // 400 KB
    int* offs = (int*)(ws + off);            off += (size_t)NBUCK * NBF * 4;    // 400 KB
    int* tot = (int*)(ws + off);             off += (size_t)NBUCK * 4;
    int* bbase = (int*)(ws + off);           off += (size_t)NBUCK * 4;
    float* pooled = (float*)(ws + off);      off += (size_t)N_GRAPHS * HID * 4;
    int* cnt = (int*)(ws + off);             off += (size_t)N_GRAPHS * 4;
    // aliases: staging lives in h2b (dead until gather2 writes h2);
    // xs (3.2 MB) + agg (6.4 MB) live in mbuf (dead until xform2 writes messages)
    unsigned* staging = h2b;
    unsigned* xs = mbuf;
    float* agg = (float*)(mbuf + (size_t)N_NODES * 8);

    // graph preprocessing (zero global atomics)
    k_init<<<(N_GRAPHS * HID + 255) / 256, 256, 0, stream>>>(pooled);
    k_hist<<<NBF, 256, 0, stream>>>(dst, cntm);
    k_btot<<<NBUCK, 256, 0, stream>>>(cntm, tot);
    k_bscan<<<1, 256, 0, stream>>>(tot, bbase, rowptr);
    k_offs<<<NBUCK, NBF, 0, stream>>>(cntm, bbase, offs);
    k_partition<<<NBF, 256, 0, stream>>>(src, dst, offs, staging);
    k_fuse<<<NBUCK, 256, 0, stream>>>(staging, bbase, rowptr, dinv, csr_src);
    k_w2pack<<<8, 256, 0, stream>>>(W2, Bp);

    // layer 1: aggregate-first (15-ch rows, 8x less gather traffic)
    k_prescale<<<(N_NODES * 8 + 255) / 256, 256, 0, stream>>>(x, dinv, xs);
    k_gather15<<<(N_NODES + 3) / 4, 256, 0, stream>>>(rowptr, csr_src, xs, dinv, agg);
    k_xform1b<<<N_NODES / 4, 256, 0, stream>>>(agg, W1, b1, h1b);

    // layer 2 (MFMA transform writes mbuf — xs/agg dead by now)
    k_xform2<<<(N_NODES + 63) / 64, 256, 0, stream>>>(h1b, Bp, dinv, (unsigned short*)mbuf);
    k_gather<<<(N_NODES + 3) / 4, 256, 0, stream>>>(rowptr, csr_src, mbuf, b2, dinv, h2b);

    // pooling + classifier
    k_cnt<<<1, 64, 0, stream>>>(batch, cnt);
    k_pool<<<(N_NODES + POOL_CHUNK - 1) / POOL_CHUNK, 256, 0, stream>>>(h2b, batch, pooled);
    k_final<<<N_GRAPHS, 128, 0, stream>>>(pooled, cnt, Wf, bf, out);
}